// Round 1
// 463.657 us; speedup vs baseline: 1.0725x; 1.0725x over previous
//
#include <hip/hip_runtime.h>
#include <hip/hip_bf16.h>

typedef __hip_bfloat16 bf16;

#define B_     8
#define N_     64
#define H_     512
#define HEADS_ 8
#define SP_    64
#define L_     4
static constexpr float INV_SCALE = 0.044194173824159216f; // 1/sqrt(512)

typedef __attribute__((ext_vector_type(8))) short short8;
typedef __attribute__((ext_vector_type(4))) float f32x4;

__device__ __forceinline__ void unpack8(uint4 u, float* f) {
    f[0] = __uint_as_float(u.x << 16); f[1] = __uint_as_float(u.x & 0xffff0000u);
    f[2] = __uint_as_float(u.y << 16); f[3] = __uint_as_float(u.y & 0xffff0000u);
    f[4] = __uint_as_float(u.z << 16); f[5] = __uint_as_float(u.z & 0xffff0000u);
    f[6] = __uint_as_float(u.w << 16); f[7] = __uint_as_float(u.w & 0xffff0000u);
}

__device__ __forceinline__ bf16 f2bf(float v) { return __float2bfloat16(v); }

__device__ __forceinline__ uint4 pack8bf(float4 a, float4 b) {
    __align__(16) bf16 t[8];
    t[0] = f2bf(a.x); t[1] = f2bf(a.y); t[2] = f2bf(a.z); t[3] = f2bf(a.w);
    t[4] = f2bf(b.x); t[5] = f2bf(b.y); t[6] = f2bf(b.z); t[7] = f2bf(b.w);
    return *(const uint4*)t;
}

#define RSTR 80

// ------------------------------------------------------------ GEMM body (64-tile)
// EPI: 0 = fp32 out, 1 = fp32 + residual, 2 = relu->bf16, 3 = bf16
template <int EPI>
__device__ __forceinline__ void gemm64_body(char* lds,
        const bf16* __restrict__ A, const bf16* __restrict__ Bt,
        void* __restrict__ Cv, const float* __restrict__ R,
        int M, int N, int K, int bx, int by, int kbeg, int kend) {
    char* As = lds;
    char* Bs = lds + 2 * 64 * RSTR;
    const int tid = threadIdx.x;
    const int bm = bx * 64, bn = by * 64;
    const int w = tid >> 6, lane = tid & 63;
    const int wr = (w >> 1) * 32, wc = (w & 1) * 32;
    const int m0 = lane & 15, q4 = lane >> 4;

    f32x4 acc[2][2] = {};

    const int rA = tid >> 3;
    const int cA = tid & 7;
    const int ksP = cA >> 2;
    const int cB = (cA & 3) * 16;
    const int cE = cA * 8;

    for (int k0 = kbeg; k0 < kend; k0 += 64) {
        uint4 a0 = *(const uint4*)(A  + (size_t)(bm + rA) * K + k0 + cE);
        uint4 a1 = *(const uint4*)(A  + (size_t)(bm + rA + 32) * K + k0 + cE);
        uint4 b0 = *(const uint4*)(Bt + (size_t)(bn + rA) * K + k0 + cE);
        uint4 b1 = *(const uint4*)(Bt + (size_t)(bn + rA + 32) * K + k0 + cE);
        __syncthreads();
        *(uint4*)(As + ksP * (64 * RSTR) + rA * RSTR + cB) = a0;
        *(uint4*)(As + ksP * (64 * RSTR) + (rA + 32) * RSTR + cB) = a1;
        *(uint4*)(Bs + ksP * (64 * RSTR) + rA * RSTR + cB) = b0;
        *(uint4*)(Bs + ksP * (64 * RSTR) + (rA + 32) * RSTR + cB) = b1;
        __syncthreads();
        short8 af[2][2], bfr[2][2];
        #pragma unroll
        for (int ks = 0; ks < 2; ++ks)
            #pragma unroll
            for (int t = 0; t < 2; ++t) {
                af[ks][t]  = *(const short8*)(As + ks * (64 * RSTR) + (wr + t * 16 + m0) * RSTR + q4 * 16);
                bfr[ks][t] = *(const short8*)(Bs + ks * (64 * RSTR) + (wc + t * 16 + m0) * RSTR + q4 * 16);
            }
        #pragma unroll
        for (int ks = 0; ks < 2; ++ks)
            #pragma unroll
            for (int mt = 0; mt < 2; ++mt)
                #pragma unroll
                for (int nt = 0; nt < 2; ++nt)
                    acc[mt][nt] = __builtin_amdgcn_mfma_f32_16x16x32_bf16(
                        af[ks][mt], bfr[ks][nt], acc[mt][nt], 0, 0, 0);
    }

    if (EPI <= 1) {
        float* C = (float*)Cv;
        #pragma unroll
        for (int mt = 0; mt < 2; ++mt)
            #pragma unroll
            for (int i = 0; i < 4; ++i) {
                int row = bm + wr + mt * 16 + q4 * 4 + i;
                #pragma unroll
                for (int nt = 0; nt < 2; ++nt) {
                    int col = bn + wc + nt * 16 + m0;
                    float v = acc[mt][nt][i];
                    if (EPI == 1) v += R[(size_t)row * N + col];
                    C[(size_t)row * N + col] = v;
                }
            }
    } else {
        bf16* C = (bf16*)Cv;
        #pragma unroll
        for (int mt = 0; mt < 2; ++mt)
            #pragma unroll
            for (int i = 0; i < 4; ++i) {
                int row = bm + wr + mt * 16 + q4 * 4 + i;
                #pragma unroll
                for (int nt = 0; nt < 2; ++nt) {
                    int col = bn + wc + nt * 16 + m0;
                    float v = acc[mt][nt][i];
                    if (EPI == 2) v = fmaxf(v, 0.0f);
                    C[(size_t)row * N + col] = __float2bfloat16(v);
                }
            }
    }
}

template <int EPI, bool SPLIT>
__launch_bounds__(256)
__global__ void mfma_gemm_s(const bf16* __restrict__ A, const bf16* __restrict__ Bt,
                            void* __restrict__ Cv, const float* __restrict__ R,
                            int M, int N, int K) {
    __shared__ __align__(16) char lds[4 * 64 * RSTR];
    int kbeg = 0, kend = K;
    const bf16* B2 = Bt;
    void* C2 = Cv;
    if (SPLIT) {
        int ks = K / gridDim.z;
        kbeg = blockIdx.z * ks;
        kend = kbeg + ks;
        C2 = (void*)((float*)Cv + (size_t)blockIdx.z * M * N);
        gemm64_body<0>(lds, A, B2, C2, nullptr, M, N, K, blockIdx.x, blockIdx.y, kbeg, kend);
    } else {
        B2 = Bt + (size_t)blockIdx.z * N * K;
        if (EPI <= 1) C2 = (void*)((float*)Cv + (size_t)blockIdx.z * M * N);
        gemm64_body<EPI>(lds, A, B2, C2, R, M, N, K, blockIdx.x, blockIdx.y, kbeg, kend);
    }
}

// ------------------------------------------------ factored-ew basis GEMMs
// l=1: bx<8 -> XW1 = x_bf @ Wew1 ; bx==8 -> E0W1 = E0pad @ Wew1
__launch_bounds__(256)
__global__ void basis_gemm1(const bf16* __restrict__ x_bf, const bf16* __restrict__ E0,
                            const bf16* __restrict__ ewt1,
                            bf16* __restrict__ xw1, bf16* __restrict__ e0w1) {
    __shared__ __align__(16) char lds[4 * 64 * RSTR];
    if (blockIdx.x < 8)
        gemm64_body<3>(lds, x_bf, ewt1, xw1, nullptr, 512, 512, 512,
                       blockIdx.x, blockIdx.y, 0, 512);
    else
        gemm64_body<3>(lds, E0, ewt1, e0w1, nullptr, 64, 512, 512,
                       0, blockIdx.y, 0, 512);
}

// l=2: bx<8 -> XW12 = xw1 @ Wew2 ; bx<16 -> X2W2 = x_bf @ Wew2 ; bx==16 -> E0W12 = e0w1 @ Wew2
__launch_bounds__(256)
__global__ void basis_gemm2(const bf16* __restrict__ xw1, const bf16* __restrict__ x_bf,
                            const bf16* __restrict__ e0w1, const bf16* __restrict__ ewt2,
                            bf16* __restrict__ xw12, bf16* __restrict__ x2w2,
                            bf16* __restrict__ e0w12) {
    __shared__ __align__(16) char lds[4 * 64 * RSTR];
    if (blockIdx.x < 8)
        gemm64_body<3>(lds, xw1, ewt2, xw12, nullptr, 512, 512, 512,
                       blockIdx.x, blockIdx.y, 0, 512);
    else if (blockIdx.x < 16)
        gemm64_body<3>(lds, x_bf, ewt2, x2w2, nullptr, 512, 512, 512,
                       blockIdx.x - 8, blockIdx.y, 0, 512);
    else
        gemm64_body<3>(lds, e0w1, ewt2, e0w12, nullptr, 64, 512, 512,
                       0, blockIdx.y, 0, 512);
}

// ew1[p] = c0*E0W1[adj[p]] + c1*XW1[i] + c2*XW1[j]      (grid 8192 x 256)
__launch_bounds__(256)
__global__ void ew_combine1(const int* __restrict__ adj,
                            const float* __restrict__ c0, const float* __restrict__ c1,
                            const float* __restrict__ c2,
                            const bf16* __restrict__ e0w1, const bf16* __restrict__ xw1,
                            bf16* __restrict__ ew) {
    int gid = blockIdx.x * 256 + threadIdx.x;
    int pair = gid >> 6;
    int c8 = (gid & 63) * 8;
    int b  = pair >> 12;
    int ri = pair >> 6;                 // b*64+i
    int rj = (b << 6) | (pair & 63);    // b*64+j
    float a = c0[pair], bb = c1[pair], cc = c2[pair];
    int t = adj[pair];
    uint4 ue = *(const uint4*)(e0w1 + (size_t)t  * H_ + c8);
    uint4 ui = *(const uint4*)(xw1  + (size_t)ri * H_ + c8);
    uint4 uj = *(const uint4*)(xw1  + (size_t)rj * H_ + c8);
    float fe[8], fi[8], fj[8];
    unpack8(ue, fe); unpack8(ui, fi); unpack8(uj, fj);
    __align__(16) bf16 o[8];
    #pragma unroll
    for (int k = 0; k < 8; ++k)
        o[k] = f2bf(a * fe[k] + bb * fi[k] + cc * fj[k]);
    *(uint4*)(ew + (size_t)pair * H_ + c8) = *(const uint4*)o;
}

// ew2[p] = v0*u0*E0W12[adj] + v0*u1*XW12[i] + v0*u2*XW12[j] + v1*X2W2[i] + v2*X2W2[j]
__launch_bounds__(256)
__global__ void ew_combine2(const int* __restrict__ adj,
                            const float* __restrict__ u0, const float* __restrict__ u1,
                            const float* __restrict__ u2,
                            const float* __restrict__ v0, const float* __restrict__ v1,
                            const float* __restrict__ v2,
                            const bf16* __restrict__ e0w12, const bf16* __restrict__ xw12,
                            const bf16* __restrict__ x2w2, bf16* __restrict__ ew) {
    int gid = blockIdx.x * 256 + threadIdx.x;
    int pair = gid >> 6;
    int c8 = (gid & 63) * 8;
    int b  = pair >> 12;
    int ri = pair >> 6;
    int rj = (b << 6) | (pair & 63);
    float a0 = v0[pair];
    float cE = a0 * u0[pair], ci = a0 * u1[pair], cj = a0 * u2[pair];
    float di = v1[pair], dj = v2[pair];
    int t = adj[pair];
    uint4 ue = *(const uint4*)(e0w12 + (size_t)t  * H_ + c8);
    uint4 ua = *(const uint4*)(xw12  + (size_t)ri * H_ + c8);
    uint4 ub = *(const uint4*)(xw12  + (size_t)rj * H_ + c8);
    uint4 uc = *(const uint4*)(x2w2  + (size_t)ri * H_ + c8);
    uint4 ud = *(const uint4*)(x2w2  + (size_t)rj * H_ + c8);
    float fe[8], fa[8], fb[8], fc[8], fd[8];
    unpack8(ue, fe); unpack8(ua, fa); unpack8(ub, fb); unpack8(uc, fc); unpack8(ud, fd);
    __align__(16) bf16 o[8];
    #pragma unroll
    for (int k = 0; k < 8; ++k)
        o[k] = f2bf(cE * fe[k] + ci * fa[k] + cj * fb[k] + di * fc[k] + dj * fd[k]);
    *(uint4*)(ew + (size_t)pair * H_ + c8) = *(const uint4*)o;
}

// ---------------------- layer-3 implicit-ew path (unchanged)
__launch_bounds__(256)
__global__ void u_gemm(const float* __restrict__ q, const bf16* __restrict__ wc3,
                       float* __restrict__ u) {
    __shared__ __align__(16) char lds[4 * 64 * RSTR];
    char* As = lds;
    char* Bs = lds + 2 * 64 * RSTR;
    const int h = blockIdx.x, mb = blockIdx.y, nb = blockIdx.z;
    const int tid = threadIdx.x;
    const int w = tid >> 6, lane = tid & 63;
    const int wr = (w >> 1) * 32, wc = (w & 1) * 32;
    const int m0 = lane & 15, q4 = lane >> 4;
    const int rA = tid >> 3;
    const int cA = tid & 7;
    const int ksP = cA >> 2;
    const int cB = (cA & 3) * 16;
    const int cE = cA * 8;

    const float* Aq = q + (size_t)(mb * 64) * 512 + h * 64;
    const bf16*  Bt = wc3 + (size_t)(nb * 64) * 512 + h * 64;

    float4 fa0 = *(const float4*)(Aq + (size_t)rA * 512 + cE);
    float4 fa1 = *(const float4*)(Aq + (size_t)rA * 512 + cE + 4);
    float4 fb0 = *(const float4*)(Aq + (size_t)(rA + 32) * 512 + cE);
    float4 fb1 = *(const float4*)(Aq + (size_t)(rA + 32) * 512 + cE + 4);
    uint4 b0 = *(const uint4*)(Bt + (size_t)rA * 512 + cE);
    uint4 b1 = *(const uint4*)(Bt + (size_t)(rA + 32) * 512 + cE);
    uint4 a0 = pack8bf(fa0, fa1);
    uint4 a1 = pack8bf(fb0, fb1);
    *(uint4*)(As + ksP * (64 * RSTR) + rA * RSTR + cB) = a0;
    *(uint4*)(As + ksP * (64 * RSTR) + (rA + 32) * RSTR + cB) = a1;
    *(uint4*)(Bs + ksP * (64 * RSTR) + rA * RSTR + cB) = b0;
    *(uint4*)(Bs + ksP * (64 * RSTR) + (rA + 32) * RSTR + cB) = b1;
    __syncthreads();

    f32x4 acc[2][2] = {};
    short8 af[2][2], bfr[2][2];
    #pragma unroll
    for (int ks = 0; ks < 2; ++ks)
        #pragma unroll
        for (int t = 0; t < 2; ++t) {
            af[ks][t]  = *(const short8*)(As + ks * (64 * RSTR) + (wr + t * 16 + m0) * RSTR + q4 * 16);
            bfr[ks][t] = *(const short8*)(Bs + ks * (64 * RSTR) + (wc + t * 16 + m0) * RSTR + q4 * 16);
        }
    #pragma unroll
    for (int ks = 0; ks < 2; ++ks)
        #pragma unroll
        for (int mt = 0; mt < 2; ++mt)
            #pragma unroll
            for (int nt = 0; nt < 2; ++nt)
                acc[mt][nt] = __builtin_amdgcn_mfma_f32_16x16x32_bf16(
                    af[ks][mt], bfr[ks][nt], acc[mt][nt], 0, 0, 0);

    #pragma unroll
    for (int mt = 0; mt < 2; ++mt)
        #pragma unroll
        for (int i = 0; i < 4; ++i) {
            int row = mb * 64 + wr + mt * 16 + q4 * 4 + i;
            #pragma unroll
            for (int nt = 0; nt < 2; ++nt) {
                int col = nb * 64 + wc + nt * 16 + m0;
                u[(size_t)row * 4096 + h * 512 + col] = acc[mt][nt][i];
            }
        }
}

__global__ void cast_w3(const float* __restrict__ in, bf16* __restrict__ out) {
    int gid = blockIdx.x * 256 + threadIdx.x;
    const float4* p = (const float4*)(in + (size_t)gid * 8);
    float4 a = p[0], b = p[1];
    *(uint4*)(out + (size_t)gid * 8) = pack8bf(a, b);
}

__global__ void s2_kernel(const bf16* __restrict__ bond, const float* __restrict__ u,
                          float* __restrict__ s2) {
    int bi = blockIdx.x;
    int b = bi >> 6, i = bi & 63;
    int lane = threadIdx.x, ty = threadIdx.y;
    int tid = ty * 64 + lane;
    __shared__ float uS[8][512];
    __shared__ float red[4][64][9];
    #pragma unroll
    for (int t = 0; t < 4; ++t) {
        int f = tid + 256 * t;
        ((uint4*)uS)[f] = ((const uint4*)(u + (size_t)bi * 4096))[f];
    }
    __syncthreads();
    const bf16* brow = bond + ((size_t)bi * 64 + lane) * 512 + ty * 128;
    float acc[8] = {};
    #pragma unroll
    for (int c16 = 0; c16 < 16; ++c16) {
        uint4 bu = ((const uint4*)brow)[c16];
        float bfv[8];
        unpack8(bu, bfv);
        int k0 = ty * 128 + c16 * 8;
        #pragma unroll
        for (int h = 0; h < 8; ++h) {
            float4 ua = *(const float4*)&uS[h][k0];
            float4 ub = *(const float4*)&uS[h][k0 + 4];
            acc[h] += bfv[0] * ua.x + bfv[1] * ua.y + bfv[2] * ua.z + bfv[3] * ua.w
                    + bfv[4] * ub.x + bfv[5] * ub.y + bfv[6] * ub.z + bfv[7] * ub.w;
        }
    }
    #pragma unroll
    for (int h = 0; h < 8; ++h) red[ty][lane][h] = acc[h];
    __syncthreads();
    if (ty == 0) {
        #pragma unroll
        for (int h = 0; h < 8; ++h) {
            float s = red[0][lane][h] + red[1][lane][h] + red[2][lane][h] + red[3][lane][h];
            s2[(((size_t)b * 8 + h) * 64 + i) * 64 + lane] = s;
        }
    }
}

// ---------------------------------------------------------------- embeddings
__global__ void embed_ln_kernel(const int* __restrict__ ids,
                                const float* __restrict__ emb,
                                float* __restrict__ xn, bf16* __restrict__ xn_bf) {
    int row = blockIdx.x;
    int tid = threadIdx.x;
    const float* r = emb + (size_t)ids[row] * H_;
    float x0 = r[tid], x1 = r[tid + 256];
    float s = x0 + x1, sq = x0 * x0 + x1 * x1;
    #pragma unroll
    for (int off = 32; off; off >>= 1) {
        s  += __shfl_xor(s,  off);
        sq += __shfl_xor(sq, off);
    }
    __shared__ float ls[4], lq[4];
    int w = tid >> 6;
    if ((tid & 63) == 0) { ls[w] = s; lq[w] = sq; }
    __syncthreads();
    float S = ls[0] + ls[1] + ls[2] + ls[3];
    float Q = lq[0] + lq[1] + lq[2] + lq[3];
    float mean = S * (1.0f / H_);
    float var  = Q * (1.0f / H_) - mean * mean;
    float inv  = rsqrtf(var + 1e-5f);
    float y0 = (x0 - mean) * inv, y1 = (x1 - mean) * inv;
    xn[(size_t)row * H_ + tid]       = y0;
    xn[(size_t)row * H_ + tid + 256] = y1;
    xn_bf[(size_t)row * H_ + tid]       = f2bf(y0);
    xn_bf[(size_t)row * H_ + tid + 256] = f2bf(y1);
}

// E0 padded to 64 rows: rows 8..63 zeroed (basis GEMMs read the full 64-row tile)
__global__ void ew0_precompute(const float* __restrict__ bond_emb,
                               const bf16* __restrict__ ewt0, bf16* __restrict__ E0) {
    int t = blockIdx.x, cb = blockIdx.y, lane = threadIdx.x;
    int c = cb * 64 + lane;
    if (t >= 8) { E0[t * 512 + c] = f2bf(0.0f); return; }
    __shared__ float be[512];
    for (int h = lane; h < 512; h += 64) be[h] = bond_emb[t * 512 + h];
    __syncthreads();
    const bf16* wr = ewt0 + (size_t)c * 512;
    float acc = 0.f;
    for (int h8 = 0; h8 < 64; ++h8) {
        uint4 u = *(const uint4*)(wr + h8 * 8);
        float wf[8];
        unpack8(u, wf);
        const float* b = &be[h8 * 8];
        acc += b[0]*wf[0] + b[1]*wf[1] + b[2]*wf[2] + b[3]*wf[3]
             + b[4]*wf[4] + b[5]*wf[5] + b[6]*wf[6] + b[7]*wf[7];
    }
    E0[t * 512 + c] = f2bf(acc);
}

// ------------------------------------------------- weight transpose + cast
__global__ void transpose_sq(const float* __restrict__ Wq, const float* __restrict__ Wk,
                             const float* __restrict__ Wv, const float* __restrict__ Wew,
                             const float* __restrict__ Wst,
                             bf16* __restrict__ qkvt, bf16* __restrict__ ewt,
                             bf16* __restrict__ stackt) {
    const size_t KN = (size_t)H_ * H_;
    int z = blockIdx.z;
    const float* W; bf16* Wt;
    if (z < 12) {
        int s = z >> 2, l = z & 3;
        W  = (s == 0 ? Wq : s == 1 ? Wk : Wv) + (size_t)l * KN;
        Wt = qkvt + (size_t)l * 3 * KN + (size_t)s * KN;
    } else if (z < 16) {
        int l = z - 12;
        W = Wew + (size_t)l * KN; Wt = ewt + (size_t)l * KN;
    } else {
        int l = z - 16;
        W = Wst + (size_t)l * KN; Wt = stackt + (size_t)l * KN;
    }
    __shared__ float t[32][33];
    int k0 = blockIdx.x * 32, n0 = blockIdx.y * 32;
    int tx = threadIdx.x, ty = threadIdx.y;
    #pragma unroll
    for (int r = ty; r < 32; r += 8)
        t[r][tx] = W[(size_t)(k0 + r) * H_ + n0 + tx];
    __syncthreads();
    #pragma unroll
    for (int r = ty; r < 32; r += 8)
        Wt[(size_t)(n0 + r) * H_ + k0 + tx] = f2bf(t[tx][r]);
}

__global__ void transpose_rect(const float* __restrict__ Wf1, const float* __restrict__ Wf2,
                               bf16* __restrict__ f1t, bf16* __restrict__ f2t) {
    const size_t KN4 = (size_t)4 * H_ * H_;
    int z = blockIdx.z;
    const float* W; bf16* Wt; int K, N;
    if (z < 4) {
        if (blockIdx.x >= 16) return;
        W = Wf1 + (size_t)z * KN4; Wt = f1t + (size_t)z * KN4; K = 512; N = 2048;
    } else {
        if (blockIdx.y >= 16) return;
        W = Wf2 + (size_t)(z - 4) * KN4; Wt = f2t + (size_t)(z - 4) * KN4; K = 2048; N = 512;
    }
    __shared__ float t[32][33];
    int k0 = blockIdx.x * 32, n0 = blockIdx.y * 32;
    int tx = threadIdx.x, ty = threadIdx.y;
    #pragma unroll
    for (int r = ty; r < 32; r += 8)
        t[r][tx] = W[(size_t)(k0 + r) * N + n0 + tx];
    __syncthreads();
    #pragma unroll
    for (int r = ty; r < 32; r += 8)
        Wt[(size_t)(n0 + r) * K + k0 + tx] = f2bf(t[tx][r]);
}

// ---------------------- split-K reduce + residual + LN variants
__global__ void reduce_stack_ln(const float* __restrict__ part, const float* __restrict__ base,
                                float* __restrict__ resid, bf16* __restrict__ ffin_bf) {
    const int MN = 512 * H_;
    int row = blockIdx.x;
    int tid = threadIdx.x;
    size_t b0 = (size_t)row * H_;
    float v0 = base[b0 + tid], v1 = base[b0 + tid + 256];
    #pragma unroll
    for (int s = 0; s < 4; ++s) {
        v0 += part[(size_t)s * MN + b0 + tid];
        v1 += part[(size_t)s * MN + b0 + tid + 256];
    }
    resid[b0 + tid] = v0;
    resid[b0 + tid + 256] = v1;
    float s = v0 + v1, sq = v0 * v0 + v1 * v1;
    #pragma unroll
    for (int off = 32; off; off >>= 1) {
        s  += __shfl_xor(s,  off);
        sq += __shfl_xor(sq, off);
    }
    __shared__ float ls[4], lq[4];
    int w = tid >> 6;
    if ((tid & 63) == 0) { ls[w] = s; lq[w] = sq; }
    __syncthreads();
    float S = ls[0] + ls[1] + ls[2] + ls[3];
    float Q = lq[0] + lq[1] + lq[2] + lq[3];
    float mean = S * (1.0f / H_);
    float var  = Q * (1.0f / H_) - mean * mean;
    float inv  = rsqrtf(var + 1e-5f);
    ffin_bf[b0 + tid]       = f2bf((v0 - mean) * inv);
    ffin_bf[b0 + tid + 256] = f2bf((v1 - mean) * inv);
}

template <bool DO_LN>
__global__ void reduce_ln_kernel(const float* __restrict__ part, const float* __restrict__ resid,
                                 float* __restrict__ x, bf16* __restrict__ x_bf,
                                 float* __restrict__ xn, bf16* __restrict__ xn_bf) {
    const int MN = 512 * H_;
    int row = blockIdx.x;
    int tid = threadIdx.x;
    size_t base = (size_t)row * H_;
    float v0 = resid[base + tid], v1 = resid[base + tid + 256];
    #pragma unroll
    for (int s = 0; s < 4; ++s) {
        v0 += part[(size_t)s * MN + base + tid];
        v1 += part[(size_t)s * MN + base + tid + 256];
    }
    x[base + tid] = v0;
    x[base + tid + 256] = v1;
    x_bf[base + tid]       = f2bf(v0);
    x_bf[base + tid + 256] = f2bf(v1);
    if (DO_LN) {
        float s = v0 + v1, sq = v0 * v0 + v1 * v1;
        #pragma unroll
        for (int off = 32; off; off >>= 1) {
            s  += __shfl_xor(s,  off);
            sq += __shfl_xor(sq, off);
        }
        __shared__ float ls[4], lq[4];
        int w = tid >> 6;
        if ((tid & 63) == 0) { ls[w] = s; lq[w] = sq; }
        __syncthreads();
        float S = ls[0] + ls[1] + ls[2] + ls[3];
        float Q = lq[0] + lq[1] + lq[2] + lq[3];
        float mean = S * (1.0f / H_);
        float var  = Q * (1.0f / H_) - mean * mean;
        float inv  = rsqrtf(var + 1e-5f);
        float y0 = (v0 - mean) * inv, y1 = (v1 - mean) * inv;
        xn[base + tid]       = y0;
        xn[base + tid + 256] = y1;
        xn_bf[base + tid]       = f2bf(y0);
        xn_bf[base + tid + 256] = f2bf(y1);
    }
}

// ---------------------------------------------------------------- attention
// GATHER: read per-pair w-row from E0[adj[pair]] (l=0) instead of materialized ew
template <bool GATHER>
__global__ void attn_kernel(const float* __restrict__ qkv, const bf16* __restrict__ ew,
                            const int* __restrict__ adj, bf16* __restrict__ o) {
    const float* q = qkv;
    const float* k = qkv + (size_t)512 * H_;
    const float* v = qkv + (size_t)1024 * H_;
    int bi = blockIdx.x;
    int b  = bi >> 6;
    int ty = threadIdx.y;
    int h  = blockIdx.y * 4 + ty;
    int lane = threadIdx.x;
    __shared__ float qs[4][64], as[4][64];
    qs[ty][lane] = q[(size_t)bi * H_ + h * 64 + lane];
    __syncthreads();

    int j = lane;
    int pair = bi * 64 + j;
    int aj = adj[pair];
    const float4* k4 = (const float4*)(k + (size_t)(b * 64 + j) * H_ + h * 64);
    const uint4*  w4 = (const uint4*)((GATHER ? ew + (size_t)aj * H_
                                              : ew + (size_t)pair * H_) + h * 64);
    float acc = 0.f;
    #pragma unroll
    for (int t = 0; t < 8; ++t) {
        uint4 wu = w4[t];
        float4 ka = k4[2 * t], kb = k4[2 * t + 1];
        float wf[8];
        unpack8(wu, wf);
        const float* qq = &qs[ty][t * 8];
        acc += qq[0] * (ka.x + wf[0]) + qq[1] * (ka.y + wf[1])
             + qq[2] * (ka.z + wf[2]) + qq[3] * (ka.w + wf[3])
             + qq[4] * (kb.x + wf[4]) + qq[5] * (kb.y + wf[5])
             + qq[6] * (kb.z + wf[6]) + qq[7] * (kb.w + wf[7]);
    }
    float logit = acc * INV_SCALE;
    if (aj <= 0) logit = -INFINITY;

    float m = logit;
    #pragma unroll
    for (int off = 32; off; off >>= 1) m = fmaxf(m, __shfl_xor(m, off));
    float p = expf(logit - m);
    float s = p;
    #pragma unroll
    for (int off = 32; off; off >>= 1) s += __shfl_xor(s, off);
    as[ty][lane] = p / s;
    __syncthreads();

    const float* vbase = v + (size_t)(b * 64) * H_ + h * 64;
    float oacc = 0.f;
    int d = lane;
    #pragma unroll 8
    for (int jj = 0; jj < 64; ++jj)
        oacc += as[ty][jj] * vbase[(size_t)jj * H_ + d];
    o[(size_t)bi * H_ + h * 64 + d] = __float2bfloat16(oacc);
}

// layer-3 variant: w-term from precomputed s2 (no ew)
__global__ void attn3_kernel(const float* __restrict__ qkv, const float* __restrict__ s2,
                             const int* __restrict__ adj, bf16* __restrict__ o) {
    const float* q = qkv;
    const float* k = qkv + (size_t)512 * H_;
    const float* v = qkv + (size_t)1024 * H_;
    int bi = blockIdx.x;
    int b  = bi >> 6, i = bi & 63;
    int ty = threadIdx.y;
    int h  = blockIdx.y * 4 + ty;
    int lane = threadIdx.x;
    __shared__ float qs[4][64], as[4][64];
    qs[ty][lane] = q[(size_t)bi * H_ + h * 64 + lane];
    __syncthreads();

    int j = lane;
    const float4* k4 = (const float4*)(k + (size_t)(b * 64 + j) * H_ + h * 64);
    float acc = s2[(((size_t)b * 8 + h) * 64 + i) * 64 + j];
    #pragma unroll
    for (int t = 0; t < 8; ++t) {
        float4 ka = k4[2 * t], kb = k4[2 * t + 1];
        const float* qq = &qs[ty][t * 8];
        acc += qq[0] * ka.x + qq[1] * ka.y + qq[2] * ka.z + qq[3] * ka.w
             + qq[4] * kb.x + qq[5] * kb.y + qq[6] * kb.z + qq[7] * kb.w;
    }
    float logit = acc * INV_SCALE;
    if (adj[(size_t)bi * 64 + j] <= 0) logit = -INFINITY;

    float m = logit;
    #pragma unroll
    for (int off = 32; off; off >>= 1) m = fmaxf(m, __shfl_xor(m, off));
    float p = expf(logit - m);
    float s = p;
    #pragma unroll
    for (int off = 32; off; off >>= 1) s += __shfl_xor(s, off);
    as[ty][lane] = p / s;
    __syncthreads();

    const float* vbase = v + (size_t)(b * 64) * H_ + h * 64;
    float oacc = 0.f;
    int d = lane;
    #pragma unroll 8
    for (int jj = 0; jj < 64; ++jj)
        oacc += as[ty][jj] * vbase[(size_t)jj * H_ + d];
    o[(size_t)bi * H_ + h * 64 + d] = __float2bfloat16(oacc);
}

// ---------------------------------------------------------------- edge update
// full variant: materializes new bond (only needed at l=2, feeds l=3 s2 path)
__global__ void edge_kernel(const bf16* __restrict__ ew, const float* __restrict__ x,
                            bf16* __restrict__ bond) {
    int pair = blockIdx.x * 4 + threadIdx.y;
    int b = pair >> 12;
    int i = (pair >> 6) & 63;
    int j = pair & 63;
    int lane = threadIdx.x;
    const uint4*  e4  = (const uint4*)(ew + (size_t)pair * H_);
    const float4* xi4 = (const float4*)(x + (size_t)(b * 64 + i) * H_);
    const float4* xj4 = (const float4*)(x + (size_t)(b * 64 + j) * H_);
    uint4  eu = e4[lane];
    float4 a0 = xi4[lane * 2], a1 = xi4[lane * 2 + 1];
    float4 c0 = xj4[lane * 2], c1 = xj4[lane * 2 + 1];
    float ef[8], af[8], cf[8];
    unpack8(eu, ef);
    af[0] = a0.x; af[1] = a0.y; af[2] = a0.z; af[3] = a0.w;
    af[4] = a1.x; af[5] = a1.y; af[6] = a1.z; af[7] = a1.w;
    cf[0] = c0.x; cf[1] = c0.y; cf[2] = c0.z; cf[3] = c0.w;
    cf[4] = c1.x; cf[5] = c1.y; cf[6] = c1.z; cf[7] = c1.w;
    float s0 = 0.f, s1 = 0.f, s2 = 0.f;
    #pragma unroll
    for (int t = 0; t < 8; ++t) {
        s0 += ef[t] * ef[t]; s1 += ef[t] * af[t]; s2 += ef[t] * cf[t];
    }
    #pragma unroll
    for (int off = 32; off; off >>= 1) {
        s0 += __shfl_xor(s0, off);
        s1 += __shfl_xor(s1, off);
        s2 += __shfl_xor(s2, off);
    }
    float t0 = s0 * INV_SCALE, t1 = s1 * INV_SCALE, t2 = s2 * INV_SCALE;
    float m = fmaxf(t0, fmaxf(t1, t2));
    float e0 = expf(t0 - m), e1 = expf(t1 - m), e2 = expf(t2 - m);
    float inv = 1.0f / (e0 + e1 + e2);
    float w0 = e0 * inv, w1 = e1 * inv, w2 = e2 * inv;
    __align__(16) bf16 ob[8];
    #pragma unroll
    for (int t = 0; t < 8; ++t)
        ob[t] = __float2bfloat16(w0 * ef[t] + w1 * af[t] + w2 * cf[t]);
    *(uint4*)(bond + (size_t)pair * H_ + lane * 8) = *(const uint4*)ob;
}

// coefficient-only variant: emits softmax weights (w0,w1,w2) per pair; no bond write.
// GATHER: read ew row from E0[adj[pair]] (l=0).
template <bool GATHER>
__global__ void edge_coeff_kernel(const bf16* __restrict__ ewsrc, const int* __restrict__ adj,
                                  const float* __restrict__ x,
                                  float* __restrict__ w0o, float* __restrict__ w1o,
                                  float* __restrict__ w2o) {
    int pair = blockIdx.x * 4 + threadIdx.y;
    int b = pair >> 12;
    int i = (pair >> 6) & 63;
    int j = pair & 63;
    int lane = threadIdx.x;
    const uint4*  e4  = (const uint4*)(GATHER ? ewsrc + (size_t)adj[pair] * H_
                                              : ewsrc + (size_t)pair * H_);
    const float4* xi4 = (const float4*)(x + (size_t)(b * 64 + i) * H_);
    const float4* xj4 = (const float4*)(x + (size_t)(b * 64 + j) * H_);
    uint4  eu = e4[lane];
    float4 a0 = xi4[lane * 2], a1 = xi4[lane * 2 + 1];
    float4 c0 = xj4[lane * 2], c1 = xj4[lane * 2 + 1];
    float ef[8], af[8], cf[8];
    unpack8(eu, ef);
    af[0] = a0.x; af[1] = a0.y; af[2] = a0.z; af[3] = a0.w;
    af[4] = a1.x; af[5] = a1.y; af[6] = a1.z; af[7] = a1.w;
    cf[0] = c0.x; cf[1] = c0.y; cf[2] = c0.z; cf[3] = c0.w;
    cf[4] = c1.x; cf[5] = c1.y; cf[6] = c1.z; cf[7] = c1.w;
    float s0 = 0.f, s1 = 0.f, s2 = 0.f;
    #pragma unroll
    for (int t = 0; t < 8; ++t) {
        s0 += ef[t] * ef[t]; s1 += ef[t] * af[t]; s2 += ef[t] * cf[t];
    }
    #pragma unroll
    for (int off = 32; off; off >>= 1) {
        s0 += __shfl_xor(s0, off);
        s1 += __shfl_xor(s1, off);
        s2 += __shfl_xor(s2, off);
    }
    float t0 = s0 * INV_SCALE, t1 = s1 * INV_SCALE, t2 = s2 * INV_SCALE;
    float m = fmaxf(t0, fmaxf(t1, t2));
    float e0 = expf(t0 - m), e1 = expf(t1 - m), e2 = expf(t2 - m);
    float inv = 1.0f / (e0 + e1 + e2);
    if (lane == 0) {
        w0o[pair] = e0 * inv;
        w1o[pair] = e1 * inv;
        w2o[pair] = e2 * inv;
    }
}

// ---------------------------------------------------------------- head
__global__ void cls_part_kernel(const float* __restrict__ x, const float* __restrict__ Wout,
                                float* __restrict__ clspart) {
    int b  = blockIdx.x;
    int cb = blockIdx.y;
    int ks = blockIdx.z;
    int tid = threadIdx.x;
    int c  = cb * 64 + (tid & 63);
    int kk = tid >> 6;
    const float* xr = x + (size_t)(b * 64) * H_;
    int h0 = ks * 128 + kk * 32;
    float acc = 0.f;
    #pragma unroll
    for (int h = 0; h < 32; ++h)
        acc += xr[h0 + h] * Wout[(size_t)(h0 + h) * H_ + c];
    __shared__ float red[4][64];
    red[kk][tid & 63] = acc;
    __syncthreads();
    if (tid < 64) {
        float v = red[0][tid] + red[1][tid] + red[2][tid] + red[3][tid];
        clspart[((size_t)ks * 8 + b) * H_ + cb * 64 + tid] = v;
    }
}

__global__ void cls_pred2_kernel(const float* __restrict__ clspart,
                                 const float* __restrict__ Wpred,
                                 const float* __restrict__ bpred,
                                 float* __restrict__ out) {
    int b = blockIdx.x;
    int tid = threadIdx.x;
    __shared__ float red0[4], red1[4];
    float a0 = 0.f, a1 = 0.f;
    #pragma unroll
    for (int t = 0; t < 2; ++t) {
        int c = tid + t * 256;
        float v = clspart[((size_t)0 * 8 + b) * H_ + c]
                + clspart[((size_t)1 * 8 + b) * H_ + c]
                + clspart[((size_t)2 * 8 + b) * H_ + c]
                + clspart[((size_t)3 * 8 + b) * H_ + c];
        float tv = tanhf(v);
        a0 += tv * Wpred[c * 2 + 0];
        a1 += tv * Wpred[c * 2 + 1];
    }
    #pragma unroll
    for (int off = 32; off; off >>= 1) {
        a0 += __shfl_xor(a0, off);
        a1 += __shfl_xor(a1, off);
    }
    int w = tid >> 6;
    if ((tid & 63) == 0) { red0[w] = a0; red1[w] = a1; }
    __syncthreads();
    if (tid == 0) {
        float s0 = red0[0] + red0[1] + red0[2] + red0[3] + bpred[0];
        float s1 = red1[0] + red1[1] + red1[2] + red1[3] + bpred[1];
        float m = fmaxf(s0, s1);
        float e0 = expf(s0 - m), e1 = expf(s1 - m);
        float inv = 1.0f / (e0 + e1);
        out[b * 2 + 0] = e0 * inv;
        out[b * 2 + 1] = e1 * inv;
    }
}

// ---------------------------------------------------------------- launch
extern "C" void kernel_launch(void* const* d_in, const int* in_sizes, int n_in,
                              void* d_out, int out_size, void* d_ws, size_t ws_size,
                              hipStream_t stream) {
    const int*   ids      = (const int*)d_in[0];
    const int*   adj      = (const int*)d_in[1];
    const float* atom_emb = (const float*)d_in[2];
    const float* bond_emb = (const float*)d_in[3];
    const float* Wq     = (const float*)d_in[4];
    const float* Wk     = (const float*)d_in[5];
    const float* Wv     = (const float*)d_in[6];
    const float* Wew    = (const float*)d_in[7];
    const float* Wstack = (const float*)d_in[8];
    const float* Wf1    = (const float*)d_in[9];
    const float* Wf2    = (const float*)d_in[10];
    const float* Wout   = (const float*)d_in[11];
    const float* Wpred  = (const float*)d_in[12];
    const float* bpred  = (const float*)d_in[13];

    char* ws = (char*)d_ws;
    size_t off = 0;
    auto alloc = [&](size_t bytes) {
        size_t o = off;
        off += (bytes + 255) & ~(size_t)255;
        return o;
    };
    const size_t ROWS  = (size_t)B_ * N_;
    const size_t PAIRS = (size_t)B_ * N_ * N_;
    const size_t KN    = (size_t)H_ * H_;

    float* x       = (float*)(ws + alloc(ROWS * H_ * 4));
    float* xn      = (float*)(ws + alloc(ROWS * H_ * 4));
    bf16*  xn_bf   = (bf16*) (ws + alloc(ROWS * H_ * 2));
    bf16*  x_bf    = (bf16*) (ws + alloc(ROWS * H_ * 2));
    float* qkv     = (float*)(ws + alloc(3 * ROWS * H_ * 4));
    bf16*  o_bf    = (bf16*) (ws + alloc(ROWS * H_ * 2));
    float* resid   = (float*)(ws + alloc(ROWS * H_ * 4));
    bf16*  ffin_bf = (bf16*) (ws + alloc(ROWS * H_ * 2));
    bf16*  ffh_bf  = (bf16*) (ws + alloc(ROWS * 4 * H_ * 2));
    float* part    = (float*)(ws + alloc(4 * ROWS * H_ * 4));
    float* clspart = (float*)(ws + alloc(4 * 8 * H_ * 4));
    float* ubuf    = (float*)(ws + alloc(ROWS * 8 * 512 * 4));
    float* s2buf   = (float*)(ws + alloc((size_t)B_ * 8 * 64 * 64 * 4));
    bf16*  wc3     = (bf16*) (ws + alloc(KN * 2));
    bf16*  E0      = (bf16*) (ws + alloc(64 * H_ * 2));      // padded to 64 rows
    bf16*  e0w1    = (bf16*) (ws + alloc(64 * H_ * 2));      // padded to 64 rows
    bf16*  e0w12   = (bf16*) (ws + alloc(64 * H_ * 2));
    bf16*  xw1     = (bf16*) (ws + alloc(KN * 2));
    bf16*  xw12    = (bf16*) (ws + alloc(KN * 2));
    bf16*  x2w2    = (bf16*) (ws + alloc(KN * 2));
    float* cw      = (float*)(ws + alloc(6 * PAIRS * 4));    // edge softmax coeffs
    bf16*  bond    = (bf16*) (ws + alloc(PAIRS * H_ * 2));
    bf16*  ew      = (bf16*) (ws + alloc(PAIRS * H_ * 2));
    bf16*  qkvt    = (bf16*) (ws + alloc((size_t)L_ * 3 * KN * 2));
    bf16*  ewt     = (bf16*) (ws + alloc((size_t)L_ * KN * 2));
    bf16*  stackt  = (bf16*) (ws + alloc((size_t)L_ * KN * 2));
    bf16*  f1t     = (bf16*) (ws + alloc((size_t)L_ * 4 * KN * 2));
    bf16*  f2t     = (bf16*) (ws + alloc((size_t)L_ * 4 * KN * 2));
    (void)ws_size;

    float* cw0a = cw;
    float* cw1a = cw + PAIRS;
    float* cw2a = cw + 2 * PAIRS;
    float* cw0b = cw + 3 * PAIRS;
    float* cw1b = cw + 4 * PAIRS;
    float* cw2b = cw + 5 * PAIRS;

    embed_ln_kernel<<<512, 256, 0, stream>>>(ids, atom_emb, xn, xn_bf);

    dim3 tb(32, 8);
    transpose_sq<<<dim3(16, 16, 20), tb, 0, stream>>>(Wq, Wk, Wv, Wew, Wstack,
                                                      qkvt, ewt, stackt);
    transpose_rect<<<dim3(64, 64, 8), tb, 0, stream>>>(Wf1, Wf2, f1t, f2t);

    ew0_precompute<<<dim3(64, 8), 64, 0, stream>>>(bond_emb, ewt, E0);
    cast_w3<<<128, 256, 0, stream>>>(Wew + 3 * KN, wc3);

    for (int l = 0; l < L_; ++l) {
        if (l == 0) {
            mfma_gemm_s<0, false><<<dim3(8, 8, 3), 256, 0, stream>>>(
                xn_bf, qkvt, qkv, nullptr, 512, 512, 512);
            attn_kernel<true><<<dim3(512, 2), dim3(64, 4), 0, stream>>>(qkv, E0, adj, o_bf);
        } else if (l == 1) {
            basis_gemm1<<<dim3(9, 8), 256, 0, stream>>>(x_bf, E0, ewt + KN, xw1, e0w1);
            ew_combine1<<<8192, 256, 0, stream>>>(adj, cw0a, cw1a, cw2a, e0w1, xw1, ew);
            mfma_gemm_s<0, false><<<dim3(8, 8, 3), 256, 0, stream>>>(
                xn_bf, qkvt + (size_t)3 * KN, qkv, nullptr, 512, 512, 512);
            attn_kernel<false><<<dim3(512, 2), dim3(64, 4), 0, stream>>>(qkv, ew, adj, o_bf);
        } else if (l == 2) {
            basis_gemm2<<<dim3(17, 8), 256, 0, stream>>>(xw1, x_bf, e0w1, ewt + 2 * KN,
                                                         xw12, x2w2, e0w12);
            ew_combine2<<<8192, 256, 0, stream>>>(adj, cw0a, cw1a, cw2a, cw0b, cw1b, cw2b,
                                                  e0w12, xw12, x2w2, ew);
            mfma_gemm_s<0, false><<<dim3(8, 8, 3), 256, 0, stream>>>(
                xn_bf, qkvt + (size_t)6 * KN, qkv, nullptr, 512, 512, 512);
            attn_kernel<false><<<dim3(512, 2), dim3(64, 4), 0, stream>>>(qkv, ew, adj, o_bf);
        } else {
            mfma_gemm_s<0, false><<<dim3(8, 8, 3), 256, 0, stream>>>(
                xn_bf, qkvt + (size_t)9 * KN, qkv, nullptr, 512, 512, 512);
            u_gemm<<<dim3(8, 8, 8), 256, 0, stream>>>(qkv, wc3, ubuf);
            s2_kernel<<<512, dim3(64, 4), 0, stream>>>(bond, ubuf, s2buf);
            attn3_kernel<<<dim3(512, 2), dim3(64, 4), 0, stream>>>(qkv, s2buf, adj, o_bf);
        }

        mfma_gemm_s<0, true><<<dim3(8, 8, 4), 256, 0, stream>>>(
            o_bf, stackt + (size_t)l * KN, part, nullptr, 512, 512, 512);
        reduce_stack_ln<<<512, 256, 0, stream>>>(part, xn, resid, ffin_bf);
        mfma_gemm_s<2, false><<<dim3(8, 32), 256, 0, stream>>>(
            ffin_bf, f1t + (size_t)l * 4 * KN, ffh_bf, nullptr, 512, 2048, 512);
        mfma_gemm_s<0, true><<<dim3(8, 8, 4), 256, 0, stream>>>(
            ffh_bf, f2t + (size_t)l * 4 * KN, part, nullptr, 512, 512, 2048);
        if (l < L_ - 1)
            reduce_ln_kernel<true><<<512, 256, 0, stream>>>(part, resid, x, x_bf, xn, xn_bf);
        else
            reduce_ln_kernel<false><<<512, 256, 0, stream>>>(part, resid, x, x_bf, xn, xn_bf);

        if (l == 0)
            edge_coeff_kernel<true><<<8192, dim3(64, 4), 0, stream>>>(
                E0, adj, x, cw0a, cw1a, cw2a);
        else if (l == 1)
            edge_coeff_kernel<false><<<8192, dim3(64, 4), 0, stream>>>(
                ew, adj, x, cw0b, cw1b, cw2b);
        else if (l == 2)
            edge_kernel<<<8192, dim3(64, 4), 0, stream>>>(ew, x, bond);
    }

    cls_part_kernel<<<dim3(8, 8, 4), 256, 0, stream>>>(x, Wout, clspart);
    cls_pred2_kernel<<<8, 256, 0, stream>>>(clspart, Wpred, bpred, (float*)d_out);
}

// Round 3
// 438.031 us; speedup vs baseline: 1.1352x; 1.0585x over previous
//
#include <hip/hip_runtime.h>
#include <hip/hip_bf16.h>

typedef __hip_bfloat16 bf16;

#define B_     8
#define N_     64
#define H_     512
#define HEADS_ 8
#define SP_    64
#define L_     4
static constexpr float INV_SCALE = 0.044194173824159216f; // 1/sqrt(512)

typedef __attribute__((ext_vector_type(8))) short short8;
typedef __attribute__((ext_vector_type(4))) float f32x4;

__device__ __forceinline__ void unpack8(uint4 u, float* f) {
    f[0] = __uint_as_float(u.x << 16); f[1] = __uint_as_float(u.x & 0xffff0000u);
    f[2] = __uint_as_float(u.y << 16); f[3] = __uint_as_float(u.y & 0xffff0000u);
    f[4] = __uint_as_float(u.z << 16); f[5] = __uint_as_float(u.z & 0xffff0000u);
    f[6] = __uint_as_float(u.w << 16); f[7] = __uint_as_float(u.w & 0xffff0000u);
}

__device__ __forceinline__ bf16 f2bf(float v) { return __float2bfloat16(v); }

__device__ __forceinline__ uint4 pack8bf(float4 a, float4 b) {
    __align__(16) bf16 t[8];
    t[0] = f2bf(a.x); t[1] = f2bf(a.y); t[2] = f2bf(a.z); t[3] = f2bf(a.w);
    t[4] = f2bf(b.x); t[5] = f2bf(b.y); t[6] = f2bf(b.z); t[7] = f2bf(b.w);
    return *(const uint4*)t;
}

#define RSTR 80

// ------------------------------------------------------------ GEMM body (64-tile)
// EPI: 0 = fp32 out, 1 = fp32 + residual, 2 = relu->bf16, 3 = bf16
template <int EPI>
__device__ __forceinline__ void gemm64_body(char* lds,
        const bf16* __restrict__ A, const bf16* __restrict__ Bt,
        void* __restrict__ Cv, const float* __restrict__ R,
        int M, int N, int K, int bx, int by, int kbeg, int kend) {
    char* As = lds;
    char* Bs = lds + 2 * 64 * RSTR;
    const int tid = threadIdx.x;
    const int bm = bx * 64, bn = by * 64;
    const int w = tid >> 6, lane = tid & 63;
    const int wr = (w >> 1) * 32, wc = (w & 1) * 32;
    const int m0 = lane & 15, q4 = lane >> 4;

    f32x4 acc[2][2] = {};

    const int rA = tid >> 3;
    const int cA = tid & 7;
    const int ksP = cA >> 2;
    const int cB = (cA & 3) * 16;
    const int cE = cA * 8;

    for (int k0 = kbeg; k0 < kend; k0 += 64) {
        uint4 a0 = *(const uint4*)(A  + (size_t)(bm + rA) * K + k0 + cE);
        uint4 a1 = *(const uint4*)(A  + (size_t)(bm + rA + 32) * K + k0 + cE);
        uint4 b0 = *(const uint4*)(Bt + (size_t)(bn + rA) * K + k0 + cE);
        uint4 b1 = *(const uint4*)(Bt + (size_t)(bn + rA + 32) * K + k0 + cE);
        __syncthreads();
        *(uint4*)(As + ksP * (64 * RSTR) + rA * RSTR + cB) = a0;
        *(uint4*)(As + ksP * (64 * RSTR) + (rA + 32) * RSTR + cB) = a1;
        *(uint4*)(Bs + ksP * (64 * RSTR) + rA * RSTR + cB) = b0;
        *(uint4*)(Bs + ksP * (64 * RSTR) + (rA + 32) * RSTR + cB) = b1;
        __syncthreads();
        short8 af[2][2], bfr[2][2];
        #pragma unroll
        for (int ks = 0; ks < 2; ++ks)
            #pragma unroll
            for (int t = 0; t < 2; ++t) {
                af[ks][t]  = *(const short8*)(As + ks * (64 * RSTR) + (wr + t * 16 + m0) * RSTR + q4 * 16);
                bfr[ks][t] = *(const short8*)(Bs + ks * (64 * RSTR) + (wc + t * 16 + m0) * RSTR + q4 * 16);
            }
        #pragma unroll
        for (int ks = 0; ks < 2; ++ks)
            #pragma unroll
            for (int mt = 0; mt < 2; ++mt)
                #pragma unroll
                for (int nt = 0; nt < 2; ++nt)
                    acc[mt][nt] = __builtin_amdgcn_mfma_f32_16x16x32_bf16(
                        af[ks][mt], bfr[ks][nt], acc[mt][nt], 0, 0, 0);
    }

    if (EPI <= 1) {
        float* C = (float*)Cv;
        #pragma unroll
        for (int mt = 0; mt < 2; ++mt)
            #pragma unroll
            for (int i = 0; i < 4; ++i) {
                int row = bm + wr + mt * 16 + q4 * 4 + i;
                #pragma unroll
                for (int nt = 0; nt < 2; ++nt) {
                    int col = bn + wc + nt * 16 + m0;
                    float v = acc[mt][nt][i];
                    if (EPI == 1) v += R[(size_t)row * N + col];
                    C[(size_t)row * N + col] = v;
                }
            }
    } else {
        bf16* C = (bf16*)Cv;
        #pragma unroll
        for (int mt = 0; mt < 2; ++mt)
            #pragma unroll
            for (int i = 0; i < 4; ++i) {
                int row = bm + wr + mt * 16 + q4 * 4 + i;
                #pragma unroll
                for (int nt = 0; nt < 2; ++nt) {
                    int col = bn + wc + nt * 16 + m0;
                    float v = acc[mt][nt][i];
                    if (EPI == 2) v = fmaxf(v, 0.0f);
                    C[(size_t)row * N + col] = __float2bfloat16(v);
                }
            }
    }
}

template <int EPI, bool SPLIT>
__launch_bounds__(256)
__global__ void mfma_gemm_s(const bf16* __restrict__ A, const bf16* __restrict__ Bt,
                            void* __restrict__ Cv, const float* __restrict__ R,
                            int M, int N, int K) {
    __shared__ __align__(16) char lds[4 * 64 * RSTR];
    int kbeg = 0, kend = K;
    const bf16* B2 = Bt;
    void* C2 = Cv;
    if (SPLIT) {
        int ks = K / gridDim.z;
        kbeg = blockIdx.z * ks;
        kend = kbeg + ks;
        C2 = (void*)((float*)Cv + (size_t)blockIdx.z * M * N);
        gemm64_body<0>(lds, A, B2, C2, nullptr, M, N, K, blockIdx.x, blockIdx.y, kbeg, kend);
    } else {
        B2 = Bt + (size_t)blockIdx.z * N * K;
        if (EPI <= 1) C2 = (void*)((float*)Cv + (size_t)blockIdx.z * M * N);
        gemm64_body<EPI>(lds, A, B2, C2, R, M, N, K, blockIdx.x, blockIdx.y, kbeg, kend);
    }
}

// ------------------------------------------------ factored-ew basis GEMMs
// l=1: bx<8 -> XW1 = x_bf @ Wew1 ; bx==8 -> E0W1 = E0pad @ Wew1
__launch_bounds__(256)
__global__ void basis_gemm1(const bf16* __restrict__ x_bf, const bf16* __restrict__ E0,
                            const bf16* __restrict__ ewt1,
                            bf16* __restrict__ xw1, bf16* __restrict__ e0w1) {
    __shared__ __align__(16) char lds[4 * 64 * RSTR];
    if (blockIdx.x < 8)
        gemm64_body<3>(lds, x_bf, ewt1, xw1, nullptr, 512, 512, 512,
                       blockIdx.x, blockIdx.y, 0, 512);
    else
        gemm64_body<3>(lds, E0, ewt1, e0w1, nullptr, 64, 512, 512,
                       0, blockIdx.y, 0, 512);
}

// l=2: bx<8 -> XW12 = xw1 @ Wew2 ; bx<16 -> X2W2 = x_bf @ Wew2 ; bx==16 -> E0W12 = e0w1 @ Wew2
__launch_bounds__(256)
__global__ void basis_gemm2(const bf16* __restrict__ xw1, const bf16* __restrict__ x_bf,
                            const bf16* __restrict__ e0w1, const bf16* __restrict__ ewt2,
                            bf16* __restrict__ xw12, bf16* __restrict__ x2w2,
                            bf16* __restrict__ e0w12) {
    __shared__ __align__(16) char lds[4 * 64 * RSTR];
    if (blockIdx.x < 8)
        gemm64_body<3>(lds, xw1, ewt2, xw12, nullptr, 512, 512, 512,
                       blockIdx.x, blockIdx.y, 0, 512);
    else if (blockIdx.x < 16)
        gemm64_body<3>(lds, x_bf, ewt2, x2w2, nullptr, 512, 512, 512,
                       blockIdx.x - 8, blockIdx.y, 0, 512);
    else
        gemm64_body<3>(lds, e0w1, ewt2, e0w12, nullptr, 64, 512, 512,
                       0, blockIdx.y, 0, 512);
}

// ew1[p] = c0*E0W1[adj[p]] + c1*XW1[i] + c2*XW1[j]      (grid 8192 x 256)
__launch_bounds__(256)
__global__ void ew_combine1(const int* __restrict__ adj,
                            const float* __restrict__ c0, const float* __restrict__ c1,
                            const float* __restrict__ c2,
                            const bf16* __restrict__ e0w1, const bf16* __restrict__ xw1,
                            bf16* __restrict__ ew) {
    int gid = blockIdx.x * 256 + threadIdx.x;
    int pair = gid >> 6;
    int c8 = (gid & 63) * 8;
    int b  = pair >> 12;
    int ri = pair >> 6;                 // b*64+i
    int rj = (b << 6) | (pair & 63);    // b*64+j
    float a = c0[pair], bb = c1[pair], cc = c2[pair];
    int t = adj[pair];
    uint4 ue = *(const uint4*)(e0w1 + (size_t)t  * H_ + c8);
    uint4 ui = *(const uint4*)(xw1  + (size_t)ri * H_ + c8);
    uint4 uj = *(const uint4*)(xw1  + (size_t)rj * H_ + c8);
    float fe[8], fi[8], fj[8];
    unpack8(ue, fe); unpack8(ui, fi); unpack8(uj, fj);
    __align__(16) bf16 o[8];
    #pragma unroll
    for (int k = 0; k < 8; ++k)
        o[k] = f2bf(a * fe[k] + bb * fi[k] + cc * fj[k]);
    *(uint4*)(ew + (size_t)pair * H_ + c8) = *(const uint4*)o;
}

// ew2[p] = v0*u0*E0W12[adj] + v0*u1*XW12[i] + v0*u2*XW12[j] + v1*X2W2[i] + v2*X2W2[j]
__launch_bounds__(256)
__global__ void ew_combine2(const int* __restrict__ adj,
                            const float* __restrict__ u0, const float* __restrict__ u1,
                            const float* __restrict__ u2,
                            const float* __restrict__ v0, const float* __restrict__ v1,
                            const float* __restrict__ v2,
                            const bf16* __restrict__ e0w12, const bf16* __restrict__ xw12,
                            const bf16* __restrict__ x2w2, bf16* __restrict__ ew) {
    int gid = blockIdx.x * 256 + threadIdx.x;
    int pair = gid >> 6;
    int c8 = (gid & 63) * 8;
    int b  = pair >> 12;
    int ri = pair >> 6;
    int rj = (b << 6) | (pair & 63);
    float a0 = v0[pair];
    float cE = a0 * u0[pair], ci = a0 * u1[pair], cj = a0 * u2[pair];
    float di = v1[pair], dj = v2[pair];
    int t = adj[pair];
    uint4 ue = *(const uint4*)(e0w12 + (size_t)t  * H_ + c8);
    uint4 ua = *(const uint4*)(xw12  + (size_t)ri * H_ + c8);
    uint4 ub = *(const uint4*)(xw12  + (size_t)rj * H_ + c8);
    uint4 uc = *(const uint4*)(x2w2  + (size_t)ri * H_ + c8);
    uint4 ud = *(const uint4*)(x2w2  + (size_t)rj * H_ + c8);
    float fe[8], fa[8], fb[8], fc[8], fd[8];
    unpack8(ue, fe); unpack8(ua, fa); unpack8(ub, fb); unpack8(uc, fc); unpack8(ud, fd);
    __align__(16) bf16 o[8];
    #pragma unroll
    for (int k = 0; k < 8; ++k)
        o[k] = f2bf(cE * fe[k] + ci * fa[k] + cj * fb[k] + di * fc[k] + dj * fd[k]);
    *(uint4*)(ew + (size_t)pair * H_ + c8) = *(const uint4*)o;
}

// ---------------------- layer-3 implicit path
// u_bf[b,i,h,k] = sum_d q[b,i,h*64+d] * Wew3[k, h*64+d]   (bf16 out)
__launch_bounds__(256)
__global__ void u_gemm(const float* __restrict__ q, const bf16* __restrict__ wc3,
                       bf16* __restrict__ ubf) {
    __shared__ __align__(16) char lds[4 * 64 * RSTR];
    char* As = lds;
    char* Bs = lds + 2 * 64 * RSTR;
    const int h = blockIdx.x, mb = blockIdx.y, nb = blockIdx.z;
    const int tid = threadIdx.x;
    const int w = tid >> 6, lane = tid & 63;
    const int wr = (w >> 1) * 32, wc = (w & 1) * 32;
    const int m0 = lane & 15, q4 = lane >> 4;
    const int rA = tid >> 3;
    const int cA = tid & 7;
    const int ksP = cA >> 2;
    const int cB = (cA & 3) * 16;
    const int cE = cA * 8;

    const float* Aq = q + (size_t)(mb * 64) * 512 + h * 64;
    const bf16*  Bt = wc3 + (size_t)(nb * 64) * 512 + h * 64;

    float4 fa0 = *(const float4*)(Aq + (size_t)rA * 512 + cE);
    float4 fa1 = *(const float4*)(Aq + (size_t)rA * 512 + cE + 4);
    float4 fb0 = *(const float4*)(Aq + (size_t)(rA + 32) * 512 + cE);
    float4 fb1 = *(const float4*)(Aq + (size_t)(rA + 32) * 512 + cE + 4);
    uint4 b0 = *(const uint4*)(Bt + (size_t)rA * 512 + cE);
    uint4 b1 = *(const uint4*)(Bt + (size_t)(rA + 32) * 512 + cE);
    uint4 a0 = pack8bf(fa0, fa1);
    uint4 a1 = pack8bf(fb0, fb1);
    *(uint4*)(As + ksP * (64 * RSTR) + rA * RSTR + cB) = a0;
    *(uint4*)(As + ksP * (64 * RSTR) + (rA + 32) * RSTR + cB) = a1;
    *(uint4*)(Bs + ksP * (64 * RSTR) + rA * RSTR + cB) = b0;
    *(uint4*)(Bs + ksP * (64 * RSTR) + (rA + 32) * RSTR + cB) = b1;
    __syncthreads();

    f32x4 acc[2][2] = {};
    short8 af[2][2], bfr[2][2];
    #pragma unroll
    for (int ks = 0; ks < 2; ++ks)
        #pragma unroll
        for (int t = 0; t < 2; ++t) {
            af[ks][t]  = *(const short8*)(As + ks * (64 * RSTR) + (wr + t * 16 + m0) * RSTR + q4 * 16);
            bfr[ks][t] = *(const short8*)(Bs + ks * (64 * RSTR) + (wc + t * 16 + m0) * RSTR + q4 * 16);
        }
    #pragma unroll
    for (int ks = 0; ks < 2; ++ks)
        #pragma unroll
        for (int mt = 0; mt < 2; ++mt)
            #pragma unroll
            for (int nt = 0; nt < 2; ++nt)
                acc[mt][nt] = __builtin_amdgcn_mfma_f32_16x16x32_bf16(
                    af[ks][mt], bfr[ks][nt], acc[mt][nt], 0, 0, 0);

    #pragma unroll
    for (int mt = 0; mt < 2; ++mt)
        #pragma unroll
        for (int i = 0; i < 4; ++i) {
            int row = mb * 64 + wr + mt * 16 + q4 * 4 + i;
            #pragma unroll
            for (int nt = 0; nt < 2; ++nt) {
                int col = nb * 64 + wc + nt * 16 + m0;
                ubf[(size_t)row * 4096 + h * 512 + col] = f2bf(acc[mt][nt][i]);
            }
        }
}

__global__ void cast_w3(const float* __restrict__ in, bf16* __restrict__ out) {
    int gid = blockIdx.x * 256 + threadIdx.x;
    const float4* p = (const float4*)(in + (size_t)gid * 8);
    float4 a = p[0], b = p[1];
    *(uint4*)(out + (size_t)gid * 8) = pack8bf(a, b);
}

// M-tables: for each b, U_b (512 rows (i,h) x 512 k) @ basis_b^T (64 x 512)
//   z=0: XW12[b] -> MX ; z=1: X2W2[b] -> MY ; z=2: x2_bf[b] -> MZ ; z=3: e0w12 (shared) -> DE
__launch_bounds__(256)
__global__ void mbuf_gemm(const bf16* __restrict__ ubf, const bf16* __restrict__ xw12,
                          const bf16* __restrict__ x2w2, const bf16* __restrict__ x_bf,
                          const bf16* __restrict__ e0w12,
                          float* __restrict__ MX, float* __restrict__ MY,
                          float* __restrict__ MZ, float* __restrict__ DE) {
    __shared__ __align__(16) char lds[4 * 64 * RSTR];
    int b = blockIdx.x, mt = blockIdx.y, z = blockIdx.z;
    const bf16* A = ubf + (size_t)b * 512 * 512;
    const bf16* Bt;
    float* C;
    if (z == 0)      { Bt = xw12 + (size_t)b * 64 * 512; C = MX + (size_t)b * 512 * 64; }
    else if (z == 1) { Bt = x2w2 + (size_t)b * 64 * 512; C = MY + (size_t)b * 512 * 64; }
    else if (z == 2) { Bt = x_bf + (size_t)b * 64 * 512; C = MZ + (size_t)b * 512 * 64; }
    else             { Bt = e0w12;                        C = DE + (size_t)b * 512 * 64; }
    gemm64_body<0>(lds, A, Bt, C, nullptr, 512, 64, 512, mt, 0, 0, 512);
}

// s2[b,h,i,j] = AE*DE[adj] + Aa*MX[i] + Ac*MY[i] + Ae*MZ[i] + Ab*MX[j] + Ad*MY[j] + Af*MZ[j]
//   (all M-tables indexed at row (b,i,h))
__global__ void s2_assemble(const int* __restrict__ adj,
        const float* __restrict__ c0a, const float* __restrict__ c1a, const float* __restrict__ c2a,
        const float* __restrict__ c0b, const float* __restrict__ c1b, const float* __restrict__ c2b,
        const float* __restrict__ v0c, const float* __restrict__ v1c, const float* __restrict__ v2c,
        const float* __restrict__ MX, const float* __restrict__ MY,
        const float* __restrict__ MZ, const float* __restrict__ DE,
        float* __restrict__ s2) {
    int bi = blockIdx.x;
    int b = bi >> 6, i = bi & 63;
    int j = threadIdx.x, h = threadIdx.y;
    int p = bi * 64 + j;
    float v0 = v0c[p];
    float q0 = v0 * c0b[p];
    float AE = q0 * c0a[p], Aa = q0 * c1a[p], Ab = q0 * c2a[p];
    float Ac = v0 * c1b[p], Ad = v0 * c2b[p];
    float Ae = v1c[p], Af = v2c[p];
    size_t rb = ((size_t)b * 512 + i * 8 + h) * 64;
    float s = AE * DE[rb + adj[p]]
            + Aa * MX[rb + i] + Ac * MY[rb + i] + Ae * MZ[rb + i]
            + Ab * MX[rb + j] + Ad * MY[rb + j] + Af * MZ[rb + j];
    s2[(((size_t)b * 8 + h) * 64 + i) * 64 + j] = s;
}

// ---------------------------------------------------------------- embeddings
__global__ void embed_ln_kernel(const int* __restrict__ ids,
                                const float* __restrict__ emb,
                                float* __restrict__ xn, bf16* __restrict__ xn_bf) {
    int row = blockIdx.x;
    int tid = threadIdx.x;
    const float* r = emb + (size_t)ids[row] * H_;
    float x0 = r[tid], x1 = r[tid + 256];
    float s = x0 + x1, sq = x0 * x0 + x1 * x1;
    #pragma unroll
    for (int off = 32; off; off >>= 1) {
        s  += __shfl_xor(s,  off);
        sq += __shfl_xor(sq, off);
    }
    __shared__ float ls[4], lq[4];
    int w = tid >> 6;
    if ((tid & 63) == 0) { ls[w] = s; lq[w] = sq; }
    __syncthreads();
    float S = ls[0] + ls[1] + ls[2] + ls[3];
    float Q = lq[0] + lq[1] + lq[2] + lq[3];
    float mean = S * (1.0f / H_);
    float var  = Q * (1.0f / H_) - mean * mean;
    float inv  = rsqrtf(var + 1e-5f);
    float y0 = (x0 - mean) * inv, y1 = (x1 - mean) * inv;
    xn[(size_t)row * H_ + tid]       = y0;
    xn[(size_t)row * H_ + tid + 256] = y1;
    xn_bf[(size_t)row * H_ + tid]       = f2bf(y0);
    xn_bf[(size_t)row * H_ + tid + 256] = f2bf(y1);
}

// E0 padded to 64 rows: rows 8..63 zeroed (basis GEMMs read the full 64-row tile)
__global__ void ew0_precompute(const float* __restrict__ bond_emb,
                               const bf16* __restrict__ ewt0, bf16* __restrict__ E0) {
    int t = blockIdx.x, cb = blockIdx.y, lane = threadIdx.x;
    int c = cb * 64 + lane;
    if (t >= 8) { E0[t * 512 + c] = f2bf(0.0f); return; }
    __shared__ float be[512];
    for (int h = lane; h < 512; h += 64) be[h] = bond_emb[t * 512 + h];
    __syncthreads();
    const bf16* wr = ewt0 + (size_t)c * 512;
    float acc = 0.f;
    for (int h8 = 0; h8 < 64; ++h8) {
        uint4 u = *(const uint4*)(wr + h8 * 8);
        float wf[8];
        unpack8(u, wf);
        const float* b = &be[h8 * 8];
        acc += b[0]*wf[0] + b[1]*wf[1] + b[2]*wf[2] + b[3]*wf[3]
             + b[4]*wf[4] + b[5]*wf[5] + b[6]*wf[6] + b[7]*wf[7];
    }
    E0[t * 512 + c] = f2bf(acc);
}

// ------------------------------------------------- weight transpose + cast
__global__ void transpose_sq(const float* __restrict__ Wq, const float* __restrict__ Wk,
                             const float* __restrict__ Wv, const float* __restrict__ Wew,
                             const float* __restrict__ Wst,
                             bf16* __restrict__ qkvt, bf16* __restrict__ ewt,
                             bf16* __restrict__ stackt) {
    const size_t KN = (size_t)H_ * H_;
    int z = blockIdx.z;
    const float* W; bf16* Wt;
    if (z < 12) {
        int s = z >> 2, l = z & 3;
        W  = (s == 0 ? Wq : s == 1 ? Wk : Wv) + (size_t)l * KN;
        Wt = qkvt + (size_t)l * 3 * KN + (size_t)s * KN;
    } else if (z < 16) {
        int l = z - 12;
        W = Wew + (size_t)l * KN; Wt = ewt + (size_t)l * KN;
    } else {
        int l = z - 16;
        W = Wst + (size_t)l * KN; Wt = stackt + (size_t)l * KN;
    }
    __shared__ float t[32][33];
    int k0 = blockIdx.x * 32, n0 = blockIdx.y * 32;
    int tx = threadIdx.x, ty = threadIdx.y;
    #pragma unroll
    for (int r = ty; r < 32; r += 8)
        t[r][tx] = W[(size_t)(k0 + r) * H_ + n0 + tx];
    __syncthreads();
    #pragma unroll
    for (int r = ty; r < 32; r += 8)
        Wt[(size_t)(n0 + r) * H_ + k0 + tx] = f2bf(t[tx][r]);
}

__global__ void transpose_rect(const float* __restrict__ Wf1, const float* __restrict__ Wf2,
                               bf16* __restrict__ f1t, bf16* __restrict__ f2t) {
    const size_t KN4 = (size_t)4 * H_ * H_;
    int z = blockIdx.z;
    const float* W; bf16* Wt; int K, N;
    if (z < 4) {
        if (blockIdx.x >= 16) return;
        W = Wf1 + (size_t)z * KN4; Wt = f1t + (size_t)z * KN4; K = 512; N = 2048;
    } else {
        if (blockIdx.y >= 16) return;
        W = Wf2 + (size_t)(z - 4) * KN4; Wt = f2t + (size_t)(z - 4) * KN4; K = 2048; N = 512;
    }
    __shared__ float t[32][33];
    int k0 = blockIdx.x * 32, n0 = blockIdx.y * 32;
    int tx = threadIdx.x, ty = threadIdx.y;
    #pragma unroll
    for (int r = ty; r < 32; r += 8)
        t[r][tx] = W[(size_t)(k0 + r) * N + n0 + tx];
    __syncthreads();
    #pragma unroll
    for (int r = ty; r < 32; r += 8)
        Wt[(size_t)(n0 + r) * K + k0 + tx] = f2bf(t[tx][r]);
}

// ---------------------- split-K reduce + residual + LN variants
__global__ void reduce_stack_ln(const float* __restrict__ part, const float* __restrict__ base,
                                float* __restrict__ resid, bf16* __restrict__ ffin_bf) {
    const int MN = 512 * H_;
    int row = blockIdx.x;
    int tid = threadIdx.x;
    size_t b0 = (size_t)row * H_;
    float v0 = base[b0 + tid], v1 = base[b0 + tid + 256];
    #pragma unroll
    for (int s = 0; s < 4; ++s) {
        v0 += part[(size_t)s * MN + b0 + tid];
        v1 += part[(size_t)s * MN + b0 + tid + 256];
    }
    resid[b0 + tid] = v0;
    resid[b0 + tid + 256] = v1;
    float s = v0 + v1, sq = v0 * v0 + v1 * v1;
    #pragma unroll
    for (int off = 32; off; off >>= 1) {
        s  += __shfl_xor(s,  off);
        sq += __shfl_xor(sq, off);
    }
    __shared__ float ls[4], lq[4];
    int w = tid >> 6;
    if ((tid & 63) == 0) { ls[w] = s; lq[w] = sq; }
    __syncthreads();
    float S = ls[0] + ls[1] + ls[2] + ls[3];
    float Q = lq[0] + lq[1] + lq[2] + lq[3];
    float mean = S * (1.0f / H_);
    float var  = Q * (1.0f / H_) - mean * mean;
    float inv  = rsqrtf(var + 1e-5f);
    ffin_bf[b0 + tid]       = f2bf((v0 - mean) * inv);
    ffin_bf[b0 + tid + 256] = f2bf((v1 - mean) * inv);
}

template <bool DO_LN>
__global__ void reduce_ln_kernel(const float* __restrict__ part, const float* __restrict__ resid,
                                 float* __restrict__ x, bf16* __restrict__ x_bf,
                                 float* __restrict__ xn, bf16* __restrict__ xn_bf) {
    const int MN = 512 * H_;
    int row = blockIdx.x;
    int tid = threadIdx.x;
    size_t base = (size_t)row * H_;
    float v0 = resid[base + tid], v1 = resid[base + tid + 256];
    #pragma unroll
    for (int s = 0; s < 4; ++s) {
        v0 += part[(size_t)s * MN + base + tid];
        v1 += part[(size_t)s * MN + base + tid + 256];
    }
    x[base + tid] = v0;
    x[base + tid + 256] = v1;
    x_bf[base + tid]       = f2bf(v0);
    x_bf[base + tid + 256] = f2bf(v1);
    if (DO_LN) {
        float s = v0 + v1, sq = v0 * v0 + v1 * v1;
        #pragma unroll
        for (int off = 32; off; off >>= 1) {
            s  += __shfl_xor(s,  off);
            sq += __shfl_xor(sq, off);
        }
        __shared__ float ls[4], lq[4];
        int w = tid >> 6;
        if ((tid & 63) == 0) { ls[w] = s; lq[w] = sq; }
        __syncthreads();
        float S = ls[0] + ls[1] + ls[2] + ls[3];
        float Q = lq[0] + lq[1] + lq[2] + lq[3];
        float mean = S * (1.0f / H_);
        float var  = Q * (1.0f / H_) - mean * mean;
        float inv  = rsqrtf(var + 1e-5f);
        float y0 = (v0 - mean) * inv, y1 = (v1 - mean) * inv;
        xn[base + tid]       = y0;
        xn[base + tid + 256] = y1;
        xn_bf[base + tid]       = f2bf(y0);
        xn_bf[base + tid + 256] = f2bf(y1);
    }
}

// ---------------------------------------------------------------- attention
// GATHER: read per-pair w-row from E0[adj[pair]] (l=0) instead of materialized ew
template <bool GATHER>
__global__ void attn_kernel(const float* __restrict__ qkv, const bf16* __restrict__ ew,
                            const int* __restrict__ adj, bf16* __restrict__ o) {
    const float* q = qkv;
    const float* k = qkv + (size_t)512 * H_;
    const float* v = qkv + (size_t)1024 * H_;
    int bi = blockIdx.x;
    int b  = bi >> 6;
    int ty = threadIdx.y;
    int h  = blockIdx.y * 4 + ty;
    int lane = threadIdx.x;
    __shared__ float qs[4][64], as[4][64];
    qs[ty][lane] = q[(size_t)bi * H_ + h * 64 + lane];
    __syncthreads();

    int j = lane;
    int pair = bi * 64 + j;
    int aj = adj[pair];
    const float4* k4 = (const float4*)(k + (size_t)(b * 64 + j) * H_ + h * 64);
    const uint4*  w4 = (const uint4*)((GATHER ? ew + (size_t)aj * H_
                                              : ew + (size_t)pair * H_) + h * 64);
    float acc = 0.f;
    #pragma unroll
    for (int t = 0; t < 8; ++t) {
        uint4 wu = w4[t];
        float4 ka = k4[2 * t], kb = k4[2 * t + 1];
        float wf[8];
        unpack8(wu, wf);
        const float* qq = &qs[ty][t * 8];
        acc += qq[0] * (ka.x + wf[0]) + qq[1] * (ka.y + wf[1])
             + qq[2] * (ka.z + wf[2]) + qq[3] * (ka.w + wf[3])
             + qq[4] * (kb.x + wf[4]) + qq[5] * (kb.y + wf[5])
             + qq[6] * (kb.z + wf[6]) + qq[7] * (kb.w + wf[7]);
    }
    float logit = acc * INV_SCALE;
    if (aj <= 0) logit = -INFINITY;

    float m = logit;
    #pragma unroll
    for (int off = 32; off; off >>= 1) m = fmaxf(m, __shfl_xor(m, off));
    float p = expf(logit - m);
    float s = p;
    #pragma unroll
    for (int off = 32; off; off >>= 1) s += __shfl_xor(s, off);
    as[ty][lane] = p / s;
    __syncthreads();

    const float* vbase = v + (size_t)(b * 64) * H_ + h * 64;
    float oacc = 0.f;
    int d = lane;
    #pragma unroll 8
    for (int jj = 0; jj < 64; ++jj)
        oacc += as[ty][jj] * vbase[(size_t)jj * H_ + d];
    o[(size_t)bi * H_ + h * 64 + d] = __float2bfloat16(oacc);
}

// layer-3 variant: w-term from precomputed s2 (no ew)
__global__ void attn3_kernel(const float* __restrict__ qkv, const float* __restrict__ s2,
                             const int* __restrict__ adj, bf16* __restrict__ o) {
    const float* q = qkv;
    const float* k = qkv + (size_t)512 * H_;
    const float* v = qkv + (size_t)1024 * H_;
    int bi = blockIdx.x;
    int b  = bi >> 6, i = bi & 63;
    int ty = threadIdx.y;
    int h  = blockIdx.y * 4 + ty;
    int lane = threadIdx.x;
    __shared__ float qs[4][64], as[4][64];
    qs[ty][lane] = q[(size_t)bi * H_ + h * 64 + lane];
    __syncthreads();

    int j = lane;
    const float4* k4 = (const float4*)(k + (size_t)(b * 64 + j) * H_ + h * 64);
    float acc = s2[(((size_t)b * 8 + h) * 64 + i) * 64 + j];
    #pragma unroll
    for (int t = 0; t < 8; ++t) {
        float4 ka = k4[2 * t], kb = k4[2 * t + 1];
        const float* qq = &qs[ty][t * 8];
        acc += qq[0] * ka.x + qq[1] * ka.y + qq[2] * ka.z + qq[3] * ka.w
             + qq[4] * kb.x + qq[5] * kb.y + qq[6] * kb.z + qq[7] * kb.w;
    }
    float logit = acc * INV_SCALE;
    if (adj[(size_t)bi * 64 + j] <= 0) logit = -INFINITY;

    float m = logit;
    #pragma unroll
    for (int off = 32; off; off >>= 1) m = fmaxf(m, __shfl_xor(m, off));
    float p = expf(logit - m);
    float s = p;
    #pragma unroll
    for (int off = 32; off; off >>= 1) s += __shfl_xor(s, off);
    as[ty][lane] = p / s;
    __syncthreads();

    const float* vbase = v + (size_t)(b * 64) * H_ + h * 64;
    float oacc = 0.f;
    int d = lane;
    #pragma unroll 8
    for (int jj = 0; jj < 64; ++jj)
        oacc += as[ty][jj] * vbase[(size_t)jj * H_ + d];
    o[(size_t)bi * H_ + h * 64 + d] = __float2bfloat16(oacc);
}

// ---------------------------------------------------------------- edge coeffs
// emits softmax weights (w0,w1,w2) per pair; no bond materialization.
// GATHER: read ew row from E0[adj[pair]] (l=0).
template <bool GATHER>
__global__ void edge_coeff_kernel(const bf16* __restrict__ ewsrc, const int* __restrict__ adj,
                                  const float* __restrict__ x,
                                  float* __restrict__ w0o, float* __restrict__ w1o,
                                  float* __restrict__ w2o) {
    int pair = blockIdx.x * 4 + threadIdx.y;
    int b = pair >> 12;
    int i = (pair >> 6) & 63;
    int j = pair & 63;
    int lane = threadIdx.x;
    const uint4*  e4  = (const uint4*)(GATHER ? ewsrc + (size_t)adj[pair] * H_
                                              : ewsrc + (size_t)pair * H_);
    const float4* xi4 = (const float4*)(x + (size_t)(b * 64 + i) * H_);
    const float4* xj4 = (const float4*)(x + (size_t)(b * 64 + j) * H_);
    uint4  eu = e4[lane];
    float4 a0 = xi4[lane * 2], a1 = xi4[lane * 2 + 1];
    float4 c0 = xj4[lane * 2], c1 = xj4[lane * 2 + 1];
    float ef[8], af[8], cf[8];
    unpack8(eu, ef);
    af[0] = a0.x; af[1] = a0.y; af[2] = a0.z; af[3] = a0.w;
    af[4] = a1.x; af[5] = a1.y; af[6] = a1.z; af[7] = a1.w;
    cf[0] = c0.x; cf[1] = c0.y; cf[2] = c0.z; cf[3] = c0.w;
    cf[4] = c1.x; cf[5] = c1.y; cf[6] = c1.z; cf[7] = c1.w;
    float s0 = 0.f, s1 = 0.f, s2 = 0.f;
    #pragma unroll
    for (int t = 0; t < 8; ++t) {
        s0 += ef[t] * ef[t]; s1 += ef[t] * af[t]; s2 += ef[t] * cf[t];
    }
    #pragma unroll
    for (int off = 32; off; off >>= 1) {
        s0 += __shfl_xor(s0, off);
        s1 += __shfl_xor(s1, off);
        s2 += __shfl_xor(s2, off);
    }
    float t0 = s0 * INV_SCALE, t1 = s1 * INV_SCALE, t2 = s2 * INV_SCALE;
    float m = fmaxf(t0, fmaxf(t1, t2));
    float e0 = expf(t0 - m), e1 = expf(t1 - m), e2 = expf(t2 - m);
    float inv = 1.0f / (e0 + e1 + e2);
    if (lane == 0) {
        w0o[pair] = e0 * inv;
        w1o[pair] = e1 * inv;
        w2o[pair] = e2 * inv;
    }
}

// ---------------------------------------------------------------- head
__global__ void cls_part_kernel(const float* __restrict__ x, const float* __restrict__ Wout,
                                float* __restrict__ clspart) {
    int b  = blockIdx.x;
    int cb = blockIdx.y;
    int ks = blockIdx.z;
    int tid = threadIdx.x;
    int c  = cb * 64 + (tid & 63);
    int kk = tid >> 6;
    const float* xr = x + (size_t)(b * 64) * H_;
    int h0 = ks * 128 + kk * 32;
    float acc = 0.f;
    #pragma unroll
    for (int h = 0; h < 32; ++h)
        acc += xr[h0 + h] * Wout[(size_t)(h0 + h) * H_ + c];
    __shared__ float red[4][64];
    red[kk][tid & 63] = acc;
    __syncthreads();
    if (tid < 64) {
        float v = red[0][tid] + red[1][tid] + red[2][tid] + red[3][tid];
        clspart[((size_t)ks * 8 + b) * H_ + cb * 64 + tid] = v;
    }
}

__global__ void cls_pred2_kernel(const float* __restrict__ clspart,
                                 const float* __restrict__ Wpred,
                                 const float* __restrict__ bpred,
                                 float* __restrict__ out) {
    int b = blockIdx.x;
    int tid = threadIdx.x;
    __shared__ float red0[4], red1[4];
    float a0 = 0.f, a1 = 0.f;
    #pragma unroll
    for (int t = 0; t < 2; ++t) {
        int c = tid + t * 256;
        float v = clspart[((size_t)0 * 8 + b) * H_ + c]
                + clspart[((size_t)1 * 8 + b) * H_ + c]
                + clspart[((size_t)2 * 8 + b) * H_ + c]
                + clspart[((size_t)3 * 8 + b) * H_ + c];
        float tv = tanhf(v);
        a0 += tv * Wpred[c * 2 + 0];
        a1 += tv * Wpred[c * 2 + 1];
    }
    #pragma unroll
    for (int off = 32; off; off >>= 1) {
        a0 += __shfl_xor(a0, off);
        a1 += __shfl_xor(a1, off);
    }
    int w = tid >> 6;
    if ((tid & 63) == 0) { red0[w] = a0; red1[w] = a1; }
    __syncthreads();
    if (tid == 0) {
        float s0 = red0[0] + red0[1] + red0[2] + red0[3] + bpred[0];
        float s1 = red1[0] + red1[1] + red1[2] + red1[3] + bpred[1];
        float m = fmaxf(s0, s1);
        float e0 = expf(s0 - m), e1 = expf(s1 - m);
        float inv = 1.0f / (e0 + e1);
        out[b * 2 + 0] = e0 * inv;
        out[b * 2 + 1] = e1 * inv;
    }
}

// ---------------------------------------------------------------- launch
extern "C" void kernel_launch(void* const* d_in, const int* in_sizes, int n_in,
                              void* d_out, int out_size, void* d_ws, size_t ws_size,
                              hipStream_t stream) {
    const int*   ids      = (const int*)d_in[0];
    const int*   adj      = (const int*)d_in[1];
    const float* atom_emb = (const float*)d_in[2];
    const float* bond_emb = (const float*)d_in[3];
    const float* Wq     = (const float*)d_in[4];
    const float* Wk     = (const float*)d_in[5];
    const float* Wv     = (const float*)d_in[6];
    const float* Wew    = (const float*)d_in[7];
    const float* Wstack = (const float*)d_in[8];
    const float* Wf1    = (const float*)d_in[9];
    const float* Wf2    = (const float*)d_in[10];
    const float* Wout   = (const float*)d_in[11];
    const float* Wpred  = (const float*)d_in[12];
    const float* bpred  = (const float*)d_in[13];

    char* ws = (char*)d_ws;
    size_t off = 0;
    auto alloc = [&](size_t bytes) {
        size_t o = off;
        off += (bytes + 255) & ~(size_t)255;
        return o;
    };
    const size_t ROWS  = (size_t)B_ * N_;
    const size_t PAIRS = (size_t)B_ * N_ * N_;
    const size_t KN    = (size_t)H_ * H_;

    float* x       = (float*)(ws + alloc(ROWS * H_ * 4));
    float* xn      = (float*)(ws + alloc(ROWS * H_ * 4));
    bf16*  xn_bf   = (bf16*) (ws + alloc(ROWS * H_ * 2));
    bf16*  x_bf    = (bf16*) (ws + alloc(ROWS * H_ * 2));
    float* qkv     = (float*)(ws + alloc(3 * ROWS * H_ * 4));
    bf16*  o_bf    = (bf16*) (ws + alloc(ROWS * H_ * 2));
    float* resid   = (float*)(ws + alloc(ROWS * H_ * 4));
    bf16*  ffin_bf = (bf16*) (ws + alloc(ROWS * H_ * 2));
    bf16*  ffh_bf  = (bf16*) (ws + alloc(ROWS * 4 * H_ * 2));
    float* part    = (float*)(ws + alloc(4 * ROWS * H_ * 4));
    float* clspart = (float*)(ws + alloc(4 * 8 * H_ * 4));
    bf16*  ubf     = (bf16*) (ws + alloc(ROWS * 8 * 512 * 2));           // 4 MB
    float* s2buf   = (float*)(ws + alloc((size_t)B_ * 8 * 64 * 64 * 4)); // 1 MB
    float* MX      = (float*)(ws + alloc((size_t)4096 * 64 * 4));        // 1 MB
    float* MY      = (float*)(ws + alloc((size_t)4096 * 64 * 4));
    float* MZ      = (float*)(ws + alloc((size_t)4096 * 64 * 4));
    float* DE      = (float*)(ws + alloc((size_t)4096 * 64 * 4));
    bf16*  wc3     = (bf16*) (ws + alloc(KN * 2));
    bf16*  E0      = (bf16*) (ws + alloc(64 * H_ * 2));      // padded to 64 rows
    bf16*  e0w1    = (bf16*) (ws + alloc(64 * H_ * 2));
    bf16*  e0w12   = (bf16*) (ws + alloc(64 * H_ * 2));
    bf16*  xw1     = (bf16*) (ws + alloc(KN * 2));
    bf16*  xw12    = (bf16*) (ws + alloc(KN * 2));
    bf16*  x2w2    = (bf16*) (ws + alloc(KN * 2));
    float* cw      = (float*)(ws + alloc(9 * PAIRS * 4));    // edge softmax coeffs
    bf16*  ew      = (bf16*) (ws + alloc(PAIRS * H_ * 2));
    bf16*  qkvt    = (bf16*) (ws + alloc((size_t)L_ * 3 * KN * 2));
    bf16*  ewt     = (bf16*) (ws + alloc((size_t)L_ * KN * 2));
    bf16*  stackt  = (bf16*) (ws + alloc((size_t)L_ * KN * 2));
    bf16*  f1t     = (bf16*) (ws + alloc((size_t)L_ * 4 * KN * 2));
    bf16*  f2t     = (bf16*) (ws + alloc((size_t)L_ * 4 * KN * 2));
    (void)ws_size;

    float* cw0a = cw;
    float* cw1a = cw + PAIRS;
    float* cw2a = cw + 2 * PAIRS;
    float* cw0b = cw + 3 * PAIRS;
    float* cw1b = cw + 4 * PAIRS;
    float* cw2b = cw + 5 * PAIRS;
    float* cw0c = cw + 6 * PAIRS;
    float* cw1c = cw + 7 * PAIRS;
    float* cw2c = cw + 8 * PAIRS;

    embed_ln_kernel<<<512, 256, 0, stream>>>(ids, atom_emb, xn, xn_bf);

    dim3 tb(32, 8);
    transpose_sq<<<dim3(16, 16, 20), tb, 0, stream>>>(Wq, Wk, Wv, Wew, Wstack,
                                                      qkvt, ewt, stackt);
    transpose_rect<<<dim3(64, 64, 8), tb, 0, stream>>>(Wf1, Wf2, f1t, f2t);

    ew0_precompute<<<dim3(64, 8), 64, 0, stream>>>(bond_emb, ewt, E0);
    cast_w3<<<128, 256, 0, stream>>>(Wew + 3 * KN, wc3);

    for (int l = 0; l < L_; ++l) {
        if (l == 0) {
            mfma_gemm_s<0, false><<<dim3(8, 8, 3), 256, 0, stream>>>(
                xn_bf, qkvt, qkv, nullptr, 512, 512, 512);
            attn_kernel<true><<<dim3(512, 2), dim3(64, 4), 0, stream>>>(qkv, E0, adj, o_bf);
        } else if (l == 1) {
            basis_gemm1<<<dim3(9, 8), 256, 0, stream>>>(x_bf, E0, ewt + KN, xw1, e0w1);
            ew_combine1<<<8192, 256, 0, stream>>>(adj, cw0a, cw1a, cw2a, e0w1, xw1, ew);
            mfma_gemm_s<0, false><<<dim3(8, 8, 3), 256, 0, stream>>>(
                xn_bf, qkvt + (size_t)3 * KN, qkv, nullptr, 512, 512, 512);
            attn_kernel<false><<<dim3(512, 2), dim3(64, 4), 0, stream>>>(qkv, ew, adj, o_bf);
        } else if (l == 2) {
            basis_gemm2<<<dim3(17, 8), 256, 0, stream>>>(xw1, x_bf, e0w1, ewt + 2 * KN,
                                                         xw12, x2w2, e0w12);
            ew_combine2<<<8192, 256, 0, stream>>>(adj, cw0a, cw1a, cw2a, cw0b, cw1b, cw2b,
                                                  e0w12, xw12, x2w2, ew);
            mfma_gemm_s<0, false><<<dim3(8, 8, 3), 256, 0, stream>>>(
                xn_bf, qkvt + (size_t)6 * KN, qkv, nullptr, 512, 512, 512);
            attn_kernel<false><<<dim3(512, 2), dim3(64, 4), 0, stream>>>(qkv, ew, adj, o_bf);
        } else {
            // l=3: fully implicit -- neither ew3 nor bond3 ever materialized.
            mfma_gemm_s<0, false><<<dim3(8, 8, 3), 256, 0, stream>>>(
                xn_bf, qkvt + (size_t)9 * KN, qkv, nullptr, 512, 512, 512);
            u_gemm<<<dim3(8, 8, 8), 256, 0, stream>>>(qkv, wc3, ubf);
            mbuf_gemm<<<dim3(8, 8, 4), 256, 0, stream>>>(ubf, xw12, x2w2, x_bf, e0w12,
                                                         MX, MY, MZ, DE);
            s2_assemble<<<512, dim3(64, 8), 0, stream>>>(adj,
                cw0a, cw1a, cw2a, cw0b, cw1b, cw2b, cw0c, cw1c, cw2c,
                MX, MY, MZ, DE, s2buf);
            attn3_kernel<<<dim3(512, 2), dim3(64, 4), 0, stream>>>(qkv, s2buf, adj, o_bf);
        }

        mfma_gemm_s<0, true><<<dim3(8, 8, 4), 256, 0, stream>>>(
            o_bf, stackt + (size_t)l * KN, part, nullptr, 512, 512, 512);
        reduce_stack_ln<<<512, 256, 0, stream>>>(part, xn, resid, ffin_bf);
        mfma_gemm_s<2, false><<<dim3(8, 32), 256, 0, stream>>>(
            ffin_bf, f1t + (size_t)l * 4 * KN, ffh_bf, nullptr, 512, 2048, 512);
        mfma_gemm_s<0, true><<<dim3(8, 8, 4), 256, 0, stream>>>(
            ffh_bf, f2t + (size_t)l * 4 * KN, part, nullptr, 512, 512, 2048);
        if (l < L_ - 1)
            reduce_ln_kernel<true><<<512, 256, 0, stream>>>(part, resid, x, x_bf, xn, xn_bf);
        else
            reduce_ln_kernel<false><<<512, 256, 0, stream>>>(part, resid, x, x_bf, xn, xn_bf);

        if (l == 0)
            edge_coeff_kernel<true><<<8192, dim3(64, 4), 0, stream>>>(
                E0, adj, x, cw0a, cw1a, cw2a);
        else if (l == 1)
            edge_coeff_kernel<false><<<8192, dim3(64, 4), 0, stream>>>(
                ew, adj, x, cw0b, cw1b, cw2b);
        else if (l == 2)
            edge_coeff_kernel<false><<<8192, dim3(64, 4), 0, stream>>>(
                ew, adj, x, cw0c, cw1c, cw2c);
    }

    cls_part_kernel<<<dim3(8, 8, 4), 256, 0, stream>>>(x, Wout, clspart);
    cls_pred2_kernel<<<8, 256, 0, stream>>>(clspart, Wpred, bpred, (float*)d_out);
}

// Round 4
// 393.457 us; speedup vs baseline: 1.2638x; 1.1133x over previous
//
#include <hip/hip_runtime.h>
#include <hip/hip_bf16.h>

typedef __hip_bfloat16 bf16;

#define B_     8
#define N_     64
#define H_     512
#define HEADS_ 8
#define SP_    64
#define L_     4
static constexpr float INV_SCALE = 0.044194173824159216f; // 1/sqrt(512)

typedef __attribute__((ext_vector_type(8))) short short8;
typedef __attribute__((ext_vector_type(4))) float f32x4;

__device__ __forceinline__ void unpack8(uint4 u, float* f) {
    f[0] = __uint_as_float(u.x << 16); f[1] = __uint_as_float(u.x & 0xffff0000u);
    f[2] = __uint_as_float(u.y << 16); f[3] = __uint_as_float(u.y & 0xffff0000u);
    f[4] = __uint_as_float(u.z << 16); f[5] = __uint_as_float(u.z & 0xffff0000u);
    f[6] = __uint_as_float(u.w << 16); f[7] = __uint_as_float(u.w & 0xffff0000u);
}

__device__ __forceinline__ bf16 f2bf(float v) { return __float2bfloat16(v); }

__device__ __forceinline__ uint4 pack8bf(float4 a, float4 b) {
    __align__(16) bf16 t[8];
    t[0] = f2bf(a.x); t[1] = f2bf(a.y); t[2] = f2bf(a.z); t[3] = f2bf(a.w);
    t[4] = f2bf(b.x); t[5] = f2bf(b.y); t[6] = f2bf(b.z); t[7] = f2bf(b.w);
    return *(const uint4*)t;
}

#define RSTR 80

// ------------------------------------------------------------ GEMM body (64-tile)
// EPI: 0 = fp32 out, 1 = fp32 + residual, 2 = relu->bf16, 3 = bf16
template <int EPI>
__device__ __forceinline__ void gemm64_body(char* lds,
        const bf16* __restrict__ A, const bf16* __restrict__ Bt,
        void* __restrict__ Cv, const float* __restrict__ R,
        int M, int N, int K, int bx, int by, int kbeg, int kend) {
    char* As = lds;
    char* Bs = lds + 2 * 64 * RSTR;
    const int tid = threadIdx.x;
    const int bm = bx * 64, bn = by * 64;
    const int w = tid >> 6, lane = tid & 63;
    const int wr = (w >> 1) * 32, wc = (w & 1) * 32;
    const int m0 = lane & 15, q4 = lane >> 4;

    f32x4 acc[2][2] = {};

    const int rA = tid >> 3;
    const int cA = tid & 7;
    const int ksP = cA >> 2;
    const int cB = (cA & 3) * 16;
    const int cE = cA * 8;

    for (int k0 = kbeg; k0 < kend; k0 += 64) {
        uint4 a0 = *(const uint4*)(A  + (size_t)(bm + rA) * K + k0 + cE);
        uint4 a1 = *(const uint4*)(A  + (size_t)(bm + rA + 32) * K + k0 + cE);
        uint4 b0 = *(const uint4*)(Bt + (size_t)(bn + rA) * K + k0 + cE);
        uint4 b1 = *(const uint4*)(Bt + (size_t)(bn + rA + 32) * K + k0 + cE);
        __syncthreads();
        *(uint4*)(As + ksP * (64 * RSTR) + rA * RSTR + cB) = a0;
        *(uint4*)(As + ksP * (64 * RSTR) + (rA + 32) * RSTR + cB) = a1;
        *(uint4*)(Bs + ksP * (64 * RSTR) + rA * RSTR + cB) = b0;
        *(uint4*)(Bs + ksP * (64 * RSTR) + (rA + 32) * RSTR + cB) = b1;
        __syncthreads();
        short8 af[2][2], bfr[2][2];
        #pragma unroll
        for (int ks = 0; ks < 2; ++ks)
            #pragma unroll
            for (int t = 0; t < 2; ++t) {
                af[ks][t]  = *(const short8*)(As + ks * (64 * RSTR) + (wr + t * 16 + m0) * RSTR + q4 * 16);
                bfr[ks][t] = *(const short8*)(Bs + ks * (64 * RSTR) + (wc + t * 16 + m0) * RSTR + q4 * 16);
            }
        #pragma unroll
        for (int ks = 0; ks < 2; ++ks)
            #pragma unroll
            for (int mt = 0; mt < 2; ++mt)
                #pragma unroll
                for (int nt = 0; nt < 2; ++nt)
                    acc[mt][nt] = __builtin_amdgcn_mfma_f32_16x16x32_bf16(
                        af[ks][mt], bfr[ks][nt], acc[mt][nt], 0, 0, 0);
    }

    if (EPI <= 1) {
        float* C = (float*)Cv;
        #pragma unroll
        for (int mt = 0; mt < 2; ++mt)
            #pragma unroll
            for (int i = 0; i < 4; ++i) {
                int row = bm + wr + mt * 16 + q4 * 4 + i;
                #pragma unroll
                for (int nt = 0; nt < 2; ++nt) {
                    int col = bn + wc + nt * 16 + m0;
                    float v = acc[mt][nt][i];
                    if (EPI == 1) v += R[(size_t)row * N + col];
                    C[(size_t)row * N + col] = v;
                }
            }
    } else {
        bf16* C = (bf16*)Cv;
        #pragma unroll
        for (int mt = 0; mt < 2; ++mt)
            #pragma unroll
            for (int i = 0; i < 4; ++i) {
                int row = bm + wr + mt * 16 + q4 * 4 + i;
                #pragma unroll
                for (int nt = 0; nt < 2; ++nt) {
                    int col = bn + wc + nt * 16 + m0;
                    float v = acc[mt][nt][i];
                    if (EPI == 2) v = fmaxf(v, 0.0f);
                    C[(size_t)row * N + col] = __float2bfloat16(v);
                }
            }
    }
}

template <int EPI, bool SPLIT>
__launch_bounds__(256)
__global__ void mfma_gemm_s(const bf16* __restrict__ A, const bf16* __restrict__ Bt,
                            void* __restrict__ Cv, const float* __restrict__ R,
                            int M, int N, int K) {
    __shared__ __align__(16) char lds[4 * 64 * RSTR];
    int kbeg = 0, kend = K;
    const bf16* B2 = Bt;
    void* C2 = Cv;
    if (SPLIT) {
        int ks = K / gridDim.z;
        kbeg = blockIdx.z * ks;
        kend = kbeg + ks;
        C2 = (void*)((float*)Cv + (size_t)blockIdx.z * M * N);
        gemm64_body<0>(lds, A, B2, C2, nullptr, M, N, K, blockIdx.x, blockIdx.y, kbeg, kend);
    } else {
        B2 = Bt + (size_t)blockIdx.z * N * K;
        if (EPI <= 1) C2 = (void*)((float*)Cv + (size_t)blockIdx.z * M * N);
        gemm64_body<EPI>(lds, A, B2, C2, R, M, N, K, blockIdx.x, blockIdx.y, kbeg, kend);
    }
}

// ------------------------------------------------ merged basis + qkv launches
// l=1: bx<8 -> XW1 = x_bf @ Wew1 ; bx==8 -> E0W1 = E0pad @ Wew1 ; else qkv GEMM
__launch_bounds__(256)
__global__ void basis1_qkv_kernel(const bf16* __restrict__ x_bf, const bf16* __restrict__ E0,
                                  const bf16* __restrict__ ewt1,
                                  bf16* __restrict__ xw1, bf16* __restrict__ e0w1,
                                  const bf16* __restrict__ xn_bf, const bf16* __restrict__ qkvt_l,
                                  float* __restrict__ qkv) {
    __shared__ __align__(16) char lds[4 * 64 * RSTR];
    int bx = blockIdx.x, by = blockIdx.y;
    if (bx < 8)
        gemm64_body<3>(lds, x_bf, ewt1, xw1, nullptr, 512, 512, 512, bx, by, 0, 512);
    else if (bx == 8)
        gemm64_body<3>(lds, E0, ewt1, e0w1, nullptr, 64, 512, 512, 0, by, 0, 512);
    else {
        int tq = bx - 9;
        int z = tq >> 3, mb = tq & 7;
        gemm64_body<0>(lds, xn_bf, qkvt_l + (size_t)z * 262144,
                       qkv + (size_t)z * 262144, nullptr, 512, 512, 512, mb, by, 0, 512);
    }
}

// l=2: bx<8 XW12 ; bx<16 X2W2 ; bx==16 E0W12 ; else qkv
__launch_bounds__(256)
__global__ void basis2_qkv_kernel(const bf16* __restrict__ xw1, const bf16* __restrict__ x_bf,
                                  const bf16* __restrict__ e0w1, const bf16* __restrict__ ewt2,
                                  bf16* __restrict__ xw12, bf16* __restrict__ x2w2,
                                  bf16* __restrict__ e0w12,
                                  const bf16* __restrict__ xn_bf, const bf16* __restrict__ qkvt_l,
                                  float* __restrict__ qkv) {
    __shared__ __align__(16) char lds[4 * 64 * RSTR];
    int bx = blockIdx.x, by = blockIdx.y;
    if (bx < 8)
        gemm64_body<3>(lds, xw1, ewt2, xw12, nullptr, 512, 512, 512, bx, by, 0, 512);
    else if (bx < 16)
        gemm64_body<3>(lds, x_bf, ewt2, x2w2, nullptr, 512, 512, 512, bx - 8, by, 0, 512);
    else if (bx == 16)
        gemm64_body<3>(lds, e0w1, ewt2, e0w12, nullptr, 64, 512, 512, 0, by, 0, 512);
    else {
        int tq = bx - 17;
        int z = tq >> 3, mb = tq & 7;
        gemm64_body<0>(lds, xn_bf, qkvt_l + (size_t)z * 262144,
                       qkv + (size_t)z * 262144, nullptr, 512, 512, 512, mb, by, 0, 512);
    }
}

// ------------------------------------------------ P-tables: per-(b,h) q . basis^T
// P[z][b,h,i,r] = sum_{d<64} q[b, i, h*64+d] * Bz[r, h*64+d]
// grid (8b, 8h, nz); z == nz-1 uses shared (non-per-b) basis rows (E-table).
__launch_bounds__(256)
__global__ void ptable_kernel(const float* __restrict__ q,
                              const bf16* __restrict__ B0, const bf16* __restrict__ B1,
                              const bf16* __restrict__ B2,
                              float* __restrict__ P0, float* __restrict__ P1,
                              float* __restrict__ P2) {
    __shared__ __align__(16) char lds[4 * 64 * RSTR];
    char* As = lds;
    char* Bs = lds + 2 * 64 * RSTR;
    const int b = blockIdx.x, h = blockIdx.y, z = blockIdx.z;
    const int nz = gridDim.z;
    const bf16* Bt = (z == 0) ? B0 : (z == 1 ? B1 : B2);
    float* P = (z == 0) ? P0 : (z == 1 ? P1 : P2);
    const bool shr = (z == nz - 1);
    const int tid = threadIdx.x;
    const int w = tid >> 6, lane = tid & 63;
    const int wr = (w >> 1) * 32, wc = (w & 1) * 32;
    const int m0 = lane & 15, q4 = lane >> 4;
    const int rA = tid >> 3;
    const int cA = tid & 7;
    const int ksP = cA >> 2;
    const int cB = (cA & 3) * 16;
    const int cE = cA * 8;

    const float* Aq = q + (size_t)(b * 64) * 512 + h * 64;
    const bf16*  Bb = Bt + (shr ? (size_t)0 : (size_t)b * 64 * 512) + h * 64;

    float4 fa0 = *(const float4*)(Aq + (size_t)rA * 512 + cE);
    float4 fa1 = *(const float4*)(Aq + (size_t)rA * 512 + cE + 4);
    float4 fb0 = *(const float4*)(Aq + (size_t)(rA + 32) * 512 + cE);
    float4 fb1 = *(const float4*)(Aq + (size_t)(rA + 32) * 512 + cE + 4);
    uint4 bv0 = *(const uint4*)(Bb + (size_t)rA * 512 + cE);
    uint4 bv1 = *(const uint4*)(Bb + (size_t)(rA + 32) * 512 + cE);
    uint4 av0 = pack8bf(fa0, fa1);
    uint4 av1 = pack8bf(fb0, fb1);
    *(uint4*)(As + ksP * (64 * RSTR) + rA * RSTR + cB) = av0;
    *(uint4*)(As + ksP * (64 * RSTR) + (rA + 32) * RSTR + cB) = av1;
    *(uint4*)(Bs + ksP * (64 * RSTR) + rA * RSTR + cB) = bv0;
    *(uint4*)(Bs + ksP * (64 * RSTR) + (rA + 32) * RSTR + cB) = bv1;
    __syncthreads();

    f32x4 acc[2][2] = {};
    short8 af[2][2], bfr[2][2];
    #pragma unroll
    for (int ks = 0; ks < 2; ++ks)
        #pragma unroll
        for (int t = 0; t < 2; ++t) {
            af[ks][t]  = *(const short8*)(As + ks * (64 * RSTR) + (wr + t * 16 + m0) * RSTR + q4 * 16);
            bfr[ks][t] = *(const short8*)(Bs + ks * (64 * RSTR) + (wc + t * 16 + m0) * RSTR + q4 * 16);
        }
    #pragma unroll
    for (int ks = 0; ks < 2; ++ks)
        #pragma unroll
        for (int mt = 0; mt < 2; ++mt)
            #pragma unroll
            for (int nt = 0; nt < 2; ++nt)
                acc[mt][nt] = __builtin_amdgcn_mfma_f32_16x16x32_bf16(
                    af[ks][mt], bfr[ks][nt], acc[mt][nt], 0, 0, 0);

    #pragma unroll
    for (int mt = 0; mt < 2; ++mt)
        #pragma unroll
        for (int i = 0; i < 4; ++i) {
            int row = wr + mt * 16 + q4 * 4 + i;
            #pragma unroll
            for (int nt = 0; nt < 2; ++nt) {
                int col = wc + nt * 16 + m0;
                P[(((size_t)b * 8 + h) * 64 + row) * 64 + col] = acc[mt][nt][i];
            }
        }
}

// ------------------------------------------------ Gram tables (per-b 64x64, K=512)
// l=1: z0 <X,X>  z1 <E,X>  z2 <X,x2>  z3 <E,x2>  z4 <E,E>
__launch_bounds__(256)
__global__ void gram1_kernel(const bf16* __restrict__ xw1, const bf16* __restrict__ e0w1,
                             const bf16* __restrict__ xb, float* __restrict__ gbuf) {
    __shared__ __align__(16) char lds[4 * 64 * RSTR];
    int b = blockIdx.x, z = blockIdx.y;
    size_t ob = (size_t)b * 32768;
    const bf16 *A, *Bt;
    switch (z) {
        case 0: A = xw1 + ob; Bt = xw1 + ob; break;
        case 1: A = e0w1;     Bt = xw1 + ob; break;
        case 2: A = xw1 + ob; Bt = xb + ob;  break;
        case 3: A = e0w1;     Bt = xb + ob;  break;
        default: A = e0w1;    Bt = e0w1;     break;
    }
    float* C = gbuf + (size_t)z * 32768 + (size_t)b * 4096;
    gemm64_body<0>(lds, A, Bt, C, nullptr, 64, 64, 512, 0, 0, 0, 512);
}

// l=2: z0 <X12,X12> z1 <X12,Y> z2 <Y,Y> z3 <E,X12> z4 <E,Y> z5 <E,E> z6 <X12,x3> z7 <Y,x3> z8 <E,x3>
__launch_bounds__(256)
__global__ void gram2_kernel(const bf16* __restrict__ xw12, const bf16* __restrict__ x2w2,
                             const bf16* __restrict__ e0w12, const bf16* __restrict__ xb,
                             float* __restrict__ gbuf) {
    __shared__ __align__(16) char lds[4 * 64 * RSTR];
    int b = blockIdx.x, z = blockIdx.y;
    size_t ob = (size_t)b * 32768;
    const bf16 *A, *Bt;
    switch (z) {
        case 0: A = xw12 + ob; Bt = xw12 + ob; break;
        case 1: A = xw12 + ob; Bt = x2w2 + ob; break;
        case 2: A = x2w2 + ob; Bt = x2w2 + ob; break;
        case 3: A = e0w12;     Bt = xw12 + ob; break;
        case 4: A = e0w12;     Bt = x2w2 + ob; break;
        case 5: A = e0w12;     Bt = e0w12;     break;
        case 6: A = xw12 + ob; Bt = xb + ob;   break;
        case 7: A = x2w2 + ob; Bt = xb + ob;   break;
        default: A = e0w12;    Bt = xb + ob;   break;
    }
    float* C = gbuf + (size_t)z * 32768 + (size_t)b * 4096;
    gemm64_body<0>(lds, A, Bt, C, nullptr, 64, 64, 512, 0, 0, 0, 512);
}

// edge softmax coeffs from l=1 Gram tables (replaces edge_coeff on materialized ew1)
__global__ void coeff_assemble1(const int* __restrict__ adj,
        const float* __restrict__ c0a, const float* __restrict__ c1a, const float* __restrict__ c2a,
        const float* __restrict__ gbuf,
        float* __restrict__ w0o, float* __restrict__ w1o, float* __restrict__ w2o) {
    int bi = blockIdx.x;
    int b = bi >> 6, i = bi & 63;
    int j = threadIdx.x;
    int p = bi * 64 + j;
    int t = adj[p];
    const float* TXX = gbuf + 0 * 32768 + (size_t)b * 4096;
    const float* TEX = gbuf + 1 * 32768 + (size_t)b * 4096;
    const float* TXx = gbuf + 2 * 32768 + (size_t)b * 4096;
    const float* TEx = gbuf + 3 * 32768 + (size_t)b * 4096;
    const float* TEE = gbuf + 4 * 32768 + (size_t)b * 4096;
    float c0 = c0a[p], c1 = c1a[p], c2 = c2a[p];
    float s1 = c0 * TEx[t * 64 + i] + c1 * TXx[i * 64 + i] + c2 * TXx[j * 64 + i];
    float s2 = c0 * TEx[t * 64 + j] + c1 * TXx[i * 64 + j] + c2 * TXx[j * 64 + j];
    float s0 = c0 * c0 * TEE[t * 64 + t] + c1 * c1 * TXX[i * 64 + i] + c2 * c2 * TXX[j * 64 + j]
             + 2.f * c0 * c1 * TEX[t * 64 + i] + 2.f * c0 * c2 * TEX[t * 64 + j]
             + 2.f * c1 * c2 * TXX[i * 64 + j];
    float t0 = s0 * INV_SCALE, t1 = s1 * INV_SCALE, t2 = s2 * INV_SCALE;
    float m = fmaxf(t0, fmaxf(t1, t2));
    float e0 = expf(t0 - m), e1 = expf(t1 - m), e2 = expf(t2 - m);
    float inv = 1.0f / (e0 + e1 + e2);
    w0o[p] = e0 * inv;
    w1o[p] = e1 * inv;
    w2o[p] = e2 * inv;
}

// edge softmax coeffs from l=2 Gram tables (5-term ew2 expansion)
__global__ void coeff_assemble2(const int* __restrict__ adj,
        const float* __restrict__ c0a, const float* __restrict__ c1a, const float* __restrict__ c2a,
        const float* __restrict__ c0b, const float* __restrict__ c1b, const float* __restrict__ c2b,
        const float* __restrict__ gbuf,
        float* __restrict__ w0o, float* __restrict__ w1o, float* __restrict__ w2o) {
    int bi = blockIdx.x;
    int b = bi >> 6, i = bi & 63;
    int j = threadIdx.x;
    int p = bi * 64 + j;
    int t = adj[p];
    const float* TXX = gbuf + 0 * 32768 + (size_t)b * 4096;
    const float* TXY = gbuf + 1 * 32768 + (size_t)b * 4096;
    const float* TYY = gbuf + 2 * 32768 + (size_t)b * 4096;
    const float* TEX = gbuf + 3 * 32768 + (size_t)b * 4096;
    const float* TEY = gbuf + 4 * 32768 + (size_t)b * 4096;
    const float* TEE = gbuf + 5 * 32768 + (size_t)b * 4096;
    const float* TXx = gbuf + 6 * 32768 + (size_t)b * 4096;
    const float* TYx = gbuf + 7 * 32768 + (size_t)b * 4096;
    const float* TEx = gbuf + 8 * 32768 + (size_t)b * 4096;
    float a0 = c0b[p];
    float AE = a0 * c0a[p], Aa = a0 * c1a[p], Ab = a0 * c2a[p];
    float Ac = c1b[p], Ad = c2b[p];
    float s1 = AE * TEx[t * 64 + i] + Aa * TXx[i * 64 + i] + Ab * TXx[j * 64 + i]
             + Ac * TYx[i * 64 + i] + Ad * TYx[j * 64 + i];
    float s2 = AE * TEx[t * 64 + j] + Aa * TXx[i * 64 + j] + Ab * TXx[j * 64 + j]
             + Ac * TYx[i * 64 + j] + Ad * TYx[j * 64 + j];
    float s0 = AE * AE * TEE[t * 64 + t] + Aa * Aa * TXX[i * 64 + i] + Ab * Ab * TXX[j * 64 + j]
             + Ac * Ac * TYY[i * 64 + i] + Ad * Ad * TYY[j * 64 + j]
             + 2.f * AE * Aa * TEX[t * 64 + i] + 2.f * AE * Ab * TEX[t * 64 + j]
             + 2.f * AE * Ac * TEY[t * 64 + i] + 2.f * AE * Ad * TEY[t * 64 + j]
             + 2.f * Aa * Ab * TXX[i * 64 + j]
             + 2.f * Aa * Ac * TXY[i * 64 + i] + 2.f * Aa * Ad * TXY[i * 64 + j]
             + 2.f * Ab * Ac * TXY[j * 64 + i] + 2.f * Ab * Ad * TXY[j * 64 + j]
             + 2.f * Ac * Ad * TYY[i * 64 + j];
    float t0 = s0 * INV_SCALE, t1 = s1 * INV_SCALE, t2 = s2 * INV_SCALE;
    float m = fmaxf(t0, fmaxf(t1, t2));
    float e0 = expf(t0 - m), e1 = expf(t1 - m), e2 = expf(t2 - m);
    float inv = 1.0f / (e0 + e1 + e2);
    w0o[p] = e0 * inv;
    w1o[p] = e1 * inv;
    w2o[p] = e2 * inv;
}

// ---------------------- layer-3 implicit path
// u_bf[b,i,h,k] = sum_d q[b,i,h*64+d] * Wew3[k, h*64+d]   (bf16 out)
__launch_bounds__(256)
__global__ void u_gemm(const float* __restrict__ q, const bf16* __restrict__ wc3,
                       bf16* __restrict__ ubf) {
    __shared__ __align__(16) char lds[4 * 64 * RSTR];
    char* As = lds;
    char* Bs = lds + 2 * 64 * RSTR;
    const int h = blockIdx.x, mb = blockIdx.y, nb = blockIdx.z;
    const int tid = threadIdx.x;
    const int w = tid >> 6, lane = tid & 63;
    const int wr = (w >> 1) * 32, wc = (w & 1) * 32;
    const int m0 = lane & 15, q4 = lane >> 4;
    const int rA = tid >> 3;
    const int cA = tid & 7;
    const int ksP = cA >> 2;
    const int cB = (cA & 3) * 16;
    const int cE = cA * 8;

    const float* Aq = q + (size_t)(mb * 64) * 512 + h * 64;
    const bf16*  Bt = wc3 + (size_t)(nb * 64) * 512 + h * 64;

    float4 fa0 = *(const float4*)(Aq + (size_t)rA * 512 + cE);
    float4 fa1 = *(const float4*)(Aq + (size_t)rA * 512 + cE + 4);
    float4 fb0 = *(const float4*)(Aq + (size_t)(rA + 32) * 512 + cE);
    float4 fb1 = *(const float4*)(Aq + (size_t)(rA + 32) * 512 + cE + 4);
    uint4 b0 = *(const uint4*)(Bt + (size_t)rA * 512 + cE);
    uint4 b1 = *(const uint4*)(Bt + (size_t)(rA + 32) * 512 + cE);
    uint4 a0 = pack8bf(fa0, fa1);
    uint4 a1 = pack8bf(fb0, fb1);
    *(uint4*)(As + ksP * (64 * RSTR) + rA * RSTR + cB) = a0;
    *(uint4*)(As + ksP * (64 * RSTR) + (rA + 32) * RSTR + cB) = a1;
    *(uint4*)(Bs + ksP * (64 * RSTR) + rA * RSTR + cB) = b0;
    *(uint4*)(Bs + ksP * (64 * RSTR) + (rA + 32) * RSTR + cB) = b1;
    __syncthreads();

    f32x4 acc[2][2] = {};
    short8 af[2][2], bfr[2][2];
    #pragma unroll
    for (int ks = 0; ks < 2; ++ks)
        #pragma unroll
        for (int t = 0; t < 2; ++t) {
            af[ks][t]  = *(const short8*)(As + ks * (64 * RSTR) + (wr + t * 16 + m0) * RSTR + q4 * 16);
            bfr[ks][t] = *(const short8*)(Bs + ks * (64 * RSTR) + (wc + t * 16 + m0) * RSTR + q4 * 16);
        }
    #pragma unroll
    for (int ks = 0; ks < 2; ++ks)
        #pragma unroll
        for (int mt = 0; mt < 2; ++mt)
            #pragma unroll
            for (int nt = 0; nt < 2; ++nt)
                acc[mt][nt] = __builtin_amdgcn_mfma_f32_16x16x32_bf16(
                    af[ks][mt], bfr[ks][nt], acc[mt][nt], 0, 0, 0);

    #pragma unroll
    for (int mt = 0; mt < 2; ++mt)
        #pragma unroll
        for (int i = 0; i < 4; ++i) {
            int row = mb * 64 + wr + mt * 16 + q4 * 4 + i;
            #pragma unroll
            for (int nt = 0; nt < 2; ++nt) {
                int col = nb * 64 + wc + nt * 16 + m0;
                ubf[(size_t)row * 4096 + h * 512 + col] = f2bf(acc[mt][nt][i]);
            }
        }
}

__global__ void cast_w3(const float* __restrict__ in, bf16* __restrict__ out) {
    int gid = blockIdx.x * 256 + threadIdx.x;
    const float4* p = (const float4*)(in + (size_t)gid * 8);
    float4 a = p[0], b = p[1];
    *(uint4*)(out + (size_t)gid * 8) = pack8bf(a, b);
}

// M-tables: for each b, U_b (512 rows (i,h) x 512 k) @ basis_b^T (64 x 512)
__launch_bounds__(256)
__global__ void mbuf_gemm(const bf16* __restrict__ ubf, const bf16* __restrict__ xw12,
                          const bf16* __restrict__ x2w2, const bf16* __restrict__ x_bf,
                          const bf16* __restrict__ e0w12,
                          float* __restrict__ MX, float* __restrict__ MY,
                          float* __restrict__ MZ, float* __restrict__ DE) {
    __shared__ __align__(16) char lds[4 * 64 * RSTR];
    int b = blockIdx.x, mt = blockIdx.y, z = blockIdx.z;
    const bf16* A = ubf + (size_t)b * 512 * 512;
    const bf16* Bt;
    float* C;
    if (z == 0)      { Bt = xw12 + (size_t)b * 64 * 512; C = MX + (size_t)b * 512 * 64; }
    else if (z == 1) { Bt = x2w2 + (size_t)b * 64 * 512; C = MY + (size_t)b * 512 * 64; }
    else if (z == 2) { Bt = x_bf + (size_t)b * 64 * 512; C = MZ + (size_t)b * 512 * 64; }
    else             { Bt = e0w12;                        C = DE + (size_t)b * 512 * 64; }
    gemm64_body<0>(lds, A, Bt, C, nullptr, 512, 64, 512, mt, 0, 0, 512);
}

// s2[b,h,i,j] for l=3 from M-tables + 3 coeff triples
__global__ void s2_assemble(const int* __restrict__ adj,
        const float* __restrict__ c0a, const float* __restrict__ c1a, const float* __restrict__ c2a,
        const float* __restrict__ c0b, const float* __restrict__ c1b, const float* __restrict__ c2b,
        const float* __restrict__ v0c, const float* __restrict__ v1c, const float* __restrict__ v2c,
        const float* __restrict__ MX, const float* __restrict__ MY,
        const float* __restrict__ MZ, const float* __restrict__ DE,
        float* __restrict__ s2) {
    int bi = blockIdx.x;
    int b = bi >> 6, i = bi & 63;
    int j = threadIdx.x, h = threadIdx.y;
    int p = bi * 64 + j;
    float v0 = v0c[p];
    float q0 = v0 * c0b[p];
    float AE = q0 * c0a[p], Aa = q0 * c1a[p], Ab = q0 * c2a[p];
    float Ac = v0 * c1b[p], Ad = v0 * c2b[p];
    float Ae = v1c[p], Af = v2c[p];
    size_t rb = ((size_t)b * 512 + i * 8 + h) * 64;
    float s = AE * DE[rb + adj[p]]
            + Aa * MX[rb + i] + Ac * MY[rb + i] + Ae * MZ[rb + i]
            + Ab * MX[rb + j] + Ad * MY[rb + j] + Af * MZ[rb + j];
    s2[(((size_t)b * 8 + h) * 64 + i) * 64 + j] = s;
}

// ---------------------------------------------------------------- embeddings
__global__ void embed_ln_kernel(const int* __restrict__ ids,
                                const float* __restrict__ emb,
                                float* __restrict__ xn, bf16* __restrict__ xn_bf) {
    int row = blockIdx.x;
    int tid = threadIdx.x;
    const float* r = emb + (size_t)ids[row] * H_;
    float x0 = r[tid], x1 = r[tid + 256];
    float s = x0 + x1, sq = x0 * x0 + x1 * x1;
    #pragma unroll
    for (int off = 32; off; off >>= 1) {
        s  += __shfl_xor(s,  off);
        sq += __shfl_xor(sq, off);
    }
    __shared__ float ls[4], lq[4];
    int w = tid >> 6;
    if ((tid & 63) == 0) { ls[w] = s; lq[w] = sq; }
    __syncthreads();
    float S = ls[0] + ls[1] + ls[2] + ls[3];
    float Q = lq[0] + lq[1] + lq[2] + lq[3];
    float mean = S * (1.0f / H_);
    float var  = Q * (1.0f / H_) - mean * mean;
    float inv  = rsqrtf(var + 1e-5f);
    float y0 = (x0 - mean) * inv, y1 = (x1 - mean) * inv;
    xn[(size_t)row * H_ + tid]       = y0;
    xn[(size_t)row * H_ + tid + 256] = y1;
    xn_bf[(size_t)row * H_ + tid]       = f2bf(y0);
    xn_bf[(size_t)row * H_ + tid + 256] = f2bf(y1);
}

// E0 padded to 64 rows: rows 8..63 zeroed
__global__ void ew0_precompute(const float* __restrict__ bond_emb,
                               const bf16* __restrict__ ewt0, bf16* __restrict__ E0) {
    int t = blockIdx.x, cb = blockIdx.y, lane = threadIdx.x;
    int c = cb * 64 + lane;
    if (t >= 8) { E0[t * 512 + c] = f2bf(0.0f); return; }
    __shared__ float be[512];
    for (int h = lane; h < 512; h += 64) be[h] = bond_emb[t * 512 + h];
    __syncthreads();
    const bf16* wr = ewt0 + (size_t)c * 512;
    float acc = 0.f;
    for (int h8 = 0; h8 < 64; ++h8) {
        uint4 u = *(const uint4*)(wr + h8 * 8);
        float wf[8];
        unpack8(u, wf);
        const float* b = &be[h8 * 8];
        acc += b[0]*wf[0] + b[1]*wf[1] + b[2]*wf[2] + b[3]*wf[3]
             + b[4]*wf[4] + b[5]*wf[5] + b[6]*wf[6] + b[7]*wf[7];
    }
    E0[t * 512 + c] = f2bf(acc);
}

// ------------------------------------------------- weight transpose + cast
__global__ void transpose_sq(const float* __restrict__ Wq, const float* __restrict__ Wk,
                             const float* __restrict__ Wv, const float* __restrict__ Wew,
                             const float* __restrict__ Wst,
                             bf16* __restrict__ qkvt, bf16* __restrict__ ewt,
                             bf16* __restrict__ stackt) {
    const size_t KN = (size_t)H_ * H_;
    int z = blockIdx.z;
    const float* W; bf16* Wt;
    if (z < 12) {
        int s = z >> 2, l = z & 3;
        W  = (s == 0 ? Wq : s == 1 ? Wk : Wv) + (size_t)l * KN;
        Wt = qkvt + (size_t)l * 3 * KN + (size_t)s * KN;
    } else if (z < 16) {
        int l = z - 12;
        W = Wew + (size_t)l * KN; Wt = ewt + (size_t)l * KN;
    } else {
        int l = z - 16;
        W = Wst + (size_t)l * KN; Wt = stackt + (size_t)l * KN;
    }
    __shared__ float t[32][33];
    int k0 = blockIdx.x * 32, n0 = blockIdx.y * 32;
    int tx = threadIdx.x, ty = threadIdx.y;
    #pragma unroll
    for (int r = ty; r < 32; r += 8)
        t[r][tx] = W[(size_t)(k0 + r) * H_ + n0 + tx];
    __syncthreads();
    #pragma unroll
    for (int r = ty; r < 32; r += 8)
        Wt[(size_t)(n0 + r) * H_ + k0 + tx] = f2bf(t[tx][r]);
}

__global__ void transpose_rect(const float* __restrict__ Wf1, const float* __restrict__ Wf2,
                               bf16* __restrict__ f1t, bf16* __restrict__ f2t) {
    const size_t KN4 = (size_t)4 * H_ * H_;
    int z = blockIdx.z;
    const float* W; bf16* Wt; int K, N;
    if (z < 4) {
        if (blockIdx.x >= 16) return;
        W = Wf1 + (size_t)z * KN4; Wt = f1t + (size_t)z * KN4; K = 512; N = 2048;
    } else {
        if (blockIdx.y >= 16) return;
        W = Wf2 + (size_t)(z - 4) * KN4; Wt = f2t + (size_t)(z - 4) * KN4; K = 2048; N = 512;
    }
    __shared__ float t[32][33];
    int k0 = blockIdx.x * 32, n0 = blockIdx.y * 32;
    int tx = threadIdx.x, ty = threadIdx.y;
    #pragma unroll
    for (int r = ty; r < 32; r += 8)
        t[r][tx] = W[(size_t)(k0 + r) * N + n0 + tx];
    __syncthreads();
    #pragma unroll
    for (int r = ty; r < 32; r += 8)
        Wt[(size_t)(n0 + r) * K + k0 + tx] = f2bf(t[tx][r]);
}

// ---------------------- split-K reduce + residual + LN variants
__global__ void reduce_stack_ln(const float* __restrict__ part, const float* __restrict__ base,
                                float* __restrict__ resid, bf16* __restrict__ ffin_bf) {
    const int MN = 512 * H_;
    int row = blockIdx.x;
    int tid = threadIdx.x;
    size_t b0 = (size_t)row * H_;
    float v0 = base[b0 + tid], v1 = base[b0 + tid + 256];
    #pragma unroll
    for (int s = 0; s < 4; ++s) {
        v0 += part[(size_t)s * MN + b0 + tid];
        v1 += part[(size_t)s * MN + b0 + tid + 256];
    }
    resid[b0 + tid] = v0;
    resid[b0 + tid + 256] = v1;
    float s = v0 + v1, sq = v0 * v0 + v1 * v1;
    #pragma unroll
    for (int off = 32; off; off >>= 1) {
        s  += __shfl_xor(s,  off);
        sq += __shfl_xor(sq, off);
    }
    __shared__ float ls[4], lq[4];
    int w = tid >> 6;
    if ((tid & 63) == 0) { ls[w] = s; lq[w] = sq; }
    __syncthreads();
    float S = ls[0] + ls[1] + ls[2] + ls[3];
    float Q = lq[0] + lq[1] + lq[2] + lq[3];
    float mean = S * (1.0f / H_);
    float var  = Q * (1.0f / H_) - mean * mean;
    float inv  = rsqrtf(var + 1e-5f);
    ffin_bf[b0 + tid]       = f2bf((v0 - mean) * inv);
    ffin_bf[b0 + tid + 256] = f2bf((v1 - mean) * inv);
}

template <bool DO_LN>
__global__ void reduce_ln_kernel(const float* __restrict__ part, const float* __restrict__ resid,
                                 float* __restrict__ x, bf16* __restrict__ x_bf,
                                 float* __restrict__ xn, bf16* __restrict__ xn_bf) {
    const int MN = 512 * H_;
    int row = blockIdx.x;
    int tid = threadIdx.x;
    size_t base = (size_t)row * H_;
    float v0 = resid[base + tid], v1 = resid[base + tid + 256];
    #pragma unroll
    for (int s = 0; s < 4; ++s) {
        v0 += part[(size_t)s * MN + base + tid];
        v1 += part[(size_t)s * MN + base + tid + 256];
    }
    x[base + tid] = v0;
    x[base + tid + 256] = v1;
    x_bf[base + tid]       = f2bf(v0);
    x_bf[base + tid + 256] = f2bf(v1);
    if (DO_LN) {
        float s = v0 + v1, sq = v0 * v0 + v1 * v1;
        #pragma unroll
        for (int off = 32; off; off >>= 1) {
            s  += __shfl_xor(s,  off);
            sq += __shfl_xor(sq, off);
        }
        __shared__ float ls[4], lq[4];
        int w = tid >> 6;
        if ((tid & 63) == 0) { ls[w] = s; lq[w] = sq; }
        __syncthreads();
        float S = ls[0] + ls[1] + ls[2] + ls[3];
        float Q = lq[0] + lq[1] + lq[2] + lq[3];
        float mean = S * (1.0f / H_);
        float var  = Q * (1.0f / H_) - mean * mean;
        float inv  = rsqrtf(var + 1e-5f);
        float y0 = (v0 - mean) * inv, y1 = (v1 - mean) * inv;
        xn[base + tid]       = y0;
        xn[base + tid + 256] = y1;
        xn_bf[base + tid]       = f2bf(y0);
        xn_bf[base + tid + 256] = f2bf(y1);
    }
}

// ---------------------------------------------------------------- attention
// l=0: w-row gathered from E0[adj[pair]] (8-row table, L1-resident)
template <bool GATHER>
__global__ void attn_kernel(const float* __restrict__ qkv, const bf16* __restrict__ ew,
                            const int* __restrict__ adj, bf16* __restrict__ o) {
    const float* q = qkv;
    const float* k = qkv + (size_t)512 * H_;
    const float* v = qkv + (size_t)1024 * H_;
    int bi = blockIdx.x;
    int b  = bi >> 6;
    int ty = threadIdx.y;
    int h  = blockIdx.y * 4 + ty;
    int lane = threadIdx.x;
    __shared__ float qs[4][64], as[4][64];
    qs[ty][lane] = q[(size_t)bi * H_ + h * 64 + lane];
    __syncthreads();

    int j = lane;
    int pair = bi * 64 + j;
    int aj = adj[pair];
    const float4* k4 = (const float4*)(k + (size_t)(b * 64 + j) * H_ + h * 64);
    const uint4*  w4 = (const uint4*)((GATHER ? ew + (size_t)aj * H_
                                              : ew + (size_t)pair * H_) + h * 64);
    float acc = 0.f;
    #pragma unroll
    for (int t = 0; t < 8; ++t) {
        uint4 wu = w4[t];
        float4 ka = k4[2 * t], kb = k4[2 * t + 1];
        float wf[8];
        unpack8(wu, wf);
        const float* qq = &qs[ty][t * 8];
        acc += qq[0] * (ka.x + wf[0]) + qq[1] * (ka.y + wf[1])
             + qq[2] * (ka.z + wf[2]) + qq[3] * (ka.w + wf[3])
             + qq[4] * (kb.x + wf[4]) + qq[5] * (kb.y + wf[5])
             + qq[6] * (kb.z + wf[6]) + qq[7] * (kb.w + wf[7]);
    }
    float logit = acc * INV_SCALE;
    if (aj <= 0) logit = -INFINITY;

    float m = logit;
    #pragma unroll
    for (int off = 32; off; off >>= 1) m = fmaxf(m, __shfl_xor(m, off));
    float p = expf(logit - m);
    float s = p;
    #pragma unroll
    for (int off = 32; off; off >>= 1) s += __shfl_xor(s, off);
    as[ty][lane] = p / s;
    __syncthreads();

    const float* vbase = v + (size_t)(b * 64) * H_ + h * 64;
    float oacc = 0.f;
    int d = lane;
    #pragma unroll 8
    for (int jj = 0; jj < 64; ++jj)
        oacc += as[ty][jj] * vbase[(size_t)jj * H_ + d];
    o[(size_t)bi * H_ + h * 64 + d] = __float2bfloat16(oacc);
}

// l=1/l=2: w-term combined inline from P-tables (MODE = number-of-basis variant)
template <int MODE>
__global__ void attn13_kernel(const float* __restrict__ qkv, const int* __restrict__ adj,
        const float* __restrict__ c0a, const float* __restrict__ c1a, const float* __restrict__ c2a,
        const float* __restrict__ c0b, const float* __restrict__ c1b, const float* __restrict__ c2b,
        const float* __restrict__ PX, const float* __restrict__ PY, const float* __restrict__ PE,
        bf16* __restrict__ o) {
    const float* q = qkv;
    const float* k = qkv + (size_t)512 * H_;
    const float* v = qkv + (size_t)1024 * H_;
    int bi = blockIdx.x;
    int b  = bi >> 6, i = bi & 63;
    int ty = threadIdx.y;
    int h  = blockIdx.y * 4 + ty;
    int lane = threadIdx.x;
    __shared__ float qs[4][64], as[4][64];
    qs[ty][lane] = q[(size_t)bi * H_ + h * 64 + lane];
    __syncthreads();

    int j = lane;
    int p = bi * 64 + j;
    int t = adj[p];
    size_t pb = (((size_t)b * 8 + h) * 64 + i) * 64;
    float acc;
    if (MODE == 1) {
        acc = c0a[p] * PE[pb + t] + c1a[p] * PX[pb + i] + c2a[p] * PX[pb + j];
    } else {
        float a0 = c0b[p];
        float AE = a0 * c0a[p], Aa = a0 * c1a[p], Ab = a0 * c2a[p];
        float Ac = c1b[p], Ad = c2b[p];
        acc = AE * PE[pb + t] + Aa * PX[pb + i] + Ab * PX[pb + j]
            + Ac * PY[pb + i] + Ad * PY[pb + j];
    }
    const float4* k4 = (const float4*)(k + (size_t)(b * 64 + j) * H_ + h * 64);
    #pragma unroll
    for (int tt = 0; tt < 8; ++tt) {
        float4 ka = k4[2 * tt], kb = k4[2 * tt + 1];
        const float* qq = &qs[ty][tt * 8];
        acc += qq[0] * ka.x + qq[1] * ka.y + qq[2] * ka.z + qq[3] * ka.w
             + qq[4] * kb.x + qq[5] * kb.y + qq[6] * kb.z + qq[7] * kb.w;
    }
    float logit = acc * INV_SCALE;
    if (t <= 0) logit = -INFINITY;

    float m = logit;
    #pragma unroll
    for (int off = 32; off; off >>= 1) m = fmaxf(m, __shfl_xor(m, off));
    float pe = expf(logit - m);
    float s = pe;
    #pragma unroll
    for (int off = 32; off; off >>= 1) s += __shfl_xor(s, off);
    as[ty][lane] = pe / s;
    __syncthreads();

    const float* vbase = v + (size_t)(b * 64) * H_ + h * 64;
    float oacc = 0.f;
    int d = lane;
    #pragma unroll 8
    for (int jj = 0; jj < 64; ++jj)
        oacc += as[ty][jj] * vbase[(size_t)jj * H_ + d];
    o[(size_t)bi * H_ + h * 64 + d] = __float2bfloat16(oacc);
}

// layer-3 variant: w-term from precomputed s2
__global__ void attn3_kernel(const float* __restrict__ qkv, const float* __restrict__ s2,
                             const int* __restrict__ adj, bf16* __restrict__ o) {
    const float* q = qkv;
    const float* k = qkv + (size_t)512 * H_;
    const float* v = qkv + (size_t)1024 * H_;
    int bi = blockIdx.x;
    int b  = bi >> 6, i = bi & 63;
    int ty = threadIdx.y;
    int h  = blockIdx.y * 4 + ty;
    int lane = threadIdx.x;
    __shared__ float qs[4][64], as[4][64];
    qs[ty][lane] = q[(size_t)bi * H_ + h * 64 + lane];
    __syncthreads();

    int j = lane;
    const float4* k4 = (const float4*)(k + (size_t)(b * 64 + j) * H_ + h * 64);
    float acc = s2[(((size_t)b * 8 + h) * 64 + i) * 64 + j];
    #pragma unroll
    for (int t = 0; t < 8; ++t) {
        float4 ka = k4[2 * t], kb = k4[2 * t + 1];
        const float* qq = &qs[ty][t * 8];
        acc += qq[0] * ka.x + qq[1] * ka.y + qq[2] * ka.z + qq[3] * ka.w
             + qq[4] * kb.x + qq[5] * kb.y + qq[6] * kb.z + qq[7] * kb.w;
    }
    float logit = acc * INV_SCALE;
    if (adj[(size_t)bi * 64 + j] <= 0) logit = -INFINITY;

    float m = logit;
    #pragma unroll
    for (int off = 32; off; off >>= 1) m = fmaxf(m, __shfl_xor(m, off));
    float p = expf(logit - m);
    float s = p;
    #pragma unroll
    for (int off = 32; off; off >>= 1) s += __shfl_xor(s, off);
    as[ty][lane] = p / s;
    __syncthreads();

    const float* vbase = v + (size_t)(b * 64) * H_ + h * 64;
    float oacc = 0.f;
    int d = lane;
    #pragma unroll 8
    for (int jj = 0; jj < 64; ++jj)
        oacc += as[ty][jj] * vbase[(size_t)jj * H_ + d];
    o[(size_t)bi * H_ + h * 64 + d] = __float2bfloat16(oacc);
}

// ---------------------------------------------------------------- edge coeffs (l=0 only)
template <bool GATHER>
__global__ void edge_coeff_kernel(const bf16* __restrict__ ewsrc, const int* __restrict__ adj,
                                  const float* __restrict__ x,
                                  float* __restrict__ w0o, float* __restrict__ w1o,
                                  float* __restrict__ w2o) {
    int pair = blockIdx.x * 4 + threadIdx.y;
    int b = pair >> 12;
    int i = (pair >> 6) & 63;
    int j = pair & 63;
    int lane = threadIdx.x;
    const uint4*  e4  = (const uint4*)(GATHER ? ewsrc + (size_t)adj[pair] * H_
                                              : ewsrc + (size_t)pair * H_);
    const float4* xi4 = (const float4*)(x + (size_t)(b * 64 + i) * H_);
    const float4* xj4 = (const float4*)(x + (size_t)(b * 64 + j) * H_);
    uint4  eu = e4[lane];
    float4 a0 = xi4[lane * 2], a1 = xi4[lane * 2 + 1];
    float4 c0 = xj4[lane * 2], c1 = xj4[lane * 2 + 1];
    float ef[8], af[8], cf[8];
    unpack8(eu, ef);
    af[0] = a0.x; af[1] = a0.y; af[2] = a0.z; af[3] = a0.w;
    af[4] = a1.x; af[5] = a1.y; af[6] = a1.z; af[7] = a1.w;
    cf[0] = c0.x; cf[1] = c0.y; cf[2] = c0.z; cf[3] = c0.w;
    cf[4] = c1.x; cf[5] = c1.y; cf[6] = c1.z; cf[7] = c1.w;
    float s0 = 0.f, s1 = 0.f, s2 = 0.f;
    #pragma unroll
    for (int t = 0; t < 8; ++t) {
        s0 += ef[t] * ef[t]; s1 += ef[t] * af[t]; s2 += ef[t] * cf[t];
    }
    #pragma unroll
    for (int off = 32; off; off >>= 1) {
        s0 += __shfl_xor(s0, off);
        s1 += __shfl_xor(s1, off);
        s2 += __shfl_xor(s2, off);
    }
    float t0 = s0 * INV_SCALE, t1 = s1 * INV_SCALE, t2 = s2 * INV_SCALE;
    float m = fmaxf(t0, fmaxf(t1, t2));
    float e0 = expf(t0 - m), e1 = expf(t1 - m), e2 = expf(t2 - m);
    float inv = 1.0f / (e0 + e1 + e2);
    if (lane == 0) {
        w0o[pair] = e0 * inv;
        w1o[pair] = e1 * inv;
        w2o[pair] = e2 * inv;
    }
}

// ---------------------------------------------------------------- head
__global__ void cls_part_kernel(const float* __restrict__ x, const float* __restrict__ Wout,
                                float* __restrict__ clspart) {
    int b  = blockIdx.x;
    int cb = blockIdx.y;
    int ks = blockIdx.z;
    int tid = threadIdx.x;
    int c  = cb * 64 + (tid & 63);
    int kk = tid >> 6;
    const float* xr = x + (size_t)(b * 64) * H_;
    int h0 = ks * 128 + kk * 32;
    float acc = 0.f;
    #pragma unroll
    for (int h = 0; h < 32; ++h)
        acc += xr[h0 + h] * Wout[(size_t)(h0 + h) * H_ + c];
    __shared__ float red[4][64];
    red[kk][tid & 63] = acc;
    __syncthreads();
    if (tid < 64) {
        float v = red[0][tid] + red[1][tid] + red[2][tid] + red[3][tid];
        clspart[((size_t)ks * 8 + b) * H_ + cb * 64 + tid] = v;
    }
}

__global__ void cls_pred2_kernel(const float* __restrict__ clspart,
                                 const float* __restrict__ Wpred,
                                 const float* __restrict__ bpred,
                                 float* __restrict__ out) {
    int b = blockIdx.x;
    int tid = threadIdx.x;
    __shared__ float red0[4], red1[4];
    float a0 = 0.f, a1 = 0.f;
    #pragma unroll
    for (int t = 0; t < 2; ++t) {
        int c = tid + t * 256;
        float v = clspart[((size_t)0 * 8 + b) * H_ + c]
                + clspart[((size_t)1 * 8 + b) * H_ + c]
                + clspart[((size_t)2 * 8 + b) * H_ + c]
                + clspart[((size_t)3 * 8 + b) * H_ + c];
        float tv = tanhf(v);
        a0 += tv * Wpred[c * 2 + 0];
        a1 += tv * Wpred[c * 2 + 1];
    }
    #pragma unroll
    for (int off = 32; off; off >>= 1) {
        a0 += __shfl_xor(a0, off);
        a1 += __shfl_xor(a1, off);
    }
    int w = tid >> 6;
    if ((tid & 63) == 0) { red0[w] = a0; red1[w] = a1; }
    __syncthreads();
    if (tid == 0) {
        float s0 = red0[0] + red0[1] + red0[2] + red0[3] + bpred[0];
        float s1 = red1[0] + red1[1] + red1[2] + red1[3] + bpred[1];
        float m = fmaxf(s0, s1);
        float e0 = expf(s0 - m), e1 = expf(s1 - m);
        float inv = 1.0f / (e0 + e1);
        out[b * 2 + 0] = e0 * inv;
        out[b * 2 + 1] = e1 * inv;
    }
}

// ---------------------------------------------------------------- launch
extern "C" void kernel_launch(void* const* d_in, const int* in_sizes, int n_in,
                              void* d_out, int out_size, void* d_ws, size_t ws_size,
                              hipStream_t stream) {
    const int*   ids      = (const int*)d_in[0];
    const int*   adj      = (const int*)d_in[1];
    const float* atom_emb = (const float*)d_in[2];
    const float* bond_emb = (const float*)d_in[3];
    const float* Wq     = (const float*)d_in[4];
    const float* Wk     = (const float*)d_in[5];
    const float* Wv     = (const float*)d_in[6];
    const float* Wew    = (const float*)d_in[7];
    const float* Wstack = (const float*)d_in[8];
    const float* Wf1    = (const float*)d_in[9];
    const float* Wf2    = (const float*)d_in[10];
    const float* Wout   = (const float*)d_in[11];
    const float* Wpred  = (const float*)d_in[12];
    const float* bpred  = (const float*)d_in[13];

    char* ws = (char*)d_ws;
    size_t off = 0;
    auto alloc = [&](size_t bytes) {
        size_t o = off;
        off += (bytes + 255) & ~(size_t)255;
        return o;
    };
    const size_t ROWS  = (size_t)B_ * N_;
    const size_t PAIRS = (size_t)B_ * N_ * N_;
    const size_t KN    = (size_t)H_ * H_;

    float* x       = (float*)(ws + alloc(ROWS * H_ * 4));
    float* xn      = (float*)(ws + alloc(ROWS * H_ * 4));
    bf16*  xn_bf   = (bf16*) (ws + alloc(ROWS * H_ * 2));
    bf16*  x_bf    = (bf16*) (ws + alloc(ROWS * H_ * 2));
    float* qkv     = (float*)(ws + alloc(3 * ROWS * H_ * 4));
    bf16*  o_bf    = (bf16*) (ws + alloc(ROWS * H_ * 2));
    float* resid   = (float*)(ws + alloc(ROWS * H_ * 4));
    bf16*  ffin_bf = (bf16*) (ws + alloc(ROWS * H_ * 2));
    bf16*  ffh_bf  = (bf16*) (ws + alloc(ROWS * 4 * H_ * 2));
    float* part    = (float*)(ws + alloc(4 * ROWS * H_ * 4));
    float* clspart = (float*)(ws + alloc(4 * 8 * H_ * 4));
    bf16*  ubf     = (bf16*) (ws + alloc(ROWS * 8 * 512 * 2));           // 4 MB
    float* s2buf   = (float*)(ws + alloc((size_t)B_ * 8 * 64 * 64 * 4)); // 1 MB
    float* MX      = (float*)(ws + alloc((size_t)4096 * 64 * 4));        // 1 MB
    float* MY      = (float*)(ws + alloc((size_t)4096 * 64 * 4));
    float* MZ      = (float*)(ws + alloc((size_t)4096 * 64 * 4));
    float* DE      = (float*)(ws + alloc((size_t)4096 * 64 * 4));
    float* PT0     = (float*)(ws + alloc((size_t)4096 * 64 * 4));        // P-tables
    float* PT1     = (float*)(ws + alloc((size_t)4096 * 64 * 4));
    float* PT2     = (float*)(ws + alloc((size_t)4096 * 64 * 4));
    float* gbuf    = (float*)(ws + alloc((size_t)9 * 8 * 4096 * 4));     // Gram tables
    bf16*  wc3     = (bf16*) (ws + alloc(KN * 2));
    bf16*  E0      = (bf16*) (ws + alloc(64 * H_ * 2));      // padded to 64 rows
    bf16*  e0w1    = (bf16*) (ws + alloc(64 * H_ * 2));
    bf16*  e0w12   = (bf16*) (ws + alloc(64 * H_ * 2));
    bf16*  xw1     = (bf16*) (ws + alloc(KN * 2));
    bf16*  xw12    = (bf16*) (ws + alloc(KN * 2));
    bf16*  x2w2    = (bf16*) (ws + alloc(KN * 2));
    float* cw      = (float*)(ws + alloc(9 * PAIRS * 4));    // edge softmax coeffs
    bf16*  qkvt    = (bf16*) (ws + alloc((size_t)L_ * 3 * KN * 2));
    bf16*  ewt     = (bf16*) (ws + alloc((size_t)L_ * KN * 2));
    bf16*  stackt  = (bf16*) (ws + alloc((size_t)L_ * KN * 2));
    bf16*  f1t     = (bf16*) (ws + alloc((size_t)L_ * 4 * KN * 2));
    bf16*  f2t     = (bf16*) (ws + alloc((size_t)L_ * 4 * KN * 2));
    (void)ws_size;

    float* cw0a = cw;
    float* cw1a = cw + PAIRS;
    float* cw2a = cw + 2 * PAIRS;
    float* cw0b = cw + 3 * PAIRS;
    float* cw1b = cw + 4 * PAIRS;
    float* cw2b = cw + 5 * PAIRS;
    float* cw0c = cw + 6 * PAIRS;
    float* cw1c = cw + 7 * PAIRS;
    float* cw2c = cw + 8 * PAIRS;

    embed_ln_kernel<<<512, 256, 0, stream>>>(ids, atom_emb, xn, xn_bf);

    dim3 tb(32, 8);
    transpose_sq<<<dim3(16, 16, 20), tb, 0, stream>>>(Wq, Wk, Wv, Wew, Wstack,
                                                      qkvt, ewt, stackt);
    transpose_rect<<<dim3(64, 64, 8), tb, 0, stream>>>(Wf1, Wf2, f1t, f2t);

    ew0_precompute<<<dim3(64, 8), 64, 0, stream>>>(bond_emb, ewt, E0);
    cast_w3<<<128, 256, 0, stream>>>(Wew + 3 * KN, wc3);

    for (int l = 0; l < L_; ++l) {
        if (l == 0) {
            mfma_gemm_s<0, false><<<dim3(8, 8, 3), 256, 0, stream>>>(
                xn_bf, qkvt, qkv, nullptr, 512, 512, 512);
            attn_kernel<true><<<dim3(512, 2), dim3(64, 4), 0, stream>>>(qkv, E0, adj, o_bf);
        } else if (l == 1) {
            basis1_qkv_kernel<<<dim3(33, 8), 256, 0, stream>>>(
                x_bf, E0, ewt + KN, xw1, e0w1, xn_bf, qkvt + (size_t)3 * KN, qkv);
            ptable_kernel<<<dim3(8, 8, 2), 256, 0, stream>>>(
                qkv, xw1, e0w1, nullptr, PT0, PT1, nullptr);
            attn13_kernel<1><<<dim3(512, 2), dim3(64, 4), 0, stream>>>(
                qkv, adj, cw0a, cw1a, cw2a, nullptr, nullptr, nullptr,
                PT0, nullptr, PT1, o_bf);
        } else if (l == 2) {
            basis2_qkv_kernel<<<dim3(41, 8), 256, 0, stream>>>(
                xw1, x_bf, e0w1, ewt + 2 * KN, xw12, x2w2, e0w12,
                xn_bf, qkvt + (size_t)6 * KN, qkv);
            ptable_kernel<<<dim3(8, 8, 3), 256, 0, stream>>>(
                qkv, xw12, x2w2, e0w12, PT0, PT1, PT2);
            attn13_kernel<2><<<dim3(512, 2), dim3(64, 4), 0, stream>>>(
                qkv, adj, cw0a, cw1a, cw2a, cw0b, cw1b, cw2b,
                PT0, PT1, PT2, o_bf);
        } else {
            // l=3: fully implicit via u / M-tables
            mfma_gemm_s<0, false><<<dim3(8, 8, 3), 256, 0, stream>>>(
                xn_bf, qkvt + (size_t)9 * KN, qkv, nullptr, 512, 512, 512);
            u_gemm<<<dim3(8, 8, 8), 256, 0, stream>>>(qkv, wc3, ubf);
            mbuf_gemm<<<dim3(8, 8, 4), 256, 0, stream>>>(ubf, xw12, x2w2, x_bf, e0w12,
                                                         MX, MY, MZ, DE);
            s2_assemble<<<512, dim3(64, 8), 0, stream>>>(adj,
                cw0a, cw1a, cw2a, cw0b, cw1b, cw2b, cw0c, cw1c, cw2c,
                MX, MY, MZ, DE, s2buf);
            attn3_kernel<<<dim3(512, 2), dim3(64, 4), 0, stream>>>(qkv, s2buf, adj, o_bf);
        }

        mfma_gemm_s<0, true><<<dim3(8, 8, 4), 256, 0, stream>>>(
            o_bf, stackt + (size_t)l * KN, part, nullptr, 512, 512, 512);
        reduce_stack_ln<<<512, 256, 0, stream>>>(part, xn, resid, ffin_bf);
        mfma_gemm_s<2, false><<<dim3(8, 32), 256, 0, stream>>>(
            ffin_bf, f1t + (size_t)l * 4 * KN, ffh_bf, nullptr, 512, 2048, 512);
        mfma_gemm_s<0, true><<<dim3(8, 8, 4), 256, 0, stream>>>(
            ffh_bf, f2t + (size_t)l * 4 * KN, part, nullptr, 512, 512, 2048);
        if (l < L_ - 1)
            reduce_ln_kernel<true><<<512, 256, 0, stream>>>(part, resid, x, x_bf, xn, xn_bf);
        else
            reduce_ln_kernel<false><<<512, 256, 0, stream>>>(part, resid, x, x_bf, xn, xn_bf);

        if (l == 0) {
            edge_coeff_kernel<true><<<8192, dim3(64, 4), 0, stream>>>(
                E0, adj, x, cw0a, cw1a, cw2a);
        } else if (l == 1) {
            gram1_kernel<<<dim3(8, 5), 256, 0, stream>>>(xw1, e0w1, x_bf, gbuf);
            coeff_assemble1<<<512, 64, 0, stream>>>(adj, cw0a, cw1a, cw2a, gbuf,
                                                    cw0b, cw1b, cw2b);
        } else if (l == 2) {
            gram2_kernel<<<dim3(8, 9), 256, 0, stream>>>(xw12, x2w2, e0w12, x_bf, gbuf);
            coeff_assemble2<<<512, 64, 0, stream>>>(adj, cw0a, cw1a, cw2a,
                                                    cw0b, cw1b, cw2b, gbuf,
                                                    cw0c, cw1c, cw2c);
        }
    }

    cls_part_kernel<<<dim3(8, 8, 4), 256, 0, stream>>>(x, Wout, clspart);
    cls_pred2_kernel<<<8, 256, 0, stream>>>(clspart, Wpred, bpred, (float*)d_out);
}

// Round 5
// 382.429 us; speedup vs baseline: 1.3003x; 1.0288x over previous
//
#include <hip/hip_runtime.h>
#include <hip/hip_bf16.h>

typedef __hip_bfloat16 bf16;

#define B_     8
#define N_     64
#define H_     512
#define HEADS_ 8
#define SP_    64
#define L_     4
static constexpr float INV_SCALE = 0.044194173824159216f; // 1/sqrt(512)

typedef __attribute__((ext_vector_type(8))) short short8;
typedef __attribute__((ext_vector_type(4))) float f32x4;

__device__ __forceinline__ void unpack8(uint4 u, float* f) {
    f[0] = __uint_as_float(u.x << 16); f[1] = __uint_as_float(u.x & 0xffff0000u);
    f[2] = __uint_as_float(u.y << 16); f[3] = __uint_as_float(u.y & 0xffff0000u);
    f[4] = __uint_as_float(u.z << 16); f[5] = __uint_as_float(u.z & 0xffff0000u);
    f[6] = __uint_as_float(u.w << 16); f[7] = __uint_as_float(u.w & 0xffff0000u);
}

__device__ __forceinline__ bf16 f2bf(float v) { return __float2bfloat16(v); }

__device__ __forceinline__ uint4 pack8bf(float4 a, float4 b) {
    __align__(16) bf16 t[8];
    t[0] = f2bf(a.x); t[1] = f2bf(a.y); t[2] = f2bf(a.z); t[3] = f2bf(a.w);
    t[4] = f2bf(b.x); t[5] = f2bf(b.y); t[6] = f2bf(b.z); t[7] = f2bf(b.w);
    return *(const uint4*)t;
}

#define RSTR 80

// ------------------------------------------------------------ GEMM body (64-tile)
// EPI: 0 = fp32 out, 1 = fp32 + residual, 2 = relu->bf16, 3 = bf16
template <int EPI>
__device__ __forceinline__ void gemm64_body(char* lds,
        const bf16* __restrict__ A, const bf16* __restrict__ Bt,
        void* __restrict__ Cv, const float* __restrict__ R,
        int M, int N, int K, int bx, int by, int kbeg, int kend) {
    char* As = lds;
    char* Bs = lds + 2 * 64 * RSTR;
    const int tid = threadIdx.x;
    const int bm = bx * 64, bn = by * 64;
    const int w = tid >> 6, lane = tid & 63;
    const int wr = (w >> 1) * 32, wc = (w & 1) * 32;
    const int m0 = lane & 15, q4 = lane >> 4;

    f32x4 acc[2][2] = {};

    const int rA = tid >> 3;
    const int cA = tid & 7;
    const int ksP = cA >> 2;
    const int cB = (cA & 3) * 16;
    const int cE = cA * 8;

    for (int k0 = kbeg; k0 < kend; k0 += 64) {
        uint4 a0 = *(const uint4*)(A  + (size_t)(bm + rA) * K + k0 + cE);
        uint4 a1 = *(const uint4*)(A  + (size_t)(bm + rA + 32) * K + k0 + cE);
        uint4 b0 = *(const uint4*)(Bt + (size_t)(bn + rA) * K + k0 + cE);
        uint4 b1 = *(const uint4*)(Bt + (size_t)(bn + rA + 32) * K + k0 + cE);
        __syncthreads();
        *(uint4*)(As + ksP * (64 * RSTR) + rA * RSTR + cB) = a0;
        *(uint4*)(As + ksP * (64 * RSTR) + (rA + 32) * RSTR + cB) = a1;
        *(uint4*)(Bs + ksP * (64 * RSTR) + rA * RSTR + cB) = b0;
        *(uint4*)(Bs + ksP * (64 * RSTR) + (rA + 32) * RSTR + cB) = b1;
        __syncthreads();
        short8 af[2][2], bfr[2][2];
        #pragma unroll
        for (int ks = 0; ks < 2; ++ks)
            #pragma unroll
            for (int t = 0; t < 2; ++t) {
                af[ks][t]  = *(const short8*)(As + ks * (64 * RSTR) + (wr + t * 16 + m0) * RSTR + q4 * 16);
                bfr[ks][t] = *(const short8*)(Bs + ks * (64 * RSTR) + (wc + t * 16 + m0) * RSTR + q4 * 16);
            }
        #pragma unroll
        for (int ks = 0; ks < 2; ++ks)
            #pragma unroll
            for (int mt = 0; mt < 2; ++mt)
                #pragma unroll
                for (int nt = 0; nt < 2; ++nt)
                    acc[mt][nt] = __builtin_amdgcn_mfma_f32_16x16x32_bf16(
                        af[ks][mt], bfr[ks][nt], acc[mt][nt], 0, 0, 0);
    }

    if (EPI <= 1) {
        float* C = (float*)Cv;
        #pragma unroll
        for (int mt = 0; mt < 2; ++mt)
            #pragma unroll
            for (int i = 0; i < 4; ++i) {
                int row = bm + wr + mt * 16 + q4 * 4 + i;
                #pragma unroll
                for (int nt = 0; nt < 2; ++nt) {
                    int col = bn + wc + nt * 16 + m0;
                    float v = acc[mt][nt][i];
                    if (EPI == 1) v += R[(size_t)row * N + col];
                    C[(size_t)row * N + col] = v;
                }
            }
    } else {
        bf16* C = (bf16*)Cv;
        #pragma unroll
        for (int mt = 0; mt < 2; ++mt)
            #pragma unroll
            for (int i = 0; i < 4; ++i) {
                int row = bm + wr + mt * 16 + q4 * 4 + i;
                #pragma unroll
                for (int nt = 0; nt < 2; ++nt) {
                    int col = bn + wc + nt * 16 + m0;
                    float v = acc[mt][nt][i];
                    if (EPI == 2) v = fmaxf(v, 0.0f);
                    C[(size_t)row * N + col] = __float2bfloat16(v);
                }
            }
    }
}

template <int EPI, bool SPLIT>
__launch_bounds__(256)
__global__ void mfma_gemm_s(const bf16* __restrict__ A, const bf16* __restrict__ Bt,
                            void* __restrict__ Cv, const float* __restrict__ R,
                            int M, int N, int K) {
    __shared__ __align__(16) char lds[4 * 64 * RSTR];
    int kbeg = 0, kend = K;
    const bf16* B2 = Bt;
    void* C2 = Cv;
    if (SPLIT) {
        int ks = K / gridDim.z;
        kbeg = blockIdx.z * ks;
        kend = kbeg + ks;
        C2 = (void*)((float*)Cv + (size_t)blockIdx.z * M * N);
        gemm64_body<0>(lds, A, B2, C2, nullptr, M, N, K, blockIdx.x, blockIdx.y, kbeg, kend);
    } else {
        B2 = Bt + (size_t)blockIdx.z * N * K;
        if (EPI <= 1) C2 = (void*)((float*)Cv + (size_t)blockIdx.z * M * N);
        gemm64_body<EPI>(lds, A, B2, C2, R, M, N, K, blockIdx.x, blockIdx.y, kbeg, kend);
    }
}

// ------------------------------------------------ device bodies (shared pieces)

// per-(b,h) q . basis^T : P[(b,h,i,r)] = sum_{d<64} q[b,i,h*64+d] * Bz[r,h*64+d]
__device__ __forceinline__ void ptable_body(char* lds, const float* __restrict__ q,
        const bf16* __restrict__ Bt, float* __restrict__ P, int b, int h, bool shr) {
    char* As = lds;
    char* Bs = lds + 2 * 64 * RSTR;
    const int tid = threadIdx.x;
    const int w = tid >> 6, lane = tid & 63;
    const int wr = (w >> 1) * 32, wc = (w & 1) * 32;
    const int m0 = lane & 15, q4 = lane >> 4;
    const int rA = tid >> 3;
    const int cA = tid & 7;
    const int ksP = cA >> 2;
    const int cB = (cA & 3) * 16;
    const int cE = cA * 8;

    const float* Aq = q + (size_t)(b * 64) * 512 + h * 64;
    const bf16*  Bb = Bt + (shr ? (size_t)0 : (size_t)b * 64 * 512) + h * 64;

    float4 fa0 = *(const float4*)(Aq + (size_t)rA * 512 + cE);
    float4 fa1 = *(const float4*)(Aq + (size_t)rA * 512 + cE + 4);
    float4 fb0 = *(const float4*)(Aq + (size_t)(rA + 32) * 512 + cE);
    float4 fb1 = *(const float4*)(Aq + (size_t)(rA + 32) * 512 + cE + 4);
    uint4 bv0 = *(const uint4*)(Bb + (size_t)rA * 512 + cE);
    uint4 bv1 = *(const uint4*)(Bb + (size_t)(rA + 32) * 512 + cE);
    uint4 av0 = pack8bf(fa0, fa1);
    uint4 av1 = pack8bf(fb0, fb1);
    *(uint4*)(As + ksP * (64 * RSTR) + rA * RSTR + cB) = av0;
    *(uint4*)(As + ksP * (64 * RSTR) + (rA + 32) * RSTR + cB) = av1;
    *(uint4*)(Bs + ksP * (64 * RSTR) + rA * RSTR + cB) = bv0;
    *(uint4*)(Bs + ksP * (64 * RSTR) + (rA + 32) * RSTR + cB) = bv1;
    __syncthreads();

    f32x4 acc[2][2] = {};
    short8 af[2][2], bfr[2][2];
    #pragma unroll
    for (int ks = 0; ks < 2; ++ks)
        #pragma unroll
        for (int t = 0; t < 2; ++t) {
            af[ks][t]  = *(const short8*)(As + ks * (64 * RSTR) + (wr + t * 16 + m0) * RSTR + q4 * 16);
            bfr[ks][t] = *(const short8*)(Bs + ks * (64 * RSTR) + (wc + t * 16 + m0) * RSTR + q4 * 16);
        }
    #pragma unroll
    for (int ks = 0; ks < 2; ++ks)
        #pragma unroll
        for (int mt = 0; mt < 2; ++mt)
            #pragma unroll
            for (int nt = 0; nt < 2; ++nt)
                acc[mt][nt] = __builtin_amdgcn_mfma_f32_16x16x32_bf16(
                    af[ks][mt], bfr[ks][nt], acc[mt][nt], 0, 0, 0);

    #pragma unroll
    for (int mt = 0; mt < 2; ++mt)
        #pragma unroll
        for (int i = 0; i < 4; ++i) {
            int row = wr + mt * 16 + q4 * 4 + i;
            #pragma unroll
            for (int nt = 0; nt < 2; ++nt) {
                int col = wc + nt * 16 + m0;
                P[(((size_t)b * 8 + h) * 64 + row) * 64 + col] = acc[mt][nt][i];
            }
        }
}

// u_bf[b,i,h,k] = sum_d q[b,i,h*64+d] * Wew3[k,h*64+d]
__device__ __forceinline__ void ugemm_body(char* lds, const float* __restrict__ q,
        const bf16* __restrict__ wc3, bf16* __restrict__ ubf, int h, int mb, int nb) {
    char* As = lds;
    char* Bs = lds + 2 * 64 * RSTR;
    const int tid = threadIdx.x;
    const int w = tid >> 6, lane = tid & 63;
    const int wr = (w >> 1) * 32, wc = (w & 1) * 32;
    const int m0 = lane & 15, q4 = lane >> 4;
    const int rA = tid >> 3;
    const int cA = tid & 7;
    const int ksP = cA >> 2;
    const int cB = (cA & 3) * 16;
    const int cE = cA * 8;

    const float* Aq = q + (size_t)(mb * 64) * 512 + h * 64;
    const bf16*  Bt = wc3 + (size_t)(nb * 64) * 512 + h * 64;

    float4 fa0 = *(const float4*)(Aq + (size_t)rA * 512 + cE);
    float4 fa1 = *(const float4*)(Aq + (size_t)rA * 512 + cE + 4);
    float4 fb0 = *(const float4*)(Aq + (size_t)(rA + 32) * 512 + cE);
    float4 fb1 = *(const float4*)(Aq + (size_t)(rA + 32) * 512 + cE + 4);
    uint4 b0 = *(const uint4*)(Bt + (size_t)rA * 512 + cE);
    uint4 b1 = *(const uint4*)(Bt + (size_t)(rA + 32) * 512 + cE);
    uint4 a0 = pack8bf(fa0, fa1);
    uint4 a1 = pack8bf(fb0, fb1);
    *(uint4*)(As + ksP * (64 * RSTR) + rA * RSTR + cB) = a0;
    *(uint4*)(As + ksP * (64 * RSTR) + (rA + 32) * RSTR + cB) = a1;
    *(uint4*)(Bs + ksP * (64 * RSTR) + rA * RSTR + cB) = b0;
    *(uint4*)(Bs + ksP * (64 * RSTR) + (rA + 32) * RSTR + cB) = b1;
    __syncthreads();

    f32x4 acc[2][2] = {};
    short8 af[2][2], bfr[2][2];
    #pragma unroll
    for (int ks = 0; ks < 2; ++ks)
        #pragma unroll
        for (int t = 0; t < 2; ++t) {
            af[ks][t]  = *(const short8*)(As + ks * (64 * RSTR) + (wr + t * 16 + m0) * RSTR + q4 * 16);
            bfr[ks][t] = *(const short8*)(Bs + ks * (64 * RSTR) + (wc + t * 16 + m0) * RSTR + q4 * 16);
        }
    #pragma unroll
    for (int ks = 0; ks < 2; ++ks)
        #pragma unroll
        for (int mt = 0; mt < 2; ++mt)
            #pragma unroll
            for (int nt = 0; nt < 2; ++nt)
                acc[mt][nt] = __builtin_amdgcn_mfma_f32_16x16x32_bf16(
                    af[ks][mt], bfr[ks][nt], acc[mt][nt], 0, 0, 0);

    #pragma unroll
    for (int mt = 0; mt < 2; ++mt)
        #pragma unroll
        for (int i = 0; i < 4; ++i) {
            int row = mb * 64 + wr + mt * 16 + q4 * 4 + i;
            #pragma unroll
            for (int nt = 0; nt < 2; ++nt) {
                int col = nb * 64 + wc + nt * 16 + m0;
                ubf[(size_t)row * 4096 + h * 512 + col] = f2bf(acc[mt][nt][i]);
            }
        }
}

// edge softmax coeffs from l=1 Gram tables (per-thread; row=(b,i), j)
__device__ __forceinline__ void coeff1_body(const int* __restrict__ adj,
        const float* __restrict__ c0a, const float* __restrict__ c1a, const float* __restrict__ c2a,
        const float* __restrict__ gbuf, int row, int j,
        float* __restrict__ w0o, float* __restrict__ w1o, float* __restrict__ w2o) {
    int b = row >> 6, i = row & 63;
    int p = row * 64 + j;
    int t = adj[p];
    const float* TXX = gbuf + 0 * 32768 + (size_t)b * 4096;
    const float* TEX = gbuf + 1 * 32768 + (size_t)b * 4096;
    const float* TXx = gbuf + 2 * 32768 + (size_t)b * 4096;
    const float* TEx = gbuf + 3 * 32768 + (size_t)b * 4096;
    const float* TEE = gbuf + 4 * 32768 + (size_t)b * 4096;
    float c0 = c0a[p], c1 = c1a[p], c2 = c2a[p];
    float s1 = c0 * TEx[t * 64 + i] + c1 * TXx[i * 64 + i] + c2 * TXx[j * 64 + i];
    float s2 = c0 * TEx[t * 64 + j] + c1 * TXx[i * 64 + j] + c2 * TXx[j * 64 + j];
    float s0 = c0 * c0 * TEE[t * 64 + t] + c1 * c1 * TXX[i * 64 + i] + c2 * c2 * TXX[j * 64 + j]
             + 2.f * c0 * c1 * TEX[t * 64 + i] + 2.f * c0 * c2 * TEX[t * 64 + j]
             + 2.f * c1 * c2 * TXX[i * 64 + j];
    float t0 = s0 * INV_SCALE, t1 = s1 * INV_SCALE, t2 = s2 * INV_SCALE;
    float m = fmaxf(t0, fmaxf(t1, t2));
    float e0 = expf(t0 - m), e1 = expf(t1 - m), e2 = expf(t2 - m);
    float inv = 1.0f / (e0 + e1 + e2);
    w0o[p] = e0 * inv;
    w1o[p] = e1 * inv;
    w2o[p] = e2 * inv;
}

// edge softmax coeffs from l=2 Gram tables
__device__ __forceinline__ void coeff2_body(const int* __restrict__ adj,
        const float* __restrict__ c0a, const float* __restrict__ c1a, const float* __restrict__ c2a,
        const float* __restrict__ c0b, const float* __restrict__ c1b, const float* __restrict__ c2b,
        const float* __restrict__ gbuf, int row, int j,
        float* __restrict__ w0o, float* __restrict__ w1o, float* __restrict__ w2o) {
    int b = row >> 6, i = row & 63;
    int p = row * 64 + j;
    int t = adj[p];
    const float* TXX = gbuf + 0 * 32768 + (size_t)b * 4096;
    const float* TXY = gbuf + 1 * 32768 + (size_t)b * 4096;
    const float* TYY = gbuf + 2 * 32768 + (size_t)b * 4096;
    const float* TEX = gbuf + 3 * 32768 + (size_t)b * 4096;
    const float* TEY = gbuf + 4 * 32768 + (size_t)b * 4096;
    const float* TEE = gbuf + 5 * 32768 + (size_t)b * 4096;
    const float* TXx = gbuf + 6 * 32768 + (size_t)b * 4096;
    const float* TYx = gbuf + 7 * 32768 + (size_t)b * 4096;
    const float* TEx = gbuf + 8 * 32768 + (size_t)b * 4096;
    float a0 = c0b[p];
    float AE = a0 * c0a[p], Aa = a0 * c1a[p], Ab = a0 * c2a[p];
    float Ac = c1b[p], Ad = c2b[p];
    float s1 = AE * TEx[t * 64 + i] + Aa * TXx[i * 64 + i] + Ab * TXx[j * 64 + i]
             + Ac * TYx[i * 64 + i] + Ad * TYx[j * 64 + i];
    float s2 = AE * TEx[t * 64 + j] + Aa * TXx[i * 64 + j] + Ab * TXx[j * 64 + j]
             + Ac * TYx[i * 64 + j] + Ad * TYx[j * 64 + j];
    float s0 = AE * AE * TEE[t * 64 + t] + Aa * Aa * TXX[i * 64 + i] + Ab * Ab * TXX[j * 64 + j]
             + Ac * Ac * TYY[i * 64 + i] + Ad * Ad * TYY[j * 64 + j]
             + 2.f * AE * Aa * TEX[t * 64 + i] + 2.f * AE * Ab * TEX[t * 64 + j]
             + 2.f * AE * Ac * TEY[t * 64 + i] + 2.f * AE * Ad * TEY[t * 64 + j]
             + 2.f * Aa * Ab * TXX[i * 64 + j]
             + 2.f * Aa * Ac * TXY[i * 64 + i] + 2.f * Aa * Ad * TXY[i * 64 + j]
             + 2.f * Ab * Ac * TXY[j * 64 + i] + 2.f * Ab * Ad * TXY[j * 64 + j]
             + 2.f * Ac * Ad * TYY[i * 64 + j];
    float t0 = s0 * INV_SCALE, t1 = s1 * INV_SCALE, t2 = s2 * INV_SCALE;
    float m = fmaxf(t0, fmaxf(t1, t2));
    float e0 = expf(t0 - m), e1 = expf(t1 - m), e2 = expf(t2 - m);
    float inv = 1.0f / (e0 + e1 + e2);
    w0o[p] = e0 * inv;
    w1o[p] = e1 * inv;
    w2o[p] = e2 * inv;
}

// ------------------------------------------------ merged one-shot setup kernel
// grid layout: [0,512) embed | [512,5632) transpose_sq | [5632,13824) transpose_rect
//              [13824,13952) ew0-direct | [13952,14080) cast_w3
__launch_bounds__(256)
__global__ void setup_kernel(const int* __restrict__ ids, const float* __restrict__ atom_emb,
                             const float* __restrict__ bond_emb,
                             const float* __restrict__ Wq, const float* __restrict__ Wk,
                             const float* __restrict__ Wv, const float* __restrict__ Wew,
                             const float* __restrict__ Wst,
                             const float* __restrict__ Wf1, const float* __restrict__ Wf2,
                             float* __restrict__ xn, bf16* __restrict__ xn_bf,
                             bf16* __restrict__ qkvt, bf16* __restrict__ ewt,
                             bf16* __restrict__ stackt,
                             bf16* __restrict__ f1t, bf16* __restrict__ f2t,
                             bf16* __restrict__ E0, bf16* __restrict__ wc3) {
    __shared__ float smem[32 * 33 + 8];
    const size_t KN = (size_t)H_ * H_;
    int bid = blockIdx.x;
    int tid = threadIdx.x;

    if (bid < 512) {
        // ---- embed + LN
        int row = bid;
        const float* r = atom_emb + (size_t)ids[row] * H_;
        float x0 = r[tid], x1 = r[tid + 256];
        float s = x0 + x1, sq = x0 * x0 + x1 * x1;
        #pragma unroll
        for (int off = 32; off; off >>= 1) {
            s  += __shfl_xor(s,  off);
            sq += __shfl_xor(sq, off);
        }
        int w = tid >> 6;
        if ((tid & 63) == 0) { smem[w] = s; smem[4 + w] = sq; }
        __syncthreads();
        float S = smem[0] + smem[1] + smem[2] + smem[3];
        float Q = smem[4] + smem[5] + smem[6] + smem[7];
        float mean = S * (1.0f / H_);
        float var  = Q * (1.0f / H_) - mean * mean;
        float inv  = rsqrtf(var + 1e-5f);
        float y0 = (x0 - mean) * inv, y1 = (x1 - mean) * inv;
        xn[(size_t)row * H_ + tid]       = y0;
        xn[(size_t)row * H_ + tid + 256] = y1;
        xn_bf[(size_t)row * H_ + tid]       = f2bf(y0);
        xn_bf[(size_t)row * H_ + tid + 256] = f2bf(y1);
    } else if (bid < 5632) {
        // ---- square transposes (Wq/Wk/Wv/Wew/Wstack)
        int idx = bid - 512;
        int z = idx >> 8;
        int rem = idx & 255;
        int byv = rem >> 4, bxv = rem & 15;
        const float* W; bf16* Wt;
        if (z < 12) {
            int sss = z >> 2, l = z & 3;
            W  = (sss == 0 ? Wq : sss == 1 ? Wk : Wv) + (size_t)l * KN;
            Wt = qkvt + (size_t)l * 3 * KN + (size_t)sss * KN;
        } else if (z < 16) {
            int l = z - 12;
            W = Wew + (size_t)l * KN; Wt = ewt + (size_t)l * KN;
        } else {
            int l = z - 16;
            W = Wst + (size_t)l * KN; Wt = stackt + (size_t)l * KN;
        }
        float (*tt)[33] = (float(*)[33])smem;
        int k0 = bxv * 32, n0 = byv * 32;
        int tx = tid & 31, tyv = tid >> 5;
        #pragma unroll
        for (int rr = tyv; rr < 32; rr += 8)
            tt[rr][tx] = W[(size_t)(k0 + rr) * H_ + n0 + tx];
        __syncthreads();
        #pragma unroll
        for (int rr = tyv; rr < 32; rr += 8)
            Wt[(size_t)(n0 + rr) * H_ + k0 + tx] = f2bf(tt[tx][rr]);
    } else if (bid < 13824) {
        // ---- rect transposes (Wf1/Wf2), exact grid, no early-outs
        int idx = bid - 5632;
        int z = idx >> 10;
        int idx2 = idx & 1023;
        const size_t KN4 = (size_t)4 * H_ * H_;
        const float* W; bf16* Wt; int K, N, kb, nb;
        if (z < 4) {
            W = Wf1 + (size_t)z * KN4; Wt = f1t + (size_t)z * KN4; K = 512; N = 2048;
            kb = idx2 & 15; nb = idx2 >> 4;
        } else {
            W = Wf2 + (size_t)(z - 4) * KN4; Wt = f2t + (size_t)(z - 4) * KN4; K = 2048; N = 512;
            kb = idx2 & 63; nb = idx2 >> 6;
        }
        float (*tt)[33] = (float(*)[33])smem;
        int k0 = kb * 32, n0 = nb * 32;
        int tx = tid & 31, tyv = tid >> 5;
        #pragma unroll
        for (int rr = tyv; rr < 32; rr += 8)
            tt[rr][tx] = W[(size_t)(k0 + rr) * N + n0 + tx];
        __syncthreads();
        #pragma unroll
        for (int rr = tyv; rr < 32; rr += 8)
            Wt[(size_t)(n0 + rr) * K + k0 + tx] = f2bf(tt[tx][rr]);
    } else if (bid < 13952) {
        // ---- E0 = bond_emb @ Wew0 directly (no transpose dependency); rows 8..63 zero
        int idx = bid - 13824;
        int t = idx >> 1;
        int c = (idx & 1) * 256 + tid;
        if (t >= 8) { E0[t * 512 + c] = f2bf(0.0f); return; }
        float* be = smem;
        be[tid]       = bond_emb[t * 512 + tid];
        be[tid + 256] = bond_emb[t * 512 + tid + 256];
        __syncthreads();
        float acc = 0.f;
        #pragma unroll 8
        for (int h = 0; h < 512; ++h)
            acc += be[h] * Wew[(size_t)h * 512 + c];
        E0[t * 512 + c] = f2bf(acc);
    } else {
        // ---- cast Wew3 -> bf16
        int idx = bid - 13952;
        int gid = idx * 256 + tid;
        const float4* p = (const float4*)(Wew + 3 * KN + (size_t)gid * 8);
        float4 a = p[0], b = p[1];
        *(uint4*)(wc3 + (size_t)gid * 8) = pack8bf(a, b);
    }
}

// ------------------------------------------------ l=1 head: basis1 + qkv + edge_coeff(l=0)
// grid: [0,264) gemm (bx=bid>>3, by=bid&7) | [264,2312) edge-coeff blocks (16 pairs each)
__launch_bounds__(256)
__global__ void basis1_qkv_ec(const bf16* __restrict__ x_bf, const bf16* __restrict__ E0,
                              const bf16* __restrict__ ewt1,
                              bf16* __restrict__ xw1, bf16* __restrict__ e0w1,
                              const bf16* __restrict__ xn_bf, const bf16* __restrict__ qkvt_l,
                              float* __restrict__ qkv,
                              const int* __restrict__ adj, const float* __restrict__ x,
                              float* __restrict__ w0o, float* __restrict__ w1o,
                              float* __restrict__ w2o) {
    __shared__ __align__(16) char lds[4 * 64 * RSTR];
    int bid = blockIdx.x;
    if (bid < 264) {
        int bx = bid >> 3, by = bid & 7;
        if (bx < 8)
            gemm64_body<3>(lds, x_bf, ewt1, xw1, nullptr, 512, 512, 512, bx, by, 0, 512);
        else if (bx == 8)
            gemm64_body<3>(lds, E0, ewt1, e0w1, nullptr, 64, 512, 512, 0, by, 0, 512);
        else {
            int tq = bx - 9;
            int z = tq >> 3, mb = tq & 7;
            gemm64_body<0>(lds, xn_bf, qkvt_l + (size_t)z * 262144,
                           qkv + (size_t)z * 262144, nullptr, 512, 512, 512, mb, by, 0, 512);
        }
    } else {
        int k = bid - 264;
        int tid = threadIdx.x;
        int lane = tid & 63, tyv = tid >> 6;
        for (int pp = 0; pp < 4; ++pp) {
            int pair = k * 16 + pp * 4 + tyv;
            int b = pair >> 12;
            int i = (pair >> 6) & 63;
            int j = pair & 63;
            const uint4*  e4  = (const uint4*)(E0 + (size_t)adj[pair] * H_);
            const float4* xi4 = (const float4*)(x + (size_t)(b * 64 + i) * H_);
            const float4* xj4 = (const float4*)(x + (size_t)(b * 64 + j) * H_);
            uint4  eu = e4[lane];
            float4 a0 = xi4[lane * 2], a1 = xi4[lane * 2 + 1];
            float4 c0 = xj4[lane * 2], c1 = xj4[lane * 2 + 1];
            float ef[8], af[8], cf[8];
            unpack8(eu, ef);
            af[0] = a0.x; af[1] = a0.y; af[2] = a0.z; af[3] = a0.w;
            af[4] = a1.x; af[5] = a1.y; af[6] = a1.z; af[7] = a1.w;
            cf[0] = c0.x; cf[1] = c0.y; cf[2] = c0.z; cf[3] = c0.w;
            cf[4] = c1.x; cf[5] = c1.y; cf[6] = c1.z; cf[7] = c1.w;
            float s0 = 0.f, s1 = 0.f, s2 = 0.f;
            #pragma unroll
            for (int t = 0; t < 8; ++t) {
                s0 += ef[t] * ef[t]; s1 += ef[t] * af[t]; s2 += ef[t] * cf[t];
            }
            #pragma unroll
            for (int off = 32; off; off >>= 1) {
                s0 += __shfl_xor(s0, off);
                s1 += __shfl_xor(s1, off);
                s2 += __shfl_xor(s2, off);
            }
            float t0 = s0 * INV_SCALE, t1 = s1 * INV_SCALE, t2 = s2 * INV_SCALE;
            float m = fmaxf(t0, fmaxf(t1, t2));
            float e0 = expf(t0 - m), e1 = expf(t1 - m), e2 = expf(t2 - m);
            float inv = 1.0f / (e0 + e1 + e2);
            if (lane == 0) {
                w0o[pair] = e0 * inv;
                w1o[pair] = e1 * inv;
                w2o[pair] = e2 * inv;
            }
        }
    }
}

// ------------------------------------------------ l=2 head: basis2 + qkv + gram1
// grid: [0,328) gemm | [328,368) gram1 (b=k&7, z=k>>3)
__launch_bounds__(256)
__global__ void basis2_qkv_g1(const bf16* __restrict__ xw1, const bf16* __restrict__ x_bf,
                              const bf16* __restrict__ e0w1, const bf16* __restrict__ ewt2,
                              bf16* __restrict__ xw12, bf16* __restrict__ x2w2,
                              bf16* __restrict__ e0w12,
                              const bf16* __restrict__ xn_bf, const bf16* __restrict__ qkvt_l,
                              float* __restrict__ qkv, float* __restrict__ gbuf) {
    __shared__ __align__(16) char lds[4 * 64 * RSTR];
    int bid = blockIdx.x;
    if (bid < 328) {
        int bx = bid >> 3, by = bid & 7;
        if (bx < 8)
            gemm64_body<3>(lds, xw1, ewt2, xw12, nullptr, 512, 512, 512, bx, by, 0, 512);
        else if (bx < 16)
            gemm64_body<3>(lds, x_bf, ewt2, x2w2, nullptr, 512, 512, 512, bx - 8, by, 0, 512);
        else if (bx == 16)
            gemm64_body<3>(lds, e0w1, ewt2, e0w12, nullptr, 64, 512, 512, 0, by, 0, 512);
        else {
            int tq = bx - 17;
            int z = tq >> 3, mb = tq & 7;
            gemm64_body<0>(lds, xn_bf, qkvt_l + (size_t)z * 262144,
                           qkv + (size_t)z * 262144, nullptr, 512, 512, 512, mb, by, 0, 512);
        }
    } else {
        int k = bid - 328;
        int b = k & 7, z = k >> 3;
        size_t ob = (size_t)b * 32768;
        const bf16 *A, *Bt;
        switch (z) {
            case 0: A = xw1 + ob; Bt = xw1 + ob; break;
            case 1: A = e0w1;     Bt = xw1 + ob; break;
            case 2: A = xw1 + ob; Bt = x_bf + ob; break;
            case 3: A = e0w1;     Bt = x_bf + ob; break;
            default: A = e0w1;    Bt = e0w1;     break;
        }
        float* C = gbuf + (size_t)z * 32768 + (size_t)b * 4096;
        gemm64_body<0>(lds, A, Bt, C, nullptr, 64, 64, 512, 0, 0, 0, 512);
    }
}

// ------------------------------------------------ l=2: ptable(3) + coeff1
// grid: [0,192) ptable (z=bid>>6, b=(bid&63)>>3, h=bid&7) | [192,256) coeff1 (8 rows each)
__launch_bounds__(256)
__global__ void ptable2c(const float* __restrict__ q,
                         const bf16* __restrict__ B0, const bf16* __restrict__ B1,
                         const bf16* __restrict__ B2,
                         float* __restrict__ P0, float* __restrict__ P1,
                         float* __restrict__ P2,
                         const int* __restrict__ adj,
                         const float* __restrict__ c0a, const float* __restrict__ c1a,
                         const float* __restrict__ c2a, const float* __restrict__ gbuf,
                         float* __restrict__ w0o, float* __restrict__ w1o,
                         float* __restrict__ w2o) {
    __shared__ __align__(16) char lds[4 * 64 * RSTR];
    int bid = blockIdx.x;
    if (bid < 192) {
        int z = bid >> 6, rem = bid & 63;
        int b = rem >> 3, h = rem & 7;
        const bf16* Bt = (z == 0) ? B0 : (z == 1 ? B1 : B2);
        float* P = (z == 0) ? P0 : (z == 1 ? P1 : P2);
        ptable_body(lds, q, Bt, P, b, h, z == 2);
    } else {
        int k = bid - 192;
        int tid = threadIdx.x;
        int j = tid & 63;
        #pragma unroll
        for (int pass = 0; pass < 2; ++pass) {
            int row = k * 8 + pass * 4 + (tid >> 6);
            coeff1_body(adj, c0a, c1a, c2a, gbuf, row, j, w0o, w1o, w2o);
        }
    }
}

// ------------------------------------------------ l=1: ptable (2 bases), standalone
__launch_bounds__(256)
__global__ void ptable_kernel(const float* __restrict__ q,
                              const bf16* __restrict__ B0, const bf16* __restrict__ B1,
                              float* __restrict__ P0, float* __restrict__ P1) {
    __shared__ __align__(16) char lds[4 * 64 * RSTR];
    const int b = blockIdx.x, h = blockIdx.y, z = blockIdx.z;
    const bf16* Bt = (z == 0) ? B0 : B1;
    float* P = (z == 0) ? P0 : P1;
    ptable_body(lds, q, Bt, P, b, h, z == 1);
}

// ------------------------------------------------ l=3 head: qkv + gram2
// grid: [0,192) qkv (z=bid>>6, mb=(bid>>3)&7, by=bid&7) | [192,264) gram2
__launch_bounds__(256)
__global__ void l3qkv_g2(const bf16* __restrict__ xn_bf, const bf16* __restrict__ qkvt_l,
                         float* __restrict__ qkv,
                         const bf16* __restrict__ xw12, const bf16* __restrict__ x2w2,
                         const bf16* __restrict__ e0w12, const bf16* __restrict__ x_bf,
                         float* __restrict__ gbuf) {
    __shared__ __align__(16) char lds[4 * 64 * RSTR];
    int bid = blockIdx.x;
    if (bid < 192) {
        int z = bid >> 6, rem = bid & 63;
        int mb = rem >> 3, by = rem & 7;
        gemm64_body<0>(lds, xn_bf, qkvt_l + (size_t)z * 262144,
                       qkv + (size_t)z * 262144, nullptr, 512, 512, 512, mb, by, 0, 512);
    } else {
        int k = bid - 192;
        int b = k & 7, z = k >> 3;
        size_t ob = (size_t)b * 32768;
        const bf16 *A, *Bt;
        switch (z) {
            case 0: A = xw12 + ob; Bt = xw12 + ob; break;
            case 1: A = xw12 + ob; Bt = x2w2 + ob; break;
            case 2: A = x2w2 + ob; Bt = x2w2 + ob; break;
            case 3: A = e0w12;     Bt = xw12 + ob; break;
            case 4: A = e0w12;     Bt = x2w2 + ob; break;
            case 5: A = e0w12;     Bt = e0w12;     break;
            case 6: A = xw12 + ob; Bt = x_bf + ob; break;
            case 7: A = x2w2 + ob; Bt = x_bf + ob; break;
            default: A = e0w12;    Bt = x_bf + ob; break;
        }
        float* C = gbuf + (size_t)z * 32768 + (size_t)b * 4096;
        gemm64_body<0>(lds, A, Bt, C, nullptr, 64, 64, 512, 0, 0, 0, 512);
    }
}

// ------------------------------------------------ l=3: u_gemm + coeff2
// grid: [0,512) u (h=bid>>6, mb=(bid>>3)&7, nb=bid&7) | [512,576) coeff2 (8 rows each)
__launch_bounds__(256)
__global__ void u_c2(const float* __restrict__ q, const bf16* __restrict__ wc3,
                     bf16* __restrict__ ubf,
                     const int* __restrict__ adj,
                     const float* __restrict__ c0a, const float* __restrict__ c1a,
                     const float* __restrict__ c2a,
                     const float* __restrict__ c0b, const float* __restrict__ c1b,
                     const float* __restrict__ c2b,
                     const float* __restrict__ gbuf,
                     float* __restrict__ w0o, float* __restrict__ w1o,
                     float* __restrict__ w2o) {
    __shared__ __align__(16) char lds[4 * 64 * RSTR];
    int bid = blockIdx.x;
    if (bid < 512) {
        int h = bid >> 6, mb = (bid >> 3) & 7, nb = bid & 7;
        ugemm_body(lds, q, wc3, ubf, h, mb, nb);
    } else {
        int k = bid - 512;
        int tid = threadIdx.x;
        int j = tid & 63;
        #pragma unroll
        for (int pass = 0; pass < 2; ++pass) {
            int row = k * 8 + pass * 4 + (tid >> 6);
            coeff2_body(adj, c0a, c1a, c2a, c0b, c1b, c2b, gbuf, row, j, w0o, w1o, w2o);
        }
    }
}

// M-tables: for each b, U_b (512 rows (i,h) x 512 k) @ basis_b^T (64 x 512)
__launch_bounds__(256)
__global__ void mbuf_gemm(const bf16* __restrict__ ubf, const bf16* __restrict__ xw12,
                          const bf16* __restrict__ x2w2, const bf16* __restrict__ x_bf,
                          const bf16* __restrict__ e0w12,
                          float* __restrict__ MX, float* __restrict__ MY,
                          float* __restrict__ MZ, float* __restrict__ DE) {
    __shared__ __align__(16) char lds[4 * 64 * RSTR];
    int b = blockIdx.x, mt = blockIdx.y, z = blockIdx.z;
    const bf16* A = ubf + (size_t)b * 512 * 512;
    const bf16* Bt;
    float* C;
    if (z == 0)      { Bt = xw12 + (size_t)b * 64 * 512; C = MX + (size_t)b * 512 * 64; }
    else if (z == 1) { Bt = x2w2 + (size_t)b * 64 * 512; C = MY + (size_t)b * 512 * 64; }
    else if (z == 2) { Bt = x_bf + (size_t)b * 64 * 512; C = MZ + (size_t)b * 512 * 64; }
    else             { Bt = e0w12;                        C = DE + (size_t)b * 512 * 64; }
    gemm64_body<0>(lds, A, Bt, C, nullptr, 512, 64, 512, mt, 0, 0, 512);
}

// ---------------------- split-K reduce + residual + LN variants
__global__ void reduce_stack_ln(const float* __restrict__ part, const float* __restrict__ base,
                                float* __restrict__ resid, bf16* __restrict__ ffin_bf) {
    const int MN = 512 * H_;
    int row = blockIdx.x;
    int tid = threadIdx.x;
    size_t b0 = (size_t)row * H_;
    float v0 = base[b0 + tid], v1 = base[b0 + tid + 256];
    #pragma unroll
    for (int s = 0; s < 4; ++s) {
        v0 += part[(size_t)s * MN + b0 + tid];
        v1 += part[(size_t)s * MN + b0 + tid + 256];
    }
    resid[b0 + tid] = v0;
    resid[b0 + tid + 256] = v1;
    float s = v0 + v1, sq = v0 * v0 + v1 * v1;
    #pragma unroll
    for (int off = 32; off; off >>= 1) {
        s  += __shfl_xor(s,  off);
        sq += __shfl_xor(sq, off);
    }
    __shared__ float ls[4], lq[4];
    int w = tid >> 6;
    if ((tid & 63) == 0) { ls[w] = s; lq[w] = sq; }
    __syncthreads();
    float S = ls[0] + ls[1] + ls[2] + ls[3];
    float Q = lq[0] + lq[1] + lq[2] + lq[3];
    float mean = S * (1.0f / H_);
    float var  = Q * (1.0f / H_) - mean * mean;
    float inv  = rsqrtf(var + 1e-5f);
    ffin_bf[b0 + tid]       = f2bf((v0 - mean) * inv);
    ffin_bf[b0 + tid + 256] = f2bf((v1 - mean) * inv);
}

template <bool DO_LN>
__global__ void reduce_ln_kernel(const float* __restrict__ part, const float* __restrict__ resid,
                                 float* __restrict__ x, bf16* __restrict__ x_bf,
                                 float* __restrict__ xn, bf16* __restrict__ xn_bf) {
    const int MN = 512 * H_;
    int row = blockIdx.x;
    int tid = threadIdx.x;
    size_t base = (size_t)row * H_;
    float v0 = resid[base + tid], v1 = resid[base + tid + 256];
    #pragma unroll
    for (int s = 0; s < 4; ++s) {
        v0 += part[(size_t)s * MN + base + tid];
        v1 += part[(size_t)s * MN + base + tid + 256];
    }
    x[base + tid] = v0;
    x[base + tid + 256] = v1;
    x_bf[base + tid]       = f2bf(v0);
    x_bf[base + tid + 256] = f2bf(v1);
    if (DO_LN) {
        float s = v0 + v1, sq = v0 * v0 + v1 * v1;
        #pragma unroll
        for (int off = 32; off; off >>= 1) {
            s  += __shfl_xor(s,  off);
            sq += __shfl_xor(sq, off);
        }
        __shared__ float ls[4], lq[4];
        int w = tid >> 6;
        if ((tid & 63) == 0) { ls[w] = s; lq[w] = sq; }
        __syncthreads();
        float S = ls[0] + ls[1] + ls[2] + ls[3];
        float Q = lq[0] + lq[1] + lq[2] + lq[3];
        float mean = S * (1.0f / H_);
        float var  = Q * (1.0f / H_) - mean * mean;
        float inv  = rsqrtf(var + 1e-5f);
        float y0 = (v0 - mean) * inv, y1 = (v1 - mean) * inv;
        xn[base + tid]       = y0;
        xn[base + tid + 256] = y1;
        xn_bf[base + tid]       = f2bf(y0);
        xn_bf[base + tid + 256] = f2bf(y1);
    }
}

// ---------------------------------------------------------------- attention
// l=0: w-row gathered from E0[adj[pair]] (8-row table, L1-resident)
template <bool GATHER>
__global__ void attn_kernel(const float* __restrict__ qkv, const bf16* __restrict__ ew,
                            const int* __restrict__ adj, bf16* __restrict__ o) {
    const float* q = qkv;
    const float* k = qkv + (size_t)512 * H_;
    const float* v = qkv + (size_t)1024 * H_;
    int bi = blockIdx.x;
    int b  = bi >> 6;
    int ty = threadIdx.y;
    int h  = blockIdx.y * 4 + ty;
    int lane = threadIdx.x;
    __shared__ float qs[4][64], as[4][64];
    qs[ty][lane] = q[(size_t)bi * H_ + h * 64 + lane];
    __syncthreads();

    int j = lane;
    int pair = bi * 64 + j;
    int aj = adj[pair];
    const float4* k4 = (const float4*)(k + (size_t)(b * 64 + j) * H_ + h * 64);
    const uint4*  w4 = (const uint4*)((GATHER ? ew + (size_t)aj * H_
                                              : ew + (size_t)pair * H_) + h * 64);
    float acc = 0.f;
    #pragma unroll
    for (int t = 0; t < 8; ++t) {
        uint4 wu = w4[t];
        float4 ka = k4[2 * t], kb = k4[2 * t + 1];
        float wf[8];
        unpack8(wu, wf);
        const float* qq = &qs[ty][t * 8];
        acc += qq[0] * (ka.x + wf[0]) + qq[1] * (ka.y + wf[1])
             + qq[2] * (ka.z + wf[2]) + qq[3] * (ka.w + wf[3])
             + qq[4] * (kb.x + wf[4]) + qq[5] * (kb.y + wf[5])
             + qq[6] * (kb.z + wf[6]) + qq[7] * (kb.w + wf[7]);
    }
    float logit = acc * INV_SCALE;
    if (aj <= 0) logit = -INFINITY;

    float m = logit;
    #pragma unroll
    for (int off = 32; off; off >>= 1) m = fmaxf(m, __shfl_xor(m, off));
    float p = expf(logit - m);
    float s = p;
    #pragma unroll
    for (int off = 32; off; off >>= 1) s += __shfl_xor(s, off);
    as[ty][lane] = p / s;
    __syncthreads();

    const float* vbase = v + (size_t)(b * 64) * H_ + h * 64;
    float oacc = 0.f;
    int d = lane;
    #pragma unroll 8
    for (int jj = 0; jj < 64; ++jj)
        oacc += as[ty][jj] * vbase[(size_t)jj * H_ + d];
    o[(size_t)bi * H_ + h * 64 + d] = __float2bfloat16(oacc);
}

// l=1/l=2: w-term combined inline from P-tables
template <int MODE>
__global__ void attn13_kernel(const float* __restrict__ qkv, const int* __restrict__ adj,
        const float* __restrict__ c0a, const float* __restrict__ c1a, const float* __restrict__ c2a,
        const float* __restrict__ c0b, const float* __restrict__ c1b, const float* __restrict__ c2b,
        const float* __restrict__ PX, const float* __restrict__ PY, const float* __restrict__ PE,
        bf16* __restrict__ o) {
    const float* q = qkv;
    const float* k = qkv + (size_t)512 * H_;
    const float* v = qkv + (size_t)1024 * H_;
    int bi = blockIdx.x;
    int b  = bi >> 6, i = bi & 63;
    int ty = threadIdx.y;
    int h  = blockIdx.y * 4 + ty;
    int lane = threadIdx.x;
    __shared__ float qs[4][64], as[4][64];
    qs[ty][lane] = q[(size_t)bi * H_ + h * 64 + lane];
    __syncthreads();

    int j = lane;
    int p = bi * 64 + j;
    int t = adj[p];
    size_t pb = (((size_t)b * 8 + h) * 64 + i) * 64;
    float acc;
    if (MODE == 1) {
        acc = c0a[p] * PE[pb + t] + c1a[p] * PX[pb + i] + c2a[p] * PX[pb + j];
    } else {
        float a0 = c0b[p];
        float AE = a0 * c0a[p], Aa = a0 * c1a[p], Ab = a0 * c2a[p];
        float Ac = c1b[p], Ad = c2b[p];
        acc = AE * PE[pb + t] + Aa * PX[pb + i] + Ab * PX[pb + j]
            + Ac * PY[pb + i] + Ad * PY[pb + j];
    }
    const float4* k4 = (const float4*)(k + (size_t)(b * 64 + j) * H_ + h * 64);
    #pragma unroll
    for (int tt = 0; tt < 8; ++tt) {
        float4 ka = k4[2 * tt], kb = k4[2 * tt + 1];
        const float* qq = &qs[ty][tt * 8];
        acc += qq[0] * ka.x + qq[1] * ka.y + qq[2] * ka.z + qq[3] * ka.w
             + qq[4] * kb.x + qq[5] * kb.y + qq[6] * kb.z + qq[7] * kb.w;
    }
    float logit = acc * INV_SCALE;
    if (t <= 0) logit = -INFINITY;

    float m = logit;
    #pragma unroll
    for (int off = 32; off; off >>= 1) m = fmaxf(m, __shfl_xor(m, off));
    float pe = expf(logit - m);
    float s = pe;
    #pragma unroll
    for (int off = 32; off; off >>= 1) s += __shfl_xor(s, off);
    as[ty][lane] = pe / s;
    __syncthreads();

    const float* vbase = v + (size_t)(b * 64) * H_ + h * 64;
    float oacc = 0.f;
    int d = lane;
    #pragma unroll 8
    for (int jj = 0; jj < 64; ++jj)
        oacc += as[ty][jj] * vbase[(size_t)jj * H_ + d];
    o[(size_t)bi * H_ + h * 64 + d] = __float2bfloat16(oacc);
}

// l=3: w-term computed inline from M-tables + coeffs (s2_assemble fused in)
__global__ void attn3s2_kernel(const float* __restrict__ qkv, const int* __restrict__ adj,
        const float* __restrict__ c0a, const float* __restrict__ c1a, const float* __restrict__ c2a,
        const float* __restrict__ c0b, const float* __restrict__ c1b, const float* __restrict__ c2b,
        const float* __restrict__ v0c, const float* __restrict__ v1c, const float* __restrict__ v2c,
        const float* __restrict__ MX, const float* __restrict__ MY,
        const float* __restrict__ MZ, const float* __restrict__ DE,
        bf16* __restrict__ o) {
    const float* q = qkv;
    const float* k = qkv + (size_t)512 * H_;
    const float* v = qkv + (size_t)1024 * H_;
    int bi = blockIdx.x;
    int b  = bi >> 6, i = bi & 63;
    int ty = threadIdx.y;
    int h  = blockIdx.y * 4 + ty;
    int lane = threadIdx.x;
    __shared__ float qs[4][64], as[4][64];
    qs[ty][lane] = q[(size_t)bi * H_ + h * 64 + lane];
    __syncthreads();

    int j = lane;
    int p = bi * 64 + j;
    int t = adj[p];
    float v0 = v0c[p];
    float q0 = v0 * c0b[p];
    float AE = q0 * c0a[p], Aa = q0 * c1a[p], Ab = q0 * c2a[p];
    float Ac = v0 * c1b[p], Ad = v0 * c2b[p];
    float Ae = v1c[p], Af = v2c[p];
    size_t rb = ((size_t)b * 512 + i * 8 + h) * 64;
    float acc = AE * DE[rb + t]
              + Aa * MX[rb + i] + Ac * MY[rb + i] + Ae * MZ[rb + i]
              + Ab * MX[rb + j] + Ad * MY[rb + j] + Af * MZ[rb + j];

    const float4* k4 = (const float4*)(k + (size_t)(b * 64 + j) * H_ + h * 64);
    #pragma unroll
    for (int tt = 0; tt < 8; ++tt) {
        float4 ka = k4[2 * tt], kb = k4[2 * tt + 1];
        const float* qq = &qs[ty][tt * 8];
        acc += qq[0] * ka.x + qq[1] * ka.y + qq[2] * ka.z + qq[3] * ka.w
             + qq[4] * kb.x + qq[5] * kb.y + qq[6] * kb.z + qq[7] * kb.w;
    }
    float logit = acc * INV_SCALE;
    if (t <= 0) logit = -INFINITY;

    float m = logit;
    #pragma unroll
    for (int off = 32; off; off >>= 1) m = fmaxf(m, __shfl_xor(m, off));
    float pe = expf(logit - m);
    float s = pe;
    #pragma unroll
    for (int off = 32; off; off >>= 1) s += __shfl_xor(s, off);
    as[ty][lane] = pe / s;
    __syncthreads();

    const float* vbase = v + (size_t)(b * 64) * H_ + h * 64;
    float oacc = 0.f;
    int d = lane;
    #pragma unroll 8
    for (int jj = 0; jj < 64; ++jj)
        oacc += as[ty][jj] * vbase[(size_t)jj * H_ + d];
    o[(size_t)bi * H_ + h * 64 + d] = __float2bfloat16(oacc);
}

// ---------------------------------------------------------------- head
__global__ void cls_part_kernel(const float* __restrict__ x, const float* __restrict__ Wout,
                                float* __restrict__ clspart) {
    int b  = blockIdx.x;
    int cb = blockIdx.y;
    int ks = blockIdx.z;
    int tid = threadIdx.x;
    int c  = cb * 64 + (tid & 63);
    int kk = tid >> 6;
    const float* xr = x + (size_t)(b * 64) * H_;
    int h0 = ks * 128 + kk * 32;
    float acc = 0.f;
    #pragma unroll
    for (int h = 0; h < 32; ++h)
        acc += xr[h0 + h] * Wout[(size_t)(h0 + h) * H_ + c];
    __shared__ float red[4][64];
    red[kk][tid & 63] = acc;
    __syncthreads();
    if (tid < 64) {
        float v = red[0][tid] + red[1][tid] + red[2][tid] + red[3][tid];
        clspart[((size_t)ks * 8 + b) * H_ + cb * 64 + tid] = v;
    }
}

__global__ void cls_pred2_kernel(const float* __restrict__ clspart,
                                 const float* __restrict__ Wpred,
                                 const float* __restrict__ bpred,
                                 float* __restrict__ out) {
    int b = blockIdx.x;
    int tid = threadIdx.x;
    __shared__ float red0[4], red1[4];
    float a0 = 0.f, a1 = 0.f;
    #pragma unroll
    for (int t = 0; t < 2; ++t) {
        int c = tid + t * 256;
        float v = clspart[((size_t)0 * 8 + b) * H_ + c]
                + clspart[((size_t)1 * 8 + b) * H_ + c]
                + clspart[((size_t)2 * 8 + b) * H_ + c]
                + clspart[((size_t)3 * 8 + b) * H_ + c];
        float tv = tanhf(v);
        a0 += tv * Wpred[c * 2 + 0];
        a1 += tv * Wpred[c * 2 + 1];
    }
    #pragma unroll
    for (int off = 32; off; off >>= 1) {
        a0 += __shfl_xor(a0, off);
        a1 += __shfl_xor(a1, off);
    }
    int w = tid >> 6;
    if ((tid & 63) == 0) { red0[w] = a0; red1[w] = a1; }
    __syncthreads();
    if (tid == 0) {
        float s0 = red0[0] + red0[1] + red0[2] + red0[3] + bpred[0];
        float s1 = red1[0] + red1[1] + red1[2] + red1[3] + bpred[1];
        float m = fmaxf(s0, s1);
        float e0 = expf(s0 - m), e1 = expf(s1 - m);
        float inv = 1.0f / (e0 + e1);
        out[b * 2 + 0] = e0 * inv;
        out[b * 2 + 1] = e1 * inv;
    }
}

// ---------------------------------------------------------------- launch
extern "C" void kernel_launch(void* const* d_in, const int* in_sizes, int n_in,
                              void* d_out, int out_size, void* d_ws, size_t ws_size,
                              hipStream_t stream) {
    const int*   ids      = (const int*)d_in[0];
    const int*   adj      = (const int*)d_in[1];
    const float* atom_emb = (const float*)d_in[2];
    const float* bond_emb = (const float*)d_in[3];
    const float* Wq     = (const float*)d_in[4];
    const float* Wk     = (const float*)d_in[5];
    const float* Wv     = (const float*)d_in[6];
    const float* Wew    = (const float*)d_in[7];
    const float* Wstack = (const float*)d_in[8];
    const float* Wf1    = (const float*)d_in[9];
    const float* Wf2    = (const float*)d_in[10];
    const float* Wout   = (const float*)d_in[11];
    const float* Wpred  = (const float*)d_in[12];
    const float* bpred  = (const float*)d_in[13];

    char* ws = (char*)d_ws;
    size_t off = 0;
    auto alloc = [&](size_t bytes) {
        size_t o = off;
        off += (bytes + 255) & ~(size_t)255;
        return o;
    };
    const size_t ROWS  = (size_t)B_ * N_;
    const size_t PAIRS = (size_t)B_ * N_ * N_;
    const size_t KN    = (size_t)H_ * H_;

    float* x       = (float*)(ws + alloc(ROWS * H_ * 4));
    float* xn      = (float*)(ws + alloc(ROWS * H_ * 4));
    bf16*  xn_bf   = (bf16*) (ws + alloc(ROWS * H_ * 2));
    bf16*  x_bf    = (bf16*) (ws + alloc(ROWS * H_ * 2));
    float* qkv     = (float*)(ws + alloc(3 * ROWS * H_ * 4));
    bf16*  o_bf    = (bf16*) (ws + alloc(ROWS * H_ * 2));
    float* resid   = (float*)(ws + alloc(ROWS * H_ * 4));
    bf16*  ffin_bf = (bf16*) (ws + alloc(ROWS * H_ * 2));
    bf16*  ffh_bf  = (bf16*) (ws + alloc(ROWS * 4 * H_ * 2));
    float* part    = (float*)(ws + alloc(4 * ROWS * H_ * 4));
    float* clspart = (float*)(ws + alloc(4 * 8 * H_ * 4));
    bf16*  ubf     = (bf16*) (ws + alloc(ROWS * 8 * 512 * 2));           // 4 MB
    float* MX      = (float*)(ws + alloc((size_t)4096 * 64 * 4));        // 1 MB each
    float* MY      = (float*)(ws + alloc((size_t)4096 * 64 * 4));
    float* MZ      = (float*)(ws + alloc((size_t)4096 * 64 * 4));
    float* DE      = (float*)(ws + alloc((size_t)4096 * 64 * 4));
    float* PT0     = (float*)(ws + alloc((size_t)4096 * 64 * 4));        // P-tables
    float* PT1     = (float*)(ws + alloc((size_t)4096 * 64 * 4));
    float* PT2     = (float*)(ws + alloc((size_t)4096 * 64 * 4));
    float* gbuf    = (float*)(ws + alloc((size_t)9 * 8 * 4096 * 4));     // Gram tables
    bf16*  wc3     = (bf16*) (ws + alloc(KN * 2));
    bf16*  E0      = (bf16*) (ws + alloc(64 * H_ * 2));      // padded to 64 rows
    bf16*  e0w1    = (bf16*) (ws + alloc(64 * H_ * 2));
    bf16*  e0w12   = (bf16*) (ws + alloc(64 * H_ * 2));
    bf16*  xw1     = (bf16*) (ws + alloc(KN * 2));
    bf16*  xw12    = (bf16*) (ws + alloc(KN * 2));
    bf16*  x2w2    = (bf16*) (ws + alloc(KN * 2));
    float* cw      = (float*)(ws + alloc(9 * PAIRS * 4));    // edge softmax coeffs
    bf16*  qkvt    = (bf16*) (ws + alloc((size_t)L_ * 3 * KN * 2));
    bf16*  ewt     = (bf16*) (ws + alloc((size_t)L_ * KN * 2));
    bf16*  stackt  = (bf16*) (ws + alloc((size_t)L_ * KN * 2));
    bf16*  f1t     = (bf16*) (ws + alloc((size_t)L_ * 4 * KN * 2));
    bf16*  f2t     = (bf16*) (ws + alloc((size_t)L_ * 4 * KN * 2));
    (void)ws_size;

    float* cw0a = cw;
    float* cw1a = cw + PAIRS;
    float* cw2a = cw + 2 * PAIRS;
    float* cw0b = cw + 3 * PAIRS;
    float* cw1b = cw + 4 * PAIRS;
    float* cw2b = cw + 5 * PAIRS;
    float* cw0c = cw + 6 * PAIRS;
    float* cw1c = cw + 7 * PAIRS;
    float* cw2c = cw + 8 * PAIRS;

    // one-shot setup: embed+LN, all weight transposes, E0, Wew3 cast
    setup_kernel<<<14080, 256, 0, stream>>>(ids, atom_emb, bond_emb,
                                            Wq, Wk, Wv, Wew, Wstack, Wf1, Wf2,
                                            xn, xn_bf, qkvt, ewt, stackt, f1t, f2t,
                                            E0, wc3);

    for (int l = 0; l < L_; ++l) {
        if (l == 0) {
            mfma_gemm_s<0, false><<<dim3(8, 8, 3), 256, 0, stream>>>(
                xn_bf, qkvt, qkv, nullptr, 512, 512, 512);
            attn_kernel<true><<<dim3(512, 2), dim3(64, 4), 0, stream>>>(qkv, E0, adj, o_bf);
        } else if (l == 1) {
            // basis1 + qkv + edge_coeff(l=0)
            basis1_qkv_ec<<<2312, 256, 0, stream>>>(
                x_bf, E0, ewt + KN, xw1, e0w1, xn_bf, qkvt + (size_t)3 * KN, qkv,
                adj, x, cw0a, cw1a, cw2a);
            ptable_kernel<<<dim3(8, 8, 2), 256, 0, stream>>>(qkv, xw1, e0w1, PT0, PT1);
            attn13_kernel<1><<<dim3(512, 2), dim3(64, 4), 0, stream>>>(
                qkv, adj, cw0a, cw1a, cw2a, nullptr, nullptr, nullptr,
                PT0, nullptr, PT1, o_bf);
        } else if (l == 2) {
            // basis2 + qkv + gram1
            basis2_qkv_g1<<<368, 256, 0, stream>>>(
                xw1, x_bf, e0w1, ewt + 2 * KN, xw12, x2w2, e0w12,
                xn_bf, qkvt + (size_t)6 * KN, qkv, gbuf);
            // ptables + coeff1
            ptable2c<<<256, 256, 0, stream>>>(
                qkv, xw12, x2w2, e0w12, PT0, PT1, PT2,
                adj, cw0a, cw1a, cw2a, gbuf, cw0b, cw1b, cw2b);
            attn13_kernel<2><<<dim3(512, 2), dim3(64, 4), 0, stream>>>(
                qkv, adj, cw0a, cw1a, cw2a, cw0b, cw1b, cw2b,
                PT0, PT1, PT2, o_bf);
        } else {
            // qkv + gram2
            l3qkv_g2<<<264, 256, 0, stream>>>(
                xn_bf, qkvt + (size_t)9 * KN, qkv, xw12, x2w2, e0w12, x_bf, gbuf);
            // u + coeff2
            u_c2<<<576, 256, 0, stream>>>(
                qkv, wc3, ubf, adj, cw0a, cw1a, cw2a, cw0b, cw1b, cw2b,
                gbuf, cw0c, cw1c, cw2c);
            mbuf_gemm<<<dim3(8, 8, 4), 256, 0, stream>>>(ubf, xw12, x2w2, x_bf, e0w12,
                                                         MX, MY, MZ, DE);
            attn3s2_kernel<<<dim3(512, 2), dim3(64, 4), 0, stream>>>(
                qkv, adj, cw0a, cw1a, cw2a, cw0b, cw1b, cw2b, cw0c, cw1c, cw2c,
                MX, MY, MZ, DE, o_bf);
        }

        mfma_gemm_s<0, true><<<dim3(8, 8, 4), 256, 0, stream>>>(
            o_bf, stackt + (size_t)l * KN, part, nullptr, 512, 512, 512);
        reduce_stack_ln<<<512, 256, 0, stream>>>(part, xn, resid, ffin_bf);
        mfma_gemm_s<2, false><<<dim3(8, 32), 256, 0, stream>>>(
            ffin_bf, f1t + (size_t)l * 4 * KN, ffh_bf, nullptr, 512, 2048, 512);
        mfma_gemm_s<0, true><<<dim3(8, 8, 4), 256, 0, stream>>>(
            ffh_bf, f2t + (size_t)l * 4 * KN, part, nullptr, 512, 512, 2048);
        if (l < L_ - 1)
            reduce_ln_kernel<true><<<512, 256, 0, stream>>>(part, resid, x, x_bf, xn, xn_bf);
        else
            reduce_ln_kernel<false><<<512, 256, 0, stream>>>(part, resid, x, x_bf, xn, xn_bf);
    }

    cls_part_kernel<<<dim3(8, 8, 4), 256, 0, stream>>>(x, Wout, clspart);
    cls_pred2_kernel<<<8, 256, 0, stream>>>(clspart, Wpred, bpred, (float*)d_out);
}

// Round 6
// 364.004 us; speedup vs baseline: 1.3661x; 1.0506x over previous
//
#include <hip/hip_runtime.h>
#include <hip/hip_bf16.h>

typedef __hip_bfloat16 bf16;

#define B_     8
#define N_     64
#define H_     512
#define HEADS_ 8
#define SP_    64
#define L_     4
static constexpr float INV_SCALE = 0.044194173824159216f; // 1/sqrt(512)

typedef __attribute__((ext_vector_type(8))) short short8;
typedef __attribute__((ext_vector_type(4))) float f32x4;

__device__ __forceinline__ void unpack8(uint4 u, float* f) {
    f[0] = __uint_as_float(u.x << 16); f[1] = __uint_as_float(u.x & 0xffff0000u);
    f[2] = __uint_as_float(u.y << 16); f[3] = __uint_as_float(u.y & 0xffff0000u);
    f[4] = __uint_as_float(u.z << 16); f[5] = __uint_as_float(u.z & 0xffff0000u);
    f[6] = __uint_as_float(u.w << 16); f[7] = __uint_as_float(u.w & 0xffff0000u);
}

__device__ __forceinline__ bf16 f2bf(float v) { return __float2bfloat16(v); }

__device__ __forceinline__ uint4 pack8bf(float4 a, float4 b) {
    __align__(16) bf16 t[8];
    t[0] = f2bf(a.x); t[1] = f2bf(a.y); t[2] = f2bf(a.z); t[3] = f2bf(a.w);
    t[4] = f2bf(b.x); t[5] = f2bf(b.y); t[6] = f2bf(b.z); t[7] = f2bf(b.w);
    return *(const uint4*)t;
}

#define RSTR 80

// ------------------------------------------------------------ GEMM body (64-tile)
// EPI: 0 = fp32 out, 1 = fp32 + residual, 2 = relu->bf16, 3 = bf16
template <int EPI>
__device__ __forceinline__ void gemm64_body(char* lds,
        const bf16* __restrict__ A, const bf16* __restrict__ Bt,
        void* __restrict__ Cv, const float* __restrict__ R,
        int M, int N, int K, int bx, int by, int kbeg, int kend) {
    char* As = lds;
    char* Bs = lds + 2 * 64 * RSTR;
    const int tid = threadIdx.x;
    const int bm = bx * 64, bn = by * 64;
    const int w = tid >> 6, lane = tid & 63;
    const int wr = (w >> 1) * 32, wc = (w & 1) * 32;
    const int m0 = lane & 15, q4 = lane >> 4;

    f32x4 acc[2][2] = {};

    const int rA = tid >> 3;
    const int cA = tid & 7;
    const int ksP = cA >> 2;
    const int cB = (cA & 3) * 16;
    const int cE = cA * 8;

    for (int k0 = kbeg; k0 < kend; k0 += 64) {
        uint4 a0 = *(const uint4*)(A  + (size_t)(bm + rA) * K + k0 + cE);
        uint4 a1 = *(const uint4*)(A  + (size_t)(bm + rA + 32) * K + k0 + cE);
        uint4 b0 = *(const uint4*)(Bt + (size_t)(bn + rA) * K + k0 + cE);
        uint4 b1 = *(const uint4*)(Bt + (size_t)(bn + rA + 32) * K + k0 + cE);
        __syncthreads();
        *(uint4*)(As + ksP * (64 * RSTR) + rA * RSTR + cB) = a0;
        *(uint4*)(As + ksP * (64 * RSTR) + (rA + 32) * RSTR + cB) = a1;
        *(uint4*)(Bs + ksP * (64 * RSTR) + rA * RSTR + cB) = b0;
        *(uint4*)(Bs + ksP * (64 * RSTR) + (rA + 32) * RSTR + cB) = b1;
        __syncthreads();
        short8 af[2][2], bfr[2][2];
        #pragma unroll
        for (int ks = 0; ks < 2; ++ks)
            #pragma unroll
            for (int t = 0; t < 2; ++t) {
                af[ks][t]  = *(const short8*)(As + ks * (64 * RSTR) + (wr + t * 16 + m0) * RSTR + q4 * 16);
                bfr[ks][t] = *(const short8*)(Bs + ks * (64 * RSTR) + (wc + t * 16 + m0) * RSTR + q4 * 16);
            }
        #pragma unroll
        for (int ks = 0; ks < 2; ++ks)
            #pragma unroll
            for (int mt = 0; mt < 2; ++mt)
                #pragma unroll
                for (int nt = 0; nt < 2; ++nt)
                    acc[mt][nt] = __builtin_amdgcn_mfma_f32_16x16x32_bf16(
                        af[ks][mt], bfr[ks][nt], acc[mt][nt], 0, 0, 0);
    }

    if (EPI <= 1) {
        float* C = (float*)Cv;
        #pragma unroll
        for (int mt = 0; mt < 2; ++mt)
            #pragma unroll
            for (int i = 0; i < 4; ++i) {
                int row = bm + wr + mt * 16 + q4 * 4 + i;
                #pragma unroll
                for (int nt = 0; nt < 2; ++nt) {
                    int col = bn + wc + nt * 16 + m0;
                    float v = acc[mt][nt][i];
                    if (EPI == 1) v += R[(size_t)row * N + col];
                    C[(size_t)row * N + col] = v;
                }
            }
    } else {
        bf16* C = (bf16*)Cv;
        #pragma unroll
        for (int mt = 0; mt < 2; ++mt)
            #pragma unroll
            for (int i = 0; i < 4; ++i) {
                int row = bm + wr + mt * 16 + q4 * 4 + i;
                #pragma unroll
                for (int nt = 0; nt < 2; ++nt) {
                    int col = bn + wc + nt * 16 + m0;
                    float v = acc[mt][nt][i];
                    if (EPI == 2) v = fmaxf(v, 0.0f);
                    C[(size_t)row * N + col] = __float2bfloat16(v);
                }
            }
    }
}

template <int EPI, bool SPLIT>
__launch_bounds__(256)
__global__ void mfma_gemm_s(const bf16* __restrict__ A, const bf16* __restrict__ Bt,
                            void* __restrict__ Cv, const float* __restrict__ R,
                            int M, int N, int K) {
    __shared__ __align__(16) char lds[4 * 64 * RSTR];
    int kbeg = 0, kend = K;
    const bf16* B2 = Bt;
    void* C2 = Cv;
    if (SPLIT) {
        int ks = K / gridDim.z;
        kbeg = blockIdx.z * ks;
        kend = kbeg + ks;
        C2 = (void*)((float*)Cv + (size_t)blockIdx.z * M * N);
        gemm64_body<0>(lds, A, B2, C2, nullptr, M, N, K, blockIdx.x, blockIdx.y, kbeg, kend);
    } else {
        B2 = Bt + (size_t)blockIdx.z * N * K;
        if (EPI <= 1) C2 = (void*)((float*)Cv + (size_t)blockIdx.z * M * N);
        gemm64_body<EPI>(lds, A, B2, C2, R, M, N, K, blockIdx.x, blockIdx.y, kbeg, kend);
    }
}

// ------------------------------------------------ device bodies (shared pieces)

// per-(b,h) q . basis^T : P[(b,h,i,r)] = sum_{d<64} q[b,i,h*64+d] * Bz[r,h*64+d]
__device__ __forceinline__ void ptable_body(char* lds, const float* __restrict__ q,
        const bf16* __restrict__ Bt, float* __restrict__ P, int b, int h, bool shr) {
    char* As = lds;
    char* Bs = lds + 2 * 64 * RSTR;
    const int tid = threadIdx.x;
    const int w = tid >> 6, lane = tid & 63;
    const int wr = (w >> 1) * 32, wc = (w & 1) * 32;
    const int m0 = lane & 15, q4 = lane >> 4;
    const int rA = tid >> 3;
    const int cA = tid & 7;
    const int ksP = cA >> 2;
    const int cB = (cA & 3) * 16;
    const int cE = cA * 8;

    const float* Aq = q + (size_t)(b * 64) * 512 + h * 64;
    const bf16*  Bb = Bt + (shr ? (size_t)0 : (size_t)b * 64 * 512) + h * 64;

    float4 fa0 = *(const float4*)(Aq + (size_t)rA * 512 + cE);
    float4 fa1 = *(const float4*)(Aq + (size_t)rA * 512 + cE + 4);
    float4 fb0 = *(const float4*)(Aq + (size_t)(rA + 32) * 512 + cE);
    float4 fb1 = *(const float4*)(Aq + (size_t)(rA + 32) * 512 + cE + 4);
    uint4 bv0 = *(const uint4*)(Bb + (size_t)rA * 512 + cE);
    uint4 bv1 = *(const uint4*)(Bb + (size_t)(rA + 32) * 512 + cE);
    uint4 av0 = pack8bf(fa0, fa1);
    uint4 av1 = pack8bf(fb0, fb1);
    *(uint4*)(As + ksP * (64 * RSTR) + rA * RSTR + cB) = av0;
    *(uint4*)(As + ksP * (64 * RSTR) + (rA + 32) * RSTR + cB) = av1;
    *(uint4*)(Bs + ksP * (64 * RSTR) + rA * RSTR + cB) = bv0;
    *(uint4*)(Bs + ksP * (64 * RSTR) + (rA + 32) * RSTR + cB) = bv1;
    __syncthreads();

    f32x4 acc[2][2] = {};
    short8 af[2][2], bfr[2][2];
    #pragma unroll
    for (int ks = 0; ks < 2; ++ks)
        #pragma unroll
        for (int t = 0; t < 2; ++t) {
            af[ks][t]  = *(const short8*)(As + ks * (64 * RSTR) + (wr + t * 16 + m0) * RSTR + q4 * 16);
            bfr[ks][t] = *(const short8*)(Bs + ks * (64 * RSTR) + (wc + t * 16 + m0) * RSTR + q4 * 16);
        }
    #pragma unroll
    for (int ks = 0; ks < 2; ++ks)
        #pragma unroll
        for (int mt = 0; mt < 2; ++mt)
            #pragma unroll
            for (int nt = 0; nt < 2; ++nt)
                acc[mt][nt] = __builtin_amdgcn_mfma_f32_16x16x32_bf16(
                    af[ks][mt], bfr[ks][nt], acc[mt][nt], 0, 0, 0);

    #pragma unroll
    for (int mt = 0; mt < 2; ++mt)
        #pragma unroll
        for (int i = 0; i < 4; ++i) {
            int row = wr + mt * 16 + q4 * 4 + i;
            #pragma unroll
            for (int nt = 0; nt < 2; ++nt) {
                int col = wc + nt * 16 + m0;
                P[(((size_t)b * 8 + h) * 64 + row) * 64 + col] = acc[mt][nt][i];
            }
        }
}

// u_bf[b,i,h,k] = sum_d q[b,i,h*64+d] * Wew3[k,h*64+d]
__device__ __forceinline__ void ugemm_body(char* lds, const float* __restrict__ q,
        const bf16* __restrict__ wc3, bf16* __restrict__ ubf, int h, int mb, int nb) {
    char* As = lds;
    char* Bs = lds + 2 * 64 * RSTR;
    const int tid = threadIdx.x;
    const int w = tid >> 6, lane = tid & 63;
    const int wr = (w >> 1) * 32, wc = (w & 1) * 32;
    const int m0 = lane & 15, q4 = lane >> 4;
    const int rA = tid >> 3;
    const int cA = tid & 7;
    const int ksP = cA >> 2;
    const int cB = (cA & 3) * 16;
    const int cE = cA * 8;

    const float* Aq = q + (size_t)(mb * 64) * 512 + h * 64;
    const bf16*  Bt = wc3 + (size_t)(nb * 64) * 512 + h * 64;

    float4 fa0 = *(const float4*)(Aq + (size_t)rA * 512 + cE);
    float4 fa1 = *(const float4*)(Aq + (size_t)rA * 512 + cE + 4);
    float4 fb0 = *(const float4*)(Aq + (size_t)(rA + 32) * 512 + cE);
    float4 fb1 = *(const float4*)(Aq + (size_t)(rA + 32) * 512 + cE + 4);
    uint4 b0 = *(const uint4*)(Bt + (size_t)rA * 512 + cE);
    uint4 b1 = *(const uint4*)(Bt + (size_t)(rA + 32) * 512 + cE);
    uint4 a0 = pack8bf(fa0, fa1);
    uint4 a1 = pack8bf(fb0, fb1);
    *(uint4*)(As + ksP * (64 * RSTR) + rA * RSTR + cB) = a0;
    *(uint4*)(As + ksP * (64 * RSTR) + (rA + 32) * RSTR + cB) = a1;
    *(uint4*)(Bs + ksP * (64 * RSTR) + rA * RSTR + cB) = b0;
    *(uint4*)(Bs + ksP * (64 * RSTR) + (rA + 32) * RSTR + cB) = b1;
    __syncthreads();

    f32x4 acc[2][2] = {};
    short8 af[2][2], bfr[2][2];
    #pragma unroll
    for (int ks = 0; ks < 2; ++ks)
        #pragma unroll
        for (int t = 0; t < 2; ++t) {
            af[ks][t]  = *(const short8*)(As + ks * (64 * RSTR) + (wr + t * 16 + m0) * RSTR + q4 * 16);
            bfr[ks][t] = *(const short8*)(Bs + ks * (64 * RSTR) + (wc + t * 16 + m0) * RSTR + q4 * 16);
        }
    #pragma unroll
    for (int ks = 0; ks < 2; ++ks)
        #pragma unroll
        for (int mt = 0; mt < 2; ++mt)
            #pragma unroll
            for (int nt = 0; nt < 2; ++nt)
                acc[mt][nt] = __builtin_amdgcn_mfma_f32_16x16x32_bf16(
                    af[ks][mt], bfr[ks][nt], acc[mt][nt], 0, 0, 0);

    #pragma unroll
    for (int mt = 0; mt < 2; ++mt)
        #pragma unroll
        for (int i = 0; i < 4; ++i) {
            int row = mb * 64 + wr + mt * 16 + q4 * 4 + i;
            #pragma unroll
            for (int nt = 0; nt < 2; ++nt) {
                int col = nb * 64 + wc + nt * 16 + m0;
                ubf[(size_t)row * 4096 + h * 512 + col] = f2bf(acc[mt][nt][i]);
            }
        }
}

// edge softmax coeffs from l=1 Gram tables (per-thread; row=(b,i), j)
__device__ __forceinline__ void coeff1_body(const int* __restrict__ adj,
        const float* __restrict__ c0a, const float* __restrict__ c1a, const float* __restrict__ c2a,
        const float* __restrict__ gbuf, int row, int j,
        float* __restrict__ w0o, float* __restrict__ w1o, float* __restrict__ w2o) {
    int b = row >> 6, i = row & 63;
    int p = row * 64 + j;
    int t = adj[p];
    const float* TXX = gbuf + 0 * 32768 + (size_t)b * 4096;
    const float* TEX = gbuf + 1 * 32768 + (size_t)b * 4096;
    const float* TXx = gbuf + 2 * 32768 + (size_t)b * 4096;
    const float* TEx = gbuf + 3 * 32768 + (size_t)b * 4096;
    const float* TEE = gbuf + 4 * 32768 + (size_t)b * 4096;
    float c0 = c0a[p], c1 = c1a[p], c2 = c2a[p];
    float s1 = c0 * TEx[t * 64 + i] + c1 * TXx[i * 64 + i] + c2 * TXx[j * 64 + i];
    float s2 = c0 * TEx[t * 64 + j] + c1 * TXx[i * 64 + j] + c2 * TXx[j * 64 + j];
    float s0 = c0 * c0 * TEE[t * 64 + t] + c1 * c1 * TXX[i * 64 + i] + c2 * c2 * TXX[j * 64 + j]
             + 2.f * c0 * c1 * TEX[t * 64 + i] + 2.f * c0 * c2 * TEX[t * 64 + j]
             + 2.f * c1 * c2 * TXX[i * 64 + j];
    float t0 = s0 * INV_SCALE, t1 = s1 * INV_SCALE, t2 = s2 * INV_SCALE;
    float m = fmaxf(t0, fmaxf(t1, t2));
    float e0 = expf(t0 - m), e1 = expf(t1 - m), e2 = expf(t2 - m);
    float inv = 1.0f / (e0 + e1 + e2);
    w0o[p] = e0 * inv;
    w1o[p] = e1 * inv;
    w2o[p] = e2 * inv;
}

// edge softmax coeffs from l=2 Gram tables
__device__ __forceinline__ void coeff2_body(const int* __restrict__ adj,
        const float* __restrict__ c0a, const float* __restrict__ c1a, const float* __restrict__ c2a,
        const float* __restrict__ c0b, const float* __restrict__ c1b, const float* __restrict__ c2b,
        const float* __restrict__ gbuf, int row, int j,
        float* __restrict__ w0o, float* __restrict__ w1o, float* __restrict__ w2o) {
    int b = row >> 6, i = row & 63;
    int p = row * 64 + j;
    int t = adj[p];
    const float* TXX = gbuf + 0 * 32768 + (size_t)b * 4096;
    const float* TXY = gbuf + 1 * 32768 + (size_t)b * 4096;
    const float* TYY = gbuf + 2 * 32768 + (size_t)b * 4096;
    const float* TEX = gbuf + 3 * 32768 + (size_t)b * 4096;
    const float* TEY = gbuf + 4 * 32768 + (size_t)b * 4096;
    const float* TEE = gbuf + 5 * 32768 + (size_t)b * 4096;
    const float* TXx = gbuf + 6 * 32768 + (size_t)b * 4096;
    const float* TYx = gbuf + 7 * 32768 + (size_t)b * 4096;
    const float* TEx = gbuf + 8 * 32768 + (size_t)b * 4096;
    float a0 = c0b[p];
    float AE = a0 * c0a[p], Aa = a0 * c1a[p], Ab = a0 * c2a[p];
    float Ac = c1b[p], Ad = c2b[p];
    float s1 = AE * TEx[t * 64 + i] + Aa * TXx[i * 64 + i] + Ab * TXx[j * 64 + i]
             + Ac * TYx[i * 64 + i] + Ad * TYx[j * 64 + i];
    float s2 = AE * TEx[t * 64 + j] + Aa * TXx[i * 64 + j] + Ab * TXx[j * 64 + j]
             + Ac * TYx[i * 64 + j] + Ad * TYx[j * 64 + j];
    float s0 = AE * AE * TEE[t * 64 + t] + Aa * Aa * TXX[i * 64 + i] + Ab * Ab * TXX[j * 64 + j]
             + Ac * Ac * TYY[i * 64 + i] + Ad * Ad * TYY[j * 64 + j]
             + 2.f * AE * Aa * TEX[t * 64 + i] + 2.f * AE * Ab * TEX[t * 64 + j]
             + 2.f * AE * Ac * TEY[t * 64 + i] + 2.f * AE * Ad * TEY[t * 64 + j]
             + 2.f * Aa * Ab * TXX[i * 64 + j]
             + 2.f * Aa * Ac * TXY[i * 64 + i] + 2.f * Aa * Ad * TXY[i * 64 + j]
             + 2.f * Ab * Ac * TXY[j * 64 + i] + 2.f * Ab * Ad * TXY[j * 64 + j]
             + 2.f * Ac * Ad * TYY[i * 64 + j];
    float t0 = s0 * INV_SCALE, t1 = s1 * INV_SCALE, t2 = s2 * INV_SCALE;
    float m = fmaxf(t0, fmaxf(t1, t2));
    float e0 = expf(t0 - m), e1 = expf(t1 - m), e2 = expf(t2 - m);
    float inv = 1.0f / (e0 + e1 + e2);
    w0o[p] = e0 * inv;
    w1o[p] = e1 * inv;
    w2o[p] = e2 * inv;
}

// ------------------------------------------------ merged one-shot setup kernel
// grid: [0,512) embed | [512,1792) sq transpose 64x64 | [1792,3840) rect transpose 64x64
//       [3840,3968) E0-direct | [3968,4096) cast_w3
__launch_bounds__(256)
__global__ void setup_kernel(const int* __restrict__ ids, const float* __restrict__ atom_emb,
                             const float* __restrict__ bond_emb,
                             const float* __restrict__ Wq, const float* __restrict__ Wk,
                             const float* __restrict__ Wv, const float* __restrict__ Wew,
                             const float* __restrict__ Wst,
                             const float* __restrict__ Wf1, const float* __restrict__ Wf2,
                             float* __restrict__ xn, bf16* __restrict__ xn_bf,
                             bf16* __restrict__ qkvt, bf16* __restrict__ ewt,
                             bf16* __restrict__ stackt,
                             bf16* __restrict__ f1t, bf16* __restrict__ f2t,
                             bf16* __restrict__ E0, bf16* __restrict__ wc3) {
    __shared__ __align__(16) float smem[64 * 65];   // 16.6 KB; reused by all sections
    const size_t KN = (size_t)H_ * H_;
    int bid = blockIdx.x;
    int tid = threadIdx.x;

    if (bid < 512) {
        // ---- embed + LN
        int row = bid;
        const float* r = atom_emb + (size_t)ids[row] * H_;
        float x0 = r[tid], x1 = r[tid + 256];
        float s = x0 + x1, sq = x0 * x0 + x1 * x1;
        #pragma unroll
        for (int off = 32; off; off >>= 1) {
            s  += __shfl_xor(s,  off);
            sq += __shfl_xor(sq, off);
        }
        int w = tid >> 6;
        if ((tid & 63) == 0) { smem[w] = s; smem[4 + w] = sq; }
        __syncthreads();
        float S = smem[0] + smem[1] + smem[2] + smem[3];
        float Q = smem[4] + smem[5] + smem[6] + smem[7];
        float mean = S * (1.0f / H_);
        float var  = Q * (1.0f / H_) - mean * mean;
        float inv  = rsqrtf(var + 1e-5f);
        float y0 = (x0 - mean) * inv, y1 = (x1 - mean) * inv;
        xn[(size_t)row * H_ + tid]       = y0;
        xn[(size_t)row * H_ + tid + 256] = y1;
        xn_bf[(size_t)row * H_ + tid]       = f2bf(y0);
        xn_bf[(size_t)row * H_ + tid + 256] = f2bf(y1);
    } else if (bid < 3840) {
        // ---- 64x64 fp32 -> bf16 transpose tiles (vectorized)
        const float* W; bf16* Wt; int K, N, kb, nb;
        if (bid < 1792) {
            int idx = bid - 512;
            int z = idx >> 6, rem = idx & 63;
            kb = rem & 7; nb = rem >> 3;
            K = 512; N = 512;
            if (z < 12) {
                int sss = z >> 2, l = z & 3;
                W  = (sss == 0 ? Wq : sss == 1 ? Wk : Wv) + (size_t)l * KN;
                Wt = qkvt + (size_t)l * 3 * KN + (size_t)sss * KN;
            } else if (z < 16) {
                int l = z - 12;
                W = Wew + (size_t)l * KN; Wt = ewt + (size_t)l * KN;
            } else {
                int l = z - 16;
                W = Wst + (size_t)l * KN; Wt = stackt + (size_t)l * KN;
            }
        } else {
            int idx = bid - 1792;
            int z = idx >> 8;       // 0..7
            int idx2 = idx & 255;
            const size_t KN4 = (size_t)4 * H_ * H_;
            if (z < 4) {
                W = Wf1 + (size_t)z * KN4; Wt = f1t + (size_t)z * KN4; K = 512; N = 2048;
                kb = idx2 & 7; nb = idx2 >> 3;
            } else {
                W = Wf2 + (size_t)(z - 4) * KN4; Wt = f2t + (size_t)(z - 4) * KN4; K = 2048; N = 512;
                kb = idx2 >> 3; nb = idx2 & 7;
            }
        }
        int k0 = kb * 64, n0 = nb * 64;
        float (*tt)[65] = (float(*)[65])smem;
        int rr = tid >> 4, c4 = (tid & 15) * 4;
        #pragma unroll
        for (int it = 0; it < 4; ++it) {
            float4 v = *(const float4*)(W + (size_t)(k0 + rr + it * 16) * N + n0 + c4);
            tt[rr + it * 16][c4 + 0] = v.x;
            tt[rr + it * 16][c4 + 1] = v.y;
            tt[rr + it * 16][c4 + 2] = v.z;
            tt[rr + it * 16][c4 + 3] = v.w;
        }
        __syncthreads();
        int nr = tid >> 3, k8 = (tid & 7) * 8;
        #pragma unroll
        for (int it = 0; it < 2; ++it) {
            int nn = nr + it * 32;
            __align__(16) bf16 ob[8];
            #pragma unroll
            for (int e = 0; e < 8; ++e)
                ob[e] = f2bf(tt[k8 + e][nn]);
            *(uint4*)(Wt + (size_t)(n0 + nn) * K + k0 + k8) = *(const uint4*)ob;
        }
    } else if (bid < 3968) {
        // ---- E0 = bond_emb @ Wew0 directly; rows 8..63 zero
        int idx = bid - 3840;
        int t = idx >> 1;
        int c = (idx & 1) * 256 + tid;
        if (t >= 8) { E0[t * 512 + c] = f2bf(0.0f); return; }
        float* be = smem;
        be[tid]       = bond_emb[t * 512 + tid];
        be[tid + 256] = bond_emb[t * 512 + tid + 256];
        __syncthreads();
        float acc = 0.f;
        #pragma unroll 8
        for (int h = 0; h < 512; ++h)
            acc += be[h] * Wew[(size_t)h * 512 + c];
        E0[t * 512 + c] = f2bf(acc);
    } else {
        // ---- cast Wew3 -> bf16
        int idx = bid - 3968;
        int gid = idx * 256 + tid;
        const float4* p = (const float4*)(Wew + 3 * KN + (size_t)gid * 8);
        float4 a = p[0], b = p[1];
        *(uint4*)(wc3 + (size_t)gid * 8) = pack8bf(a, b);
    }
}

// ------------------------------------------------ l=1 head: basis1 + qkv + edge_coeff(l=0)
// grid: [0,264) gemm (bx=bid>>3, by=bid&7) | [264,2312) edge-coeff blocks (16 pairs each)
__launch_bounds__(256)
__global__ void basis1_qkv_ec(const bf16* __restrict__ x_bf, const bf16* __restrict__ E0,
                              const bf16* __restrict__ ewt1,
                              bf16* __restrict__ xw1, bf16* __restrict__ e0w1,
                              const bf16* __restrict__ xn_bf, const bf16* __restrict__ qkvt_l,
                              float* __restrict__ qkv,
                              const int* __restrict__ adj, const float* __restrict__ x,
                              float* __restrict__ w0o, float* __restrict__ w1o,
                              float* __restrict__ w2o) {
    __shared__ __align__(16) char lds[4 * 64 * RSTR];
    int bid = blockIdx.x;
    if (bid < 264) {
        int bx = bid >> 3, by = bid & 7;
        if (bx < 8)
            gemm64_body<3>(lds, x_bf, ewt1, xw1, nullptr, 512, 512, 512, bx, by, 0, 512);
        else if (bx == 8)
            gemm64_body<3>(lds, E0, ewt1, e0w1, nullptr, 64, 512, 512, 0, by, 0, 512);
        else {
            int tq = bx - 9;
            int z = tq >> 3, mb = tq & 7;
            gemm64_body<0>(lds, xn_bf, qkvt_l + (size_t)z * 262144,
                           qkv + (size_t)z * 262144, nullptr, 512, 512, 512, mb, by, 0, 512);
        }
    } else {
        int k = bid - 264;
        int tid = threadIdx.x;
        int lane = tid & 63, tyv = tid >> 6;
        for (int pp = 0; pp < 4; ++pp) {
            int pair = k * 16 + pp * 4 + tyv;
            int b = pair >> 12;
            int i = (pair >> 6) & 63;
            int j = pair & 63;
            const uint4*  e4  = (const uint4*)(E0 + (size_t)adj[pair] * H_);
            const float4* xi4 = (const float4*)(x + (size_t)(b * 64 + i) * H_);
            const float4* xj4 = (const float4*)(x + (size_t)(b * 64 + j) * H_);
            uint4  eu = e4[lane];
            float4 a0 = xi4[lane * 2], a1 = xi4[lane * 2 + 1];
            float4 c0 = xj4[lane * 2], c1 = xj4[lane * 2 + 1];
            float ef[8], af[8], cf[8];
            unpack8(eu, ef);
            af[0] = a0.x; af[1] = a0.y; af[2] = a0.z; af[3] = a0.w;
            af[4] = a1.x; af[5] = a1.y; af[6] = a1.z; af[7] = a1.w;
            cf[0] = c0.x; cf[1] = c0.y; cf[2] = c0.z; cf[3] = c0.w;
            cf[4] = c1.x; cf[5] = c1.y; cf[6] = c1.z; cf[7] = c1.w;
            float s0 = 0.f, s1 = 0.f, s2 = 0.f;
            #pragma unroll
            for (int t = 0; t < 8; ++t) {
                s0 += ef[t] * ef[t]; s1 += ef[t] * af[t]; s2 += ef[t] * cf[t];
            }
            #pragma unroll
            for (int off = 32; off; off >>= 1) {
                s0 += __shfl_xor(s0, off);
                s1 += __shfl_xor(s1, off);
                s2 += __shfl_xor(s2, off);
            }
            float t0 = s0 * INV_SCALE, t1 = s1 * INV_SCALE, t2 = s2 * INV_SCALE;
            float m = fmaxf(t0, fmaxf(t1, t2));
            float e0 = expf(t0 - m), e1 = expf(t1 - m), e2 = expf(t2 - m);
            float inv = 1.0f / (e0 + e1 + e2);
            if (lane == 0) {
                w0o[pair] = e0 * inv;
                w1o[pair] = e1 * inv;
                w2o[pair] = e2 * inv;
            }
        }
    }
}

// ------------------------------------------------ l=2 head: basis2 + qkv + gram1
// grid: [0,328) gemm | [328,368) gram1 (b=k&7, z=k>>3)
__launch_bounds__(256)
__global__ void basis2_qkv_g1(const bf16* __restrict__ xw1, const bf16* __restrict__ x_bf,
                              const bf16* __restrict__ e0w1, const bf16* __restrict__ ewt2,
                              bf16* __restrict__ xw12, bf16* __restrict__ x2w2,
                              bf16* __restrict__ e0w12,
                              const bf16* __restrict__ xn_bf, const bf16* __restrict__ qkvt_l,
                              float* __restrict__ qkv, float* __restrict__ gbuf) {
    __shared__ __align__(16) char lds[4 * 64 * RSTR];
    int bid = blockIdx.x;
    if (bid < 328) {
        int bx = bid >> 3, by = bid & 7;
        if (bx < 8)
            gemm64_body<3>(lds, xw1, ewt2, xw12, nullptr, 512, 512, 512, bx, by, 0, 512);
        else if (bx < 16)
            gemm64_body<3>(lds, x_bf, ewt2, x2w2, nullptr, 512, 512, 512, bx - 8, by, 0, 512);
        else if (bx == 16)
            gemm64_body<3>(lds, e0w1, ewt2, e0w12, nullptr, 64, 512, 512, 0, by, 0, 512);
        else {
            int tq = bx - 17;
            int z = tq >> 3, mb = tq & 7;
            gemm64_body<0>(lds, xn_bf, qkvt_l + (size_t)z * 262144,
                           qkv + (size_t)z * 262144, nullptr, 512, 512, 512, mb, by, 0, 512);
        }
    } else {
        int k = bid - 328;
        int b = k & 7, z = k >> 3;
        size_t ob = (size_t)b * 32768;
        const bf16 *A, *Bt;
        switch (z) {
            case 0: A = xw1 + ob; Bt = xw1 + ob; break;
            case 1: A = e0w1;     Bt = xw1 + ob; break;
            case 2: A = xw1 + ob; Bt = x_bf + ob; break;
            case 3: A = e0w1;     Bt = x_bf + ob; break;
            default: A = e0w1;    Bt = e0w1;     break;
        }
        float* C = gbuf + (size_t)z * 32768 + (size_t)b * 4096;
        gemm64_body<0>(lds, A, Bt, C, nullptr, 64, 64, 512, 0, 0, 0, 512);
    }
}

// ------------------------------------------------ l=2: ptable(3) + coeff1
// grid: [0,192) ptable (z=bid>>6, b=(bid&63)>>3, h=bid&7) | [192,256) coeff1 (8 rows each)
__launch_bounds__(256)
__global__ void ptable2c(const float* __restrict__ q,
                         const bf16* __restrict__ B0, const bf16* __restrict__ B1,
                         const bf16* __restrict__ B2,
                         float* __restrict__ P0, float* __restrict__ P1,
                         float* __restrict__ P2,
                         const int* __restrict__ adj,
                         const float* __restrict__ c0a, const float* __restrict__ c1a,
                         const float* __restrict__ c2a, const float* __restrict__ gbuf,
                         float* __restrict__ w0o, float* __restrict__ w1o,
                         float* __restrict__ w2o) {
    __shared__ __align__(16) char lds[4 * 64 * RSTR];
    int bid = blockIdx.x;
    if (bid < 192) {
        int z = bid >> 6, rem = bid & 63;
        int b = rem >> 3, h = rem & 7;
        const bf16* Bt = (z == 0) ? B0 : (z == 1 ? B1 : B2);
        float* P = (z == 0) ? P0 : (z == 1 ? P1 : P2);
        ptable_body(lds, q, Bt, P, b, h, z == 2);
    } else {
        int k = bid - 192;
        int tid = threadIdx.x;
        int j = tid & 63;
        #pragma unroll
        for (int pass = 0; pass < 2; ++pass) {
            int row = k * 8 + pass * 4 + (tid >> 6);
            coeff1_body(adj, c0a, c1a, c2a, gbuf, row, j, w0o, w1o, w2o);
        }
    }
}

// ------------------------------------------------ l=1: ptable (2 bases), standalone
__launch_bounds__(256)
__global__ void ptable_kernel(const float* __restrict__ q,
                              const bf16* __restrict__ B0, const bf16* __restrict__ B1,
                              float* __restrict__ P0, float* __restrict__ P1) {
    __shared__ __align__(16) char lds[4 * 64 * RSTR];
    const int b = blockIdx.x, h = blockIdx.y, z = blockIdx.z;
    const bf16* Bt = (z == 0) ? B0 : B1;
    float* P = (z == 0) ? P0 : P1;
    ptable_body(lds, q, Bt, P, b, h, z == 1);
}

// ------------------------------------------------ l=3 head: qkv + gram2
// grid: [0,192) qkv (z=bid>>6, mb=(bid>>3)&7, by=bid&7) | [192,264) gram2
__launch_bounds__(256)
__global__ void l3qkv_g2(const bf16* __restrict__ xn_bf, const bf16* __restrict__ qkvt_l,
                         float* __restrict__ qkv,
                         const bf16* __restrict__ xw12, const bf16* __restrict__ x2w2,
                         const bf16* __restrict__ e0w12, const bf16* __restrict__ x_bf,
                         float* __restrict__ gbuf) {
    __shared__ __align__(16) char lds[4 * 64 * RSTR];
    int bid = blockIdx.x;
    if (bid < 192) {
        int z = bid >> 6, rem = bid & 63;
        int mb = rem >> 3, by = rem & 7;
        gemm64_body<0>(lds, xn_bf, qkvt_l + (size_t)z * 262144,
                       qkv + (size_t)z * 262144, nullptr, 512, 512, 512, mb, by, 0, 512);
    } else {
        int k = bid - 192;
        int b = k & 7, z = k >> 3;
        size_t ob = (size_t)b * 32768;
        const bf16 *A, *Bt;
        switch (z) {
            case 0: A = xw12 + ob; Bt = xw12 + ob; break;
            case 1: A = xw12 + ob; Bt = x2w2 + ob; break;
            case 2: A = x2w2 + ob; Bt = x2w2 + ob; break;
            case 3: A = e0w12;     Bt = xw12 + ob; break;
            case 4: A = e0w12;     Bt = x2w2 + ob; break;
            case 5: A = e0w12;     Bt = e0w12;     break;
            case 6: A = xw12 + ob; Bt = x_bf + ob; break;
            case 7: A = x2w2 + ob; Bt = x_bf + ob; break;
            default: A = e0w12;    Bt = x_bf + ob; break;
        }
        float* C = gbuf + (size_t)z * 32768 + (size_t)b * 4096;
        gemm64_body<0>(lds, A, Bt, C, nullptr, 64, 64, 512, 0, 0, 0, 512);
    }
}

// ------------------------------------------------ l=3: u_gemm + coeff2
// grid: [0,512) u (h=bid>>6, mb=(bid>>3)&7, nb=bid&7) | [512,576) coeff2 (8 rows each)
__launch_bounds__(256)
__global__ void u_c2(const float* __restrict__ q, const bf16* __restrict__ wc3,
                     bf16* __restrict__ ubf,
                     const int* __restrict__ adj,
                     const float* __restrict__ c0a, const float* __restrict__ c1a,
                     const float* __restrict__ c2a,
                     const float* __restrict__ c0b, const float* __restrict__ c1b,
                     const float* __restrict__ c2b,
                     const float* __restrict__ gbuf,
                     float* __restrict__ w0o, float* __restrict__ w1o,
                     float* __restrict__ w2o) {
    __shared__ __align__(16) char lds[4 * 64 * RSTR];
    int bid = blockIdx.x;
    if (bid < 512) {
        int h = bid >> 6, mb = (bid >> 3) & 7, nb = bid & 7;
        ugemm_body(lds, q, wc3, ubf, h, mb, nb);
    } else {
        int k = bid - 512;
        int tid = threadIdx.x;
        int j = tid & 63;
        #pragma unroll
        for (int pass = 0; pass < 2; ++pass) {
            int row = k * 8 + pass * 4 + (tid >> 6);
            coeff2_body(adj, c0a, c1a, c2a, c0b, c1b, c2b, gbuf, row, j, w0o, w1o, w2o);
        }
    }
}

// M-tables: for each b, U_b (512 rows (i,h) x 512 k) @ basis_b^T (64 x 512)
__launch_bounds__(256)
__global__ void mbuf_gemm(const bf16* __restrict__ ubf, const bf16* __restrict__ xw12,
                          const bf16* __restrict__ x2w2, const bf16* __restrict__ x_bf,
                          const bf16* __restrict__ e0w12,
                          float* __restrict__ MX, float* __restrict__ MY,
                          float* __restrict__ MZ, float* __restrict__ DE) {
    __shared__ __align__(16) char lds[4 * 64 * RSTR];
    int b = blockIdx.x, mt = blockIdx.y, z = blockIdx.z;
    const bf16* A = ubf + (size_t)b * 512 * 512;
    const bf16* Bt;
    float* C;
    if (z == 0)      { Bt = xw12 + (size_t)b * 64 * 512; C = MX + (size_t)b * 512 * 64; }
    else if (z == 1) { Bt = x2w2 + (size_t)b * 64 * 512; C = MY + (size_t)b * 512 * 64; }
    else if (z == 2) { Bt = x_bf + (size_t)b * 64 * 512; C = MZ + (size_t)b * 512 * 64; }
    else             { Bt = e0w12;                        C = DE + (size_t)b * 512 * 64; }
    gemm64_body<0>(lds, A, Bt, C, nullptr, 512, 64, 512, mt, 0, 0, 512);
}

// ---------------------- split-K reduce + residual + LN variants
__global__ void reduce_stack_ln(const float* __restrict__ part, const float* __restrict__ base,
                                float* __restrict__ resid, bf16* __restrict__ ffin_bf) {
    const int MN = 512 * H_;
    int row = blockIdx.x;
    int tid = threadIdx.x;
    size_t b0 = (size_t)row * H_;
    float v0 = base[b0 + tid], v1 = base[b0 + tid + 256];
    #pragma unroll
    for (int s = 0; s < 4; ++s) {
        v0 += part[(size_t)s * MN + b0 + tid];
        v1 += part[(size_t)s * MN + b0 + tid + 256];
    }
    resid[b0 + tid] = v0;
    resid[b0 + tid + 256] = v1;
    float s = v0 + v1, sq = v0 * v0 + v1 * v1;
    #pragma unroll
    for (int off = 32; off; off >>= 1) {
        s  += __shfl_xor(s,  off);
        sq += __shfl_xor(sq, off);
    }
    __shared__ float ls[4], lq[4];
    int w = tid >> 6;
    if ((tid & 63) == 0) { ls[w] = s; lq[w] = sq; }
    __syncthreads();
    float S = ls[0] + ls[1] + ls[2] + ls[3];
    float Q = lq[0] + lq[1] + lq[2] + lq[3];
    float mean = S * (1.0f / H_);
    float var  = Q * (1.0f / H_) - mean * mean;
    float inv  = rsqrtf(var + 1e-5f);
    ffin_bf[b0 + tid]       = f2bf((v0 - mean) * inv);
    ffin_bf[b0 + tid + 256] = f2bf((v1 - mean) * inv);
}

template <bool DO_LN>
__global__ void reduce_ln_kernel(const float* __restrict__ part, const float* __restrict__ resid,
                                 float* __restrict__ x, bf16* __restrict__ x_bf,
                                 float* __restrict__ xn, bf16* __restrict__ xn_bf) {
    const int MN = 512 * H_;
    int row = blockIdx.x;
    int tid = threadIdx.x;
    size_t base = (size_t)row * H_;
    float v0 = resid[base + tid], v1 = resid[base + tid + 256];
    #pragma unroll
    for (int s = 0; s < 4; ++s) {
        v0 += part[(size_t)s * MN + base + tid];
        v1 += part[(size_t)s * MN + base + tid + 256];
    }
    x[base + tid] = v0;
    x[base + tid + 256] = v1;
    x_bf[base + tid]       = f2bf(v0);
    x_bf[base + tid + 256] = f2bf(v1);
    if (DO_LN) {
        float s = v0 + v1, sq = v0 * v0 + v1 * v1;
        #pragma unroll
        for (int off = 32; off; off >>= 1) {
            s  += __shfl_xor(s,  off);
            sq += __shfl_xor(sq, off);
        }
        __shared__ float ls[4], lq[4];
        int w = tid >> 6;
        if ((tid & 63) == 0) { ls[w] = s; lq[w] = sq; }
        __syncthreads();
        float S = ls[0] + ls[1] + ls[2] + ls[3];
        float Q = lq[0] + lq[1] + lq[2] + lq[3];
        float mean = S * (1.0f / H_);
        float var  = Q * (1.0f / H_) - mean * mean;
        float inv  = rsqrtf(var + 1e-5f);
        float y0 = (v0 - mean) * inv, y1 = (v1 - mean) * inv;
        xn[base + tid]       = y0;
        xn[base + tid + 256] = y1;
        xn_bf[base + tid]       = f2bf(y0);
        xn_bf[base + tid + 256] = f2bf(y1);
    }
}

// ---------------------------------------------------------------- attention
// l=0: w-row gathered from E0[adj[pair]] (8-row table, L1-resident)
template <bool GATHER>
__global__ void attn_kernel(const float* __restrict__ qkv, const bf16* __restrict__ ew,
                            const int* __restrict__ adj, bf16* __restrict__ o) {
    const float* q = qkv;
    const float* k = qkv + (size_t)512 * H_;
    const float* v = qkv + (size_t)1024 * H_;
    int bi = blockIdx.x;
    int b  = bi >> 6;
    int ty = threadIdx.y;
    int h  = blockIdx.y * 4 + ty;
    int lane = threadIdx.x;
    __shared__ float qs[4][64], as[4][64];
    qs[ty][lane] = q[(size_t)bi * H_ + h * 64 + lane];
    __syncthreads();

    int j = lane;
    int pair = bi * 64 + j;
    int aj = adj[pair];
    const float4* k4 = (const float4*)(k + (size_t)(b * 64 + j) * H_ + h * 64);
    const uint4*  w4 = (const uint4*)((GATHER ? ew + (size_t)aj * H_
                                              : ew + (size_t)pair * H_) + h * 64);
    float acc = 0.f;
    #pragma unroll
    for (int t = 0; t < 8; ++t) {
        uint4 wu = w4[t];
        float4 ka = k4[2 * t], kb = k4[2 * t + 1];
        float wf[8];
        unpack8(wu, wf);
        const float* qq = &qs[ty][t * 8];
        acc += qq[0] * (ka.x + wf[0]) + qq[1] * (ka.y + wf[1])
             + qq[2] * (ka.z + wf[2]) + qq[3] * (ka.w + wf[3])
             + qq[4] * (kb.x + wf[4]) + qq[5] * (kb.y + wf[5])
             + qq[6] * (kb.z + wf[6]) + qq[7] * (kb.w + wf[7]);
    }
    float logit = acc * INV_SCALE;
    if (aj <= 0) logit = -INFINITY;

    float m = logit;
    #pragma unroll
    for (int off = 32; off; off >>= 1) m = fmaxf(m, __shfl_xor(m, off));
    float p = expf(logit - m);
    float s = p;
    #pragma unroll
    for (int off = 32; off; off >>= 1) s += __shfl_xor(s, off);
    as[ty][lane] = p / s;
    __syncthreads();

    const float* vbase = v + (size_t)(b * 64) * H_ + h * 64;
    float oacc = 0.f;
    int d = lane;
    #pragma unroll 8
    for (int jj = 0; jj < 64; ++jj)
        oacc += as[ty][jj] * vbase[(size_t)jj * H_ + d];
    o[(size_t)bi * H_ + h * 64 + d] = __float2bfloat16(oacc);
}

// l=1/l=2: w-term combined inline from P-tables
template <int MODE>
__global__ void attn13_kernel(const float* __restrict__ qkv, const int* __restrict__ adj,
        const float* __restrict__ c0a, const float* __restrict__ c1a, const float* __restrict__ c2a,
        const float* __restrict__ c0b, const float* __restrict__ c1b, const float* __restrict__ c2b,
        const float* __restrict__ PX, const float* __restrict__ PY, const float* __restrict__ PE,
        bf16* __restrict__ o) {
    const float* q = qkv;
    const float* k = qkv + (size_t)512 * H_;
    const float* v = qkv + (size_t)1024 * H_;
    int bi = blockIdx.x;
    int b  = bi >> 6, i = bi & 63;
    int ty = threadIdx.y;
    int h  = blockIdx.y * 4 + ty;
    int lane = threadIdx.x;
    __shared__ float qs[4][64], as[4][64];
    qs[ty][lane] = q[(size_t)bi * H_ + h * 64 + lane];
    __syncthreads();

    int j = lane;
    int p = bi * 64 + j;
    int t = adj[p];
    size_t pb = (((size_t)b * 8 + h) * 64 + i) * 64;
    float acc;
    if (MODE == 1) {
        acc = c0a[p] * PE[pb + t] + c1a[p] * PX[pb + i] + c2a[p] * PX[pb + j];
    } else {
        float a0 = c0b[p];
        float AE = a0 * c0a[p], Aa = a0 * c1a[p], Ab = a0 * c2a[p];
        float Ac = c1b[p], Ad = c2b[p];
        acc = AE * PE[pb + t] + Aa * PX[pb + i] + Ab * PX[pb + j]
            + Ac * PY[pb + i] + Ad * PY[pb + j];
    }
    const float4* k4 = (const float4*)(k + (size_t)(b * 64 + j) * H_ + h * 64);
    #pragma unroll
    for (int tt = 0; tt < 8; ++tt) {
        float4 ka = k4[2 * tt], kb = k4[2 * tt + 1];
        const float* qq = &qs[ty][tt * 8];
        acc += qq[0] * ka.x + qq[1] * ka.y + qq[2] * ka.z + qq[3] * ka.w
             + qq[4] * kb.x + qq[5] * kb.y + qq[6] * kb.z + qq[7] * kb.w;
    }
    float logit = acc * INV_SCALE;
    if (t <= 0) logit = -INFINITY;

    float m = logit;
    #pragma unroll
    for (int off = 32; off; off >>= 1) m = fmaxf(m, __shfl_xor(m, off));
    float pe = expf(logit - m);
    float s = pe;
    #pragma unroll
    for (int off = 32; off; off >>= 1) s += __shfl_xor(s, off);
    as[ty][lane] = pe / s;
    __syncthreads();

    const float* vbase = v + (size_t)(b * 64) * H_ + h * 64;
    float oacc = 0.f;
    int d = lane;
    #pragma unroll 8
    for (int jj = 0; jj < 64; ++jj)
        oacc += as[ty][jj] * vbase[(size_t)jj * H_ + d];
    o[(size_t)bi * H_ + h * 64 + d] = __float2bfloat16(oacc);
}

// l=3: w-term computed inline from M-tables + coeffs (s2_assemble fused in)
__global__ void attn3s2_kernel(const float* __restrict__ qkv, const int* __restrict__ adj,
        const float* __restrict__ c0a, const float* __restrict__ c1a, const float* __restrict__ c2a,
        const float* __restrict__ c0b, const float* __restrict__ c1b, const float* __restrict__ c2b,
        const float* __restrict__ v0c, const float* __restrict__ v1c, const float* __restrict__ v2c,
        const float* __restrict__ MX, const float* __restrict__ MY,
        const float* __restrict__ MZ, const float* __restrict__ DE,
        bf16* __restrict__ o) {
    const float* q = qkv;
    const float* k = qkv + (size_t)512 * H_;
    const float* v = qkv + (size_t)1024 * H_;
    int bi = blockIdx.x;
    int b  = bi >> 6, i = bi & 63;
    int ty = threadIdx.y;
    int h  = blockIdx.y * 4 + ty;
    int lane = threadIdx.x;
    __shared__ float qs[4][64], as[4][64];
    qs[ty][lane] = q[(size_t)bi * H_ + h * 64 + lane];
    __syncthreads();

    int j = lane;
    int p = bi * 64 + j;
    int t = adj[p];
    float v0 = v0c[p];
    float q0 = v0 * c0b[p];
    float AE = q0 * c0a[p], Aa = q0 * c1a[p], Ab = q0 * c2a[p];
    float Ac = v0 * c1b[p], Ad = v0 * c2b[p];
    float Ae = v1c[p], Af = v2c[p];
    size_t rb = ((size_t)b * 512 + i * 8 + h) * 64;
    float acc = AE * DE[rb + t]
              + Aa * MX[rb + i] + Ac * MY[rb + i] + Ae * MZ[rb + i]
              + Ab * MX[rb + j] + Ad * MY[rb + j] + Af * MZ[rb + j];

    const float4* k4 = (const float4*)(k + (size_t)(b * 64 + j) * H_ + h * 64);
    #pragma unroll
    for (int tt = 0; tt < 8; ++tt) {
        float4 ka = k4[2 * tt], kb = k4[2 * tt + 1];
        const float* qq = &qs[ty][tt * 8];
        acc += qq[0] * ka.x + qq[1] * ka.y + qq[2] * ka.z + qq[3] * ka.w
             + qq[4] * kb.x + qq[5] * kb.y + qq[6] * kb.z + qq[7] * kb.w;
    }
    float logit = acc * INV_SCALE;
    if (t <= 0) logit = -INFINITY;

    float m = logit;
    #pragma unroll
    for (int off = 32; off; off >>= 1) m = fmaxf(m, __shfl_xor(m, off));
    float pe = expf(logit - m);
    float s = pe;
    #pragma unroll
    for (int off = 32; off; off >>= 1) s += __shfl_xor(s, off);
    as[ty][lane] = pe / s;
    __syncthreads();

    const float* vbase = v + (size_t)(b * 64) * H_ + h * 64;
    float oacc = 0.f;
    int d = lane;
    #pragma unroll 8
    for (int jj = 0; jj < 64; ++jj)
        oacc += as[ty][jj] * vbase[(size_t)jj * H_ + d];
    o[(size_t)bi * H_ + h * 64 + d] = __float2bfloat16(oacc);
}

// ---------------------------------------------------------------- head
__global__ void cls_part_kernel(const float* __restrict__ x, const float* __restrict__ Wout,
                                float* __restrict__ clspart) {
    int b  = blockIdx.x;
    int cb = blockIdx.y;
    int ks = blockIdx.z;
    int tid = threadIdx.x;
    int c  = cb * 64 + (tid & 63);
    int kk = tid >> 6;
    const float* xr = x + (size_t)(b * 64) * H_;
    int h0 = ks * 128 + kk * 32;
    float acc = 0.f;
    #pragma unroll
    for (int h = 0; h < 32; ++h)
        acc += xr[h0 + h] * Wout[(size_t)(h0 + h) * H_ + c];
    __shared__ float red[4][64];
    red[kk][tid & 63] = acc;
    __syncthreads();
    if (tid < 64) {
        float v = red[0][tid] + red[1][tid] + red[2][tid] + red[3][tid];
        clspart[((size_t)ks * 8 + b) * H_ + cb * 64 + tid] = v;
    }
}

__global__ void cls_pred2_kernel(const float* __restrict__ clspart,
                                 const float* __restrict__ Wpred,
                                 const float* __restrict__ bpred,
                                 float* __restrict__ out) {
    int b = blockIdx.x;
    int tid = threadIdx.x;
    __shared__ float red0[4], red1[4];
    float a0 = 0.f, a1 = 0.f;
    #pragma unroll
    for (int t = 0; t < 2; ++t) {
        int c = tid + t * 256;
        float v = clspart[((size_t)0 * 8 + b) * H_ + c]
                + clspart[((size_t)1 * 8 + b) * H_ + c]
                + clspart[((size_t)2 * 8 + b) * H_ + c]
                + clspart[((size_t)3 * 8 + b) * H_ + c];
        float tv = tanhf(v);
        a0 += tv * Wpred[c * 2 + 0];
        a1 += tv * Wpred[c * 2 + 1];
    }
    #pragma unroll
    for (int off = 32; off; off >>= 1) {
        a0 += __shfl_xor(a0, off);
        a1 += __shfl_xor(a1, off);
    }
    int w = tid >> 6;
    if ((tid & 63) == 0) { red0[w] = a0; red1[w] = a1; }
    __syncthreads();
    if (tid == 0) {
        float s0 = red0[0] + red0[1] + red0[2] + red0[3] + bpred[0];
        float s1 = red1[0] + red1[1] + red1[2] + red1[3] + bpred[1];
        float m = fmaxf(s0, s1);
        float e0 = expf(s0 - m), e1 = expf(s1 - m);
        float inv = 1.0f / (e0 + e1);
        out[b * 2 + 0] = e0 * inv;
        out[b * 2 + 1] = e1 * inv;
    }
}

// ---------------------------------------------------------------- launch
extern "C" void kernel_launch(void* const* d_in, const int* in_sizes, int n_in,
                              void* d_out, int out_size, void* d_ws, size_t ws_size,
                              hipStream_t stream) {
    const int*   ids      = (const int*)d_in[0];
    const int*   adj      = (const int*)d_in[1];
    const float* atom_emb = (const float*)d_in[2];
    const float* bond_emb = (const float*)d_in[3];
    const float* Wq     = (const float*)d_in[4];
    const float* Wk     = (const float*)d_in[5];
    const float* Wv     = (const float*)d_in[6];
    const float* Wew    = (const float*)d_in[7];
    const float* Wstack = (const float*)d_in[8];
    const float* Wf1    = (const float*)d_in[9];
    const float* Wf2    = (const float*)d_in[10];
    const float* Wout   = (const float*)d_in[11];
    const float* Wpred  = (const float*)d_in[12];
    const float* bpred  = (const float*)d_in[13];

    char* ws = (char*)d_ws;
    size_t off = 0;
    auto alloc = [&](size_t bytes) {
        size_t o = off;
        off += (bytes + 255) & ~(size_t)255;
        return o;
    };
    const size_t ROWS  = (size_t)B_ * N_;
    const size_t PAIRS = (size_t)B_ * N_ * N_;
    const size_t KN    = (size_t)H_ * H_;

    float* x       = (float*)(ws + alloc(ROWS * H_ * 4));
    float* xn      = (float*)(ws + alloc(ROWS * H_ * 4));
    bf16*  xn_bf   = (bf16*) (ws + alloc(ROWS * H_ * 2));
    bf16*  x_bf    = (bf16*) (ws + alloc(ROWS * H_ * 2));
    float* qkv     = (float*)(ws + alloc(3 * ROWS * H_ * 4));
    bf16*  o_bf    = (bf16*) (ws + alloc(ROWS * H_ * 2));
    float* resid   = (float*)(ws + alloc(ROWS * H_ * 4));
    bf16*  ffin_bf = (bf16*) (ws + alloc(ROWS * H_ * 2));
    bf16*  ffh_bf  = (bf16*) (ws + alloc(ROWS * 4 * H_ * 2));
    float* part    = (float*)(ws + alloc(4 * ROWS * H_ * 4));
    float* clspart = (float*)(ws + alloc(4 * 8 * H_ * 4));
    bf16*  ubf     = (bf16*) (ws + alloc(ROWS * 8 * 512 * 2));           // 4 MB
    float* MX      = (float*)(ws + alloc((size_t)4096 * 64 * 4));        // 1 MB each
    float* MY      = (float*)(ws + alloc((size_t)4096 * 64 * 4));
    float* MZ      = (float*)(ws + alloc((size_t)4096 * 64 * 4));
    float* DE      = (float*)(ws + alloc((size_t)4096 * 64 * 4));
    float* PT0     = (float*)(ws + alloc((size_t)4096 * 64 * 4));        // P-tables
    float* PT1     = (float*)(ws + alloc((size_t)4096 * 64 * 4));
    float* PT2     = (float*)(ws + alloc((size_t)4096 * 64 * 4));
    float* gbuf    = (float*)(ws + alloc((size_t)9 * 8 * 4096 * 4));     // Gram tables
    bf16*  wc3     = (bf16*) (ws + alloc(KN * 2));
    bf16*  E0      = (bf16*) (ws + alloc(64 * H_ * 2));      // padded to 64 rows
    bf16*  e0w1    = (bf16*) (ws + alloc(64 * H_ * 2));
    bf16*  e0w12   = (bf16*) (ws + alloc(64 * H_ * 2));
    bf16*  xw1     = (bf16*) (ws + alloc(KN * 2));
    bf16*  xw12    = (bf16*) (ws + alloc(KN * 2));
    bf16*  x2w2    = (bf16*) (ws + alloc(KN * 2));
    float* cw      = (float*)(ws + alloc(9 * PAIRS * 4));    // edge softmax coeffs
    bf16*  qkvt    = (bf16*) (ws + alloc((size_t)L_ * 3 * KN * 2));
    bf16*  ewt     = (bf16*) (ws + alloc((size_t)L_ * KN * 2));
    bf16*  stackt  = (bf16*) (ws + alloc((size_t)L_ * KN * 2));
    bf16*  f1t     = (bf16*) (ws + alloc((size_t)L_ * 4 * KN * 2));
    bf16*  f2t     = (bf16*) (ws + alloc((size_t)L_ * 4 * KN * 2));
    (void)ws_size;

    float* cw0a = cw;
    float* cw1a = cw + PAIRS;
    float* cw2a = cw + 2 * PAIRS;
    float* cw0b = cw + 3 * PAIRS;
    float* cw1b = cw + 4 * PAIRS;
    float* cw2b = cw + 5 * PAIRS;
    float* cw0c = cw + 6 * PAIRS;
    float* cw1c = cw + 7 * PAIRS;
    float* cw2c = cw + 8 * PAIRS;

    // one-shot setup: embed+LN, all weight transposes (64x64 vectorized), E0, Wew3 cast
    setup_kernel<<<4096, 256, 0, stream>>>(ids, atom_emb, bond_emb,
                                           Wq, Wk, Wv, Wew, Wstack, Wf1, Wf2,
                                           xn, xn_bf, qkvt, ewt, stackt, f1t, f2t,
                                           E0, wc3);

    for (int l = 0; l < L_; ++l) {
        if (l == 0) {
            mfma_gemm_s<0, false><<<dim3(8, 8, 3), 256, 0, stream>>>(
                xn_bf, qkvt, qkv, nullptr, 512, 512, 512);
            attn_kernel<true><<<dim3(512, 2), dim3(64, 4), 0, stream>>>(qkv, E0, adj, o_bf);
        } else if (l == 1) {
            // basis1 + qkv + edge_coeff(l=0)
            basis1_qkv_ec<<<2312, 256, 0, stream>>>(
                x_bf, E0, ewt + KN, xw1, e0w1, xn_bf, qkvt + (size_t)3 * KN, qkv,
                adj, x, cw0a, cw1a, cw2a);
            ptable_kernel<<<dim3(8, 8, 2), 256, 0, stream>>>(qkv, xw1, e0w1, PT0, PT1);
            attn13_kernel<1><<<dim3(512, 2), dim3(64, 4), 0, stream>>>(
                qkv, adj, cw0a, cw1a, cw2a, nullptr, nullptr, nullptr,
                PT0, nullptr, PT1, o_bf);
        } else if (l == 2) {
            // basis2 + qkv + gram1
            basis2_qkv_g1<<<368, 256, 0, stream>>>(
                xw1, x_bf, e0w1, ewt + 2 * KN, xw12, x2w2, e0w12,
                xn_bf, qkvt + (size_t)6 * KN, qkv, gbuf);
            // ptables + coeff1
            ptable2c<<<256, 256, 0, stream>>>(
                qkv, xw12, x2w2, e0w12, PT0, PT1, PT2,
                adj, cw0a, cw1a, cw2a, gbuf, cw0b, cw1b, cw2b);
            attn13_kernel<2><<<dim3(512, 2), dim3(64, 4), 0, stream>>>(
                qkv, adj, cw0a, cw1a, cw2a, cw0b, cw1b, cw2b,
                PT0, PT1, PT2, o_bf);
        } else {
            // qkv + gram2
            l3qkv_g2<<<264, 256, 0, stream>>>(
                xn_bf, qkvt + (size_t)9 * KN, qkv, xw12, x2w2, e0w12, x_bf, gbuf);
            // u + coeff2
            u_c2<<<576, 256, 0, stream>>>(
                qkv, wc3, ubf, adj, cw0a, cw1a, cw2a, cw0b, cw1b, cw2b,
                gbuf, cw0c, cw1c, cw2c);
            mbuf_gemm<<<dim3(8, 8, 4), 256, 0, stream>>>(ubf, xw12, x2w2, x_bf, e0w12,
                                                         MX, MY, MZ, DE);
            attn3s2_kernel<<<dim3(512, 2), dim3(64, 4), 0, stream>>>(
                qkv, adj, cw0a, cw1a, cw2a, cw0b, cw1b, cw2b, cw0c, cw1c, cw2c,
                MX, MY, MZ, DE, o_bf);
        }

        mfma_gemm_s<0, true><<<dim3(8, 8, 4), 256, 0, stream>>>(
            o_bf, stackt + (size_t)l * KN, part, nullptr, 512, 512, 512);
        reduce_stack_ln<<<512, 256, 0, stream>>>(part, xn, resid, ffin_bf);
        mfma_gemm_s<2, false><<<dim3(8, 32), 256, 0, stream>>>(
            ffin_bf, f1t + (size_t)l * 4 * KN, ffh_bf, nullptr, 512, 2048, 512);
        mfma_gemm_s<0, true><<<dim3(8, 8, 4), 256, 0, stream>>>(
            ffh_bf, f2t + (size_t)l * 4 * KN, part, nullptr, 512, 512, 2048);
        if (l < L_ - 1)
            reduce_ln_kernel<true><<<512, 256, 0, stream>>>(part, resid, x, x_bf, xn, xn_bf);
        else
            reduce_ln_kernel<false><<<512, 256, 0, stream>>>(part, resid, x, x_bf, xn, xn_bf);
    }

    cls_part_kernel<<<dim3(8, 8, 4), 256, 0, stream>>>(x, Wout, clspart);
    cls_pred2_kernel<<<8, 256, 0, stream>>>(clspart, Wpred, bpred, (float*)d_out);
}

// Round 7
// 347.867 us; speedup vs baseline: 1.4295x; 1.0464x over previous
//
#include <hip/hip_runtime.h>
#include <hip/hip_bf16.h>

typedef __hip_bfloat16 bf16;

#define B_     8
#define N_     64
#define H_     512
#define HEADS_ 8
#define SP_    64
#define L_     4
static constexpr float INV_SCALE = 0.044194173824159216f; // 1/sqrt(512)

typedef __attribute__((ext_vector_type(8))) short short8;
typedef __attribute__((ext_vector_type(4))) float f32x4;

__device__ __forceinline__ void unpack8(uint4 u, float* f) {
    f[0] = __uint_as_float(u.x << 16); f[1] = __uint_as_float(u.x & 0xffff0000u);
    f[2] = __uint_as_float(u.y << 16); f[3] = __uint_as_float(u.y & 0xffff0000u);
    f[4] = __uint_as_float(u.z << 16); f[5] = __uint_as_float(u.z & 0xffff0000u);
    f[6] = __uint_as_float(u.w << 16); f[7] = __uint_as_float(u.w & 0xffff0000u);
}

__device__ __forceinline__ bf16 f2bf(float v) { return __float2bfloat16(v); }

__device__ __forceinline__ uint4 pack8bf(float4 a, float4 b) {
    __align__(16) bf16 t[8];
    t[0] = f2bf(a.x); t[1] = f2bf(a.y); t[2] = f2bf(a.z); t[3] = f2bf(a.w);
    t[4] = f2bf(b.x); t[5] = f2bf(b.y); t[6] = f2bf(b.z); t[7] = f2bf(b.w);
    return *(const uint4*)t;
}

#define RSTR 80

// ------------------------------------------------------------ GEMM body (64-tile)
// EPI: 0 = fp32 out, 1 = fp32 + residual, 2 = relu->bf16, 3 = bf16
template <int EPI>
__device__ __forceinline__ void gemm64_body(char* lds,
        const bf16* __restrict__ A, const bf16* __restrict__ Bt,
        void* __restrict__ Cv, const float* __restrict__ R,
        int M, int N, int K, int bx, int by, int kbeg, int kend) {
    char* As = lds;
    char* Bs = lds + 2 * 64 * RSTR;
    const int tid = threadIdx.x;
    const int bm = bx * 64, bn = by * 64;
    const int w = tid >> 6, lane = tid & 63;
    const int wr = (w >> 1) * 32, wc = (w & 1) * 32;
    const int m0 = lane & 15, q4 = lane >> 4;

    f32x4 acc[2][2] = {};

    const int rA = tid >> 3;
    const int cA = tid & 7;
    const int ksP = cA >> 2;
    const int cB = (cA & 3) * 16;
    const int cE = cA * 8;

    for (int k0 = kbeg; k0 < kend; k0 += 64) {
        uint4 a0 = *(const uint4*)(A  + (size_t)(bm + rA) * K + k0 + cE);
        uint4 a1 = *(const uint4*)(A  + (size_t)(bm + rA + 32) * K + k0 + cE);
        uint4 b0 = *(const uint4*)(Bt + (size_t)(bn + rA) * K + k0 + cE);
        uint4 b1 = *(const uint4*)(Bt + (size_t)(bn + rA + 32) * K + k0 + cE);
        __syncthreads();
        *(uint4*)(As + ksP * (64 * RSTR) + rA * RSTR + cB) = a0;
        *(uint4*)(As + ksP * (64 * RSTR) + (rA + 32) * RSTR + cB) = a1;
        *(uint4*)(Bs + ksP * (64 * RSTR) + rA * RSTR + cB) = b0;
        *(uint4*)(Bs + ksP * (64 * RSTR) + (rA + 32) * RSTR + cB) = b1;
        __syncthreads();
        short8 af[2][2], bfr[2][2];
        #pragma unroll
        for (int ks = 0; ks < 2; ++ks)
            #pragma unroll
            for (int t = 0; t < 2; ++t) {
                af[ks][t]  = *(const short8*)(As + ks * (64 * RSTR) + (wr + t * 16 + m0) * RSTR + q4 * 16);
                bfr[ks][t] = *(const short8*)(Bs + ks * (64 * RSTR) + (wc + t * 16 + m0) * RSTR + q4 * 16);
            }
        #pragma unroll
        for (int ks = 0; ks < 2; ++ks)
            #pragma unroll
            for (int mt = 0; mt < 2; ++mt)
                #pragma unroll
                for (int nt = 0; nt < 2; ++nt)
                    acc[mt][nt] = __builtin_amdgcn_mfma_f32_16x16x32_bf16(
                        af[ks][mt], bfr[ks][nt], acc[mt][nt], 0, 0, 0);
    }

    if (EPI <= 1) {
        float* C = (float*)Cv;
        #pragma unroll
        for (int mt = 0; mt < 2; ++mt)
            #pragma unroll
            for (int i = 0; i < 4; ++i) {
                int row = bm + wr + mt * 16 + q4 * 4 + i;
                #pragma unroll
                for (int nt = 0; nt < 2; ++nt) {
                    int col = bn + wc + nt * 16 + m0;
                    float v = acc[mt][nt][i];
                    if (EPI == 1) v += R[(size_t)row * N + col];
                    C[(size_t)row * N + col] = v;
                }
            }
    } else {
        bf16* C = (bf16*)Cv;
        #pragma unroll
        for (int mt = 0; mt < 2; ++mt)
            #pragma unroll
            for (int i = 0; i < 4; ++i) {
                int row = bm + wr + mt * 16 + q4 * 4 + i;
                #pragma unroll
                for (int nt = 0; nt < 2; ++nt) {
                    int col = bn + wc + nt * 16 + m0;
                    float v = acc[mt][nt][i];
                    if (EPI == 2) v = fmaxf(v, 0.0f);
                    C[(size_t)row * N + col] = __float2bfloat16(v);
                }
            }
    }
}

template <int EPI, bool SPLIT>
__launch_bounds__(256)
__global__ void mfma_gemm_s(const bf16* __restrict__ A, const bf16* __restrict__ Bt,
                            void* __restrict__ Cv, const float* __restrict__ R,
                            int M, int N, int K) {
    __shared__ __align__(16) char lds[4 * 64 * RSTR];
    int kbeg = 0, kend = K;
    const bf16* B2 = Bt;
    void* C2 = Cv;
    if (SPLIT) {
        int ks = K / gridDim.z;
        kbeg = blockIdx.z * ks;
        kend = kbeg + ks;
        C2 = (void*)((float*)Cv + (size_t)blockIdx.z * M * N);
        gemm64_body<0>(lds, A, B2, C2, nullptr, M, N, K, blockIdx.x, blockIdx.y, kbeg, kend);
    } else {
        B2 = Bt + (size_t)blockIdx.z * N * K;
        if (EPI <= 1) C2 = (void*)((float*)Cv + (size_t)blockIdx.z * M * N);
        gemm64_body<EPI>(lds, A, B2, C2, R, M, N, K, blockIdx.x, blockIdx.y, kbeg, kend);
    }
}

// ------------------------------------------------ device bodies (shared pieces)

// per-(b,h) q . basis^T : P[(b,h,i,r)] = sum_{d<64} q[b,i,h*64+d] * Bz[r,h*64+d]
__device__ __forceinline__ void ptable_body(char* lds, const float* __restrict__ q,
        const bf16* __restrict__ Bt, float* __restrict__ P, int b, int h, bool shr) {
    char* As = lds;
    char* Bs = lds + 2 * 64 * RSTR;
    const int tid = threadIdx.x;
    const int w = tid >> 6, lane = tid & 63;
    const int wr = (w >> 1) * 32, wc = (w & 1) * 32;
    const int m0 = lane & 15, q4 = lane >> 4;
    const int rA = tid >> 3;
    const int cA = tid & 7;
    const int ksP = cA >> 2;
    const int cB = (cA & 3) * 16;
    const int cE = cA * 8;

    const float* Aq = q + (size_t)(b * 64) * 512 + h * 64;
    const bf16*  Bb = Bt + (shr ? (size_t)0 : (size_t)b * 64 * 512) + h * 64;

    float4 fa0 = *(const float4*)(Aq + (size_t)rA * 512 + cE);
    float4 fa1 = *(const float4*)(Aq + (size_t)rA * 512 + cE + 4);
    float4 fb0 = *(const float4*)(Aq + (size_t)(rA + 32) * 512 + cE);
    float4 fb1 = *(const float4*)(Aq + (size_t)(rA + 32) * 512 + cE + 4);
    uint4 bv0 = *(const uint4*)(Bb + (size_t)rA * 512 + cE);
    uint4 bv1 = *(const uint4*)(Bb + (size_t)(rA + 32) * 512 + cE);
    uint4 av0 = pack8bf(fa0, fa1);
    uint4 av1 = pack8bf(fb0, fb1);
    *(uint4*)(As + ksP * (64 * RSTR) + rA * RSTR + cB) = av0;
    *(uint4*)(As + ksP * (64 * RSTR) + (rA + 32) * RSTR + cB) = av1;
    *(uint4*)(Bs + ksP * (64 * RSTR) + rA * RSTR + cB) = bv0;
    *(uint4*)(Bs + ksP * (64 * RSTR) + (rA + 32) * RSTR + cB) = bv1;
    __syncthreads();

    f32x4 acc[2][2] = {};
    short8 af[2][2], bfr[2][2];
    #pragma unroll
    for (int ks = 0; ks < 2; ++ks)
        #pragma unroll
        for (int t = 0; t < 2; ++t) {
            af[ks][t]  = *(const short8*)(As + ks * (64 * RSTR) + (wr + t * 16 + m0) * RSTR + q4 * 16);
            bfr[ks][t] = *(const short8*)(Bs + ks * (64 * RSTR) + (wc + t * 16 + m0) * RSTR + q4 * 16);
        }
    #pragma unroll
    for (int ks = 0; ks < 2; ++ks)
        #pragma unroll
        for (int mt = 0; mt < 2; ++mt)
            #pragma unroll
            for (int nt = 0; nt < 2; ++nt)
                acc[mt][nt] = __builtin_amdgcn_mfma_f32_16x16x32_bf16(
                    af[ks][mt], bfr[ks][nt], acc[mt][nt], 0, 0, 0);

    #pragma unroll
    for (int mt = 0; mt < 2; ++mt)
        #pragma unroll
        for (int i = 0; i < 4; ++i) {
            int row = wr + mt * 16 + q4 * 4 + i;
            #pragma unroll
            for (int nt = 0; nt < 2; ++nt) {
                int col = wc + nt * 16 + m0;
                P[(((size_t)b * 8 + h) * 64 + row) * 64 + col] = acc[mt][nt][i];
            }
        }
}

// u_bf[b,i,h,k] = sum_d q[b,i,h*64+d] * Wew3[k,h*64+d]
__device__ __forceinline__ void ugemm_body(char* lds, const float* __restrict__ q,
        const bf16* __restrict__ wc3, bf16* __restrict__ ubf, int h, int mb, int nb) {
    char* As = lds;
    char* Bs = lds + 2 * 64 * RSTR;
    const int tid = threadIdx.x;
    const int w = tid >> 6, lane = tid & 63;
    const int wr = (w >> 1) * 32, wc = (w & 1) * 32;
    const int m0 = lane & 15, q4 = lane >> 4;
    const int rA = tid >> 3;
    const int cA = tid & 7;
    const int ksP = cA >> 2;
    const int cB = (cA & 3) * 16;
    const int cE = cA * 8;

    const float* Aq = q + (size_t)(mb * 64) * 512 + h * 64;
    const bf16*  Bt = wc3 + (size_t)(nb * 64) * 512 + h * 64;

    float4 fa0 = *(const float4*)(Aq + (size_t)rA * 512 + cE);
    float4 fa1 = *(const float4*)(Aq + (size_t)rA * 512 + cE + 4);
    float4 fb0 = *(const float4*)(Aq + (size_t)(rA + 32) * 512 + cE);
    float4 fb1 = *(const float4*)(Aq + (size_t)(rA + 32) * 512 + cE + 4);
    uint4 b0 = *(const uint4*)(Bt + (size_t)rA * 512 + cE);
    uint4 b1 = *(const uint4*)(Bt + (size_t)(rA + 32) * 512 + cE);
    uint4 a0 = pack8bf(fa0, fa1);
    uint4 a1 = pack8bf(fb0, fb1);
    *(uint4*)(As + ksP * (64 * RSTR) + rA * RSTR + cB) = a0;
    *(uint4*)(As + ksP * (64 * RSTR) + (rA + 32) * RSTR + cB) = a1;
    *(uint4*)(Bs + ksP * (64 * RSTR) + rA * RSTR + cB) = b0;
    *(uint4*)(Bs + ksP * (64 * RSTR) + (rA + 32) * RSTR + cB) = b1;
    __syncthreads();

    f32x4 acc[2][2] = {};
    short8 af[2][2], bfr[2][2];
    #pragma unroll
    for (int ks = 0; ks < 2; ++ks)
        #pragma unroll
        for (int t = 0; t < 2; ++t) {
            af[ks][t]  = *(const short8*)(As + ks * (64 * RSTR) + (wr + t * 16 + m0) * RSTR + q4 * 16);
            bfr[ks][t] = *(const short8*)(Bs + ks * (64 * RSTR) + (wc + t * 16 + m0) * RSTR + q4 * 16);
        }
    #pragma unroll
    for (int ks = 0; ks < 2; ++ks)
        #pragma unroll
        for (int mt = 0; mt < 2; ++mt)
            #pragma unroll
            for (int nt = 0; nt < 2; ++nt)
                acc[mt][nt] = __builtin_amdgcn_mfma_f32_16x16x32_bf16(
                    af[ks][mt], bfr[ks][nt], acc[mt][nt], 0, 0, 0);

    #pragma unroll
    for (int mt = 0; mt < 2; ++mt)
        #pragma unroll
        for (int i = 0; i < 4; ++i) {
            int row = mb * 64 + wr + mt * 16 + q4 * 4 + i;
            #pragma unroll
            for (int nt = 0; nt < 2; ++nt) {
                int col = nb * 64 + wc + nt * 16 + m0;
                ubf[(size_t)row * 4096 + h * 512 + col] = f2bf(acc[mt][nt][i]);
            }
        }
}

// edge softmax coeffs from l=1 Gram tables (per-thread; row=(b,i), j)
__device__ __forceinline__ void coeff1_body(const int* __restrict__ adj,
        const float* __restrict__ c0a, const float* __restrict__ c1a, const float* __restrict__ c2a,
        const float* __restrict__ gbuf, int row, int j,
        float* __restrict__ w0o, float* __restrict__ w1o, float* __restrict__ w2o) {
    int b = row >> 6, i = row & 63;
    int p = row * 64 + j;
    int t = adj[p];
    const float* TXX = gbuf + 0 * 32768 + (size_t)b * 4096;
    const float* TEX = gbuf + 1 * 32768 + (size_t)b * 4096;
    const float* TXx = gbuf + 2 * 32768 + (size_t)b * 4096;
    const float* TEx = gbuf + 3 * 32768 + (size_t)b * 4096;
    const float* TEE = gbuf + 4 * 32768 + (size_t)b * 4096;
    float c0 = c0a[p], c1 = c1a[p], c2 = c2a[p];
    float s1 = c0 * TEx[t * 64 + i] + c1 * TXx[i * 64 + i] + c2 * TXx[j * 64 + i];
    float s2 = c0 * TEx[t * 64 + j] + c1 * TXx[i * 64 + j] + c2 * TXx[j * 64 + j];
    float s0 = c0 * c0 * TEE[t * 64 + t] + c1 * c1 * TXX[i * 64 + i] + c2 * c2 * TXX[j * 64 + j]
             + 2.f * c0 * c1 * TEX[t * 64 + i] + 2.f * c0 * c2 * TEX[t * 64 + j]
             + 2.f * c1 * c2 * TXX[i * 64 + j];
    float t0 = s0 * INV_SCALE, t1 = s1 * INV_SCALE, t2 = s2 * INV_SCALE;
    float m = fmaxf(t0, fmaxf(t1, t2));
    float e0 = expf(t0 - m), e1 = expf(t1 - m), e2 = expf(t2 - m);
    float inv = 1.0f / (e0 + e1 + e2);
    w0o[p] = e0 * inv;
    w1o[p] = e1 * inv;
    w2o[p] = e2 * inv;
}

// edge softmax coeffs from l=2 Gram tables
__device__ __forceinline__ void coeff2_body(const int* __restrict__ adj,
        const float* __restrict__ c0a, const float* __restrict__ c1a, const float* __restrict__ c2a,
        const float* __restrict__ c0b, const float* __restrict__ c1b, const float* __restrict__ c2b,
        const float* __restrict__ gbuf, int row, int j,
        float* __restrict__ w0o, float* __restrict__ w1o, float* __restrict__ w2o) {
    int b = row >> 6, i = row & 63;
    int p = row * 64 + j;
    int t = adj[p];
    const float* TXX = gbuf + 0 * 32768 + (size_t)b * 4096;
    const float* TXY = gbuf + 1 * 32768 + (size_t)b * 4096;
    const float* TYY = gbuf + 2 * 32768 + (size_t)b * 4096;
    const float* TEX = gbuf + 3 * 32768 + (size_t)b * 4096;
    const float* TEY = gbuf + 4 * 32768 + (size_t)b * 4096;
    const float* TEE = gbuf + 5 * 32768 + (size_t)b * 4096;
    const float* TXx = gbuf + 6 * 32768 + (size_t)b * 4096;
    const float* TYx = gbuf + 7 * 32768 + (size_t)b * 4096;
    const float* TEx = gbuf + 8 * 32768 + (size_t)b * 4096;
    float a0 = c0b[p];
    float AE = a0 * c0a[p], Aa = a0 * c1a[p], Ab = a0 * c2a[p];
    float Ac = c1b[p], Ad = c2b[p];
    float s1 = AE * TEx[t * 64 + i] + Aa * TXx[i * 64 + i] + Ab * TXx[j * 64 + i]
             + Ac * TYx[i * 64 + i] + Ad * TYx[j * 64 + i];
    float s2 = AE * TEx[t * 64 + j] + Aa * TXx[i * 64 + j] + Ab * TXx[j * 64 + j]
             + Ac * TYx[i * 64 + j] + Ad * TYx[j * 64 + j];
    float s0 = AE * AE * TEE[t * 64 + t] + Aa * Aa * TXX[i * 64 + i] + Ab * Ab * TXX[j * 64 + j]
             + Ac * Ac * TYY[i * 64 + i] + Ad * Ad * TYY[j * 64 + j]
             + 2.f * AE * Aa * TEX[t * 64 + i] + 2.f * AE * Ab * TEX[t * 64 + j]
             + 2.f * AE * Ac * TEY[t * 64 + i] + 2.f * AE * Ad * TEY[t * 64 + j]
             + 2.f * Aa * Ab * TXX[i * 64 + j]
             + 2.f * Aa * Ac * TXY[i * 64 + i] + 2.f * Aa * Ad * TXY[i * 64 + j]
             + 2.f * Ab * Ac * TXY[j * 64 + i] + 2.f * Ab * Ad * TXY[j * 64 + j]
             + 2.f * Ac * Ad * TYY[i * 64 + j];
    float t0 = s0 * INV_SCALE, t1 = s1 * INV_SCALE, t2 = s2 * INV_SCALE;
    float m = fmaxf(t0, fmaxf(t1, t2));
    float e0 = expf(t0 - m), e1 = expf(t1 - m), e2 = expf(t2 - m);
    float inv = 1.0f / (e0 + e1 + e2);
    w0o[p] = e0 * inv;
    w1o[p] = e1 * inv;
    w2o[p] = e2 * inv;
}

// ------------------------------------------------ merged one-shot setup kernel
// grid: [0,512) embed | [512,1792) sq transpose 64x64 | [1792,3840) rect transpose 64x64
//       [3840,3968) bond_bf cast/zero | [3968,4096) cast_w3
__launch_bounds__(256)
__global__ void setup_kernel(const int* __restrict__ ids, const float* __restrict__ atom_emb,
                             const float* __restrict__ bond_emb,
                             const float* __restrict__ Wq, const float* __restrict__ Wk,
                             const float* __restrict__ Wv, const float* __restrict__ Wew,
                             const float* __restrict__ Wst,
                             const float* __restrict__ Wf1, const float* __restrict__ Wf2,
                             float* __restrict__ xn, bf16* __restrict__ xn_bf,
                             bf16* __restrict__ qkvt, bf16* __restrict__ ewt,
                             bf16* __restrict__ stackt,
                             bf16* __restrict__ f1t, bf16* __restrict__ f2t,
                             bf16* __restrict__ bond_bf, bf16* __restrict__ wc3) {
    __shared__ __align__(16) float smem[64 * 65];   // 16.6 KB; reused by all sections
    const size_t KN = (size_t)H_ * H_;
    int bid = blockIdx.x;
    int tid = threadIdx.x;

    if (bid < 512) {
        // ---- embed + LN
        int row = bid;
        const float* r = atom_emb + (size_t)ids[row] * H_;
        float x0 = r[tid], x1 = r[tid + 256];
        float s = x0 + x1, sq = x0 * x0 + x1 * x1;
        #pragma unroll
        for (int off = 32; off; off >>= 1) {
            s  += __shfl_xor(s,  off);
            sq += __shfl_xor(sq, off);
        }
        int w = tid >> 6;
        if ((tid & 63) == 0) { smem[w] = s; smem[4 + w] = sq; }
        __syncthreads();
        float S = smem[0] + smem[1] + smem[2] + smem[3];
        float Q = smem[4] + smem[5] + smem[6] + smem[7];
        float mean = S * (1.0f / H_);
        float var  = Q * (1.0f / H_) - mean * mean;
        float inv  = rsqrtf(var + 1e-5f);
        float y0 = (x0 - mean) * inv, y1 = (x1 - mean) * inv;
        xn[(size_t)row * H_ + tid]       = y0;
        xn[(size_t)row * H_ + tid + 256] = y1;
        xn_bf[(size_t)row * H_ + tid]       = f2bf(y0);
        xn_bf[(size_t)row * H_ + tid + 256] = f2bf(y1);
    } else if (bid < 3840) {
        // ---- 64x64 fp32 -> bf16 transpose tiles (vectorized)
        const float* W; bf16* Wt; int K, N, kb, nb;
        if (bid < 1792) {
            int idx = bid - 512;
            int z = idx >> 6, rem = idx & 63;
            kb = rem & 7; nb = rem >> 3;
            K = 512; N = 512;
            if (z < 12) {
                int sss = z >> 2, l = z & 3;
                W  = (sss == 0 ? Wq : sss == 1 ? Wk : Wv) + (size_t)l * KN;
                Wt = qkvt + (size_t)l * 3 * KN + (size_t)sss * KN;
            } else if (z < 16) {
                int l = z - 12;
                W = Wew + (size_t)l * KN; Wt = ewt + (size_t)l * KN;
            } else {
                int l = z - 16;
                W = Wst + (size_t)l * KN; Wt = stackt + (size_t)l * KN;
            }
        } else {
            int idx = bid - 1792;
            int z = idx >> 8;       // 0..7
            int idx2 = idx & 255;
            const size_t KN4 = (size_t)4 * H_ * H_;
            if (z < 4) {
                W = Wf1 + (size_t)z * KN4; Wt = f1t + (size_t)z * KN4; K = 512; N = 2048;
                kb = idx2 & 7; nb = idx2 >> 3;
            } else {
                W = Wf2 + (size_t)(z - 4) * KN4; Wt = f2t + (size_t)(z - 4) * KN4; K = 2048; N = 512;
                kb = idx2 >> 3; nb = idx2 & 7;
            }
        }
        int k0 = kb * 64, n0 = nb * 64;
        float (*tt)[65] = (float(*)[65])smem;
        int rr = tid >> 4, c4 = (tid & 15) * 4;
        #pragma unroll
        for (int it = 0; it < 4; ++it) {
            float4 v = *(const float4*)(W + (size_t)(k0 + rr + it * 16) * N + n0 + c4);
            tt[rr + it * 16][c4 + 0] = v.x;
            tt[rr + it * 16][c4 + 1] = v.y;
            tt[rr + it * 16][c4 + 2] = v.z;
            tt[rr + it * 16][c4 + 3] = v.w;
        }
        __syncthreads();
        int nr = tid >> 3, k8 = (tid & 7) * 8;
        #pragma unroll
        for (int it = 0; it < 2; ++it) {
            int nn = nr + it * 32;
            __align__(16) bf16 ob[8];
            #pragma unroll
            for (int e = 0; e < 8; ++e)
                ob[e] = f2bf(tt[k8 + e][nn]);
            *(uint4*)(Wt + (size_t)(n0 + nn) * K + k0 + k8) = *(const uint4*)ob;
        }
    } else if (bid < 3968) {
        // ---- bond_bf: bf16 cast of bond_emb rows <8; rows 8..63 zero (pad for E0 GEMM)
        int idx = bid - 3840;
        int t = idx >> 1;
        int c = (idx & 1) * 256 + tid;
        bond_bf[t * 512 + c] = (t < 8) ? f2bf(bond_emb[t * 512 + c]) : f2bf(0.0f);
    } else {
        // ---- cast Wew3 -> bf16
        int idx = bid - 3968;
        int gid = idx * 256 + tid;
        const float4* p = (const float4*)(Wew + 3 * KN + (size_t)gid * 8);
        float4 a = p[0], b = p[1];
        *(uint4*)(wc3 + (size_t)gid * 8) = pack8bf(a, b);
    }
}

// ------------------------------------------------ l=0 head: qkv + E0 MFMA GEMM
// grid: [0,192) qkv (z=bid>>6, mb=(bid>>3)&7, by=bid&7) | [192,200) E0 = bond_bf @ ewt0
__launch_bounds__(256)
__global__ void qkv0_e0(const bf16* __restrict__ xn_bf, const bf16* __restrict__ qkvt,
                        float* __restrict__ qkv,
                        const bf16* __restrict__ bond_bf, const bf16* __restrict__ ewt0,
                        bf16* __restrict__ E0) {
    __shared__ __align__(16) char lds[4 * 64 * RSTR];
    int bid = blockIdx.x;
    if (bid < 192) {
        int z = bid >> 6, rem = bid & 63;
        int mb = rem >> 3, by = rem & 7;
        gemm64_body<0>(lds, xn_bf, qkvt + (size_t)z * 262144,
                       qkv + (size_t)z * 262144, nullptr, 512, 512, 512, mb, by, 0, 512);
    } else {
        gemm64_body<3>(lds, bond_bf, ewt0, E0, nullptr, 64, 512, 512,
                       0, bid - 192, 0, 512);
    }
}

// ------------------------------------------------ l=1 head: basis1 + qkv + edge_coeff(l=0)
// grid: [0,264) gemm (bx=bid>>3, by=bid&7) | [264,2312) edge-coeff blocks (16 pairs each)
__launch_bounds__(256)
__global__ void basis1_qkv_ec(const bf16* __restrict__ x_bf, const bf16* __restrict__ E0,
                              const bf16* __restrict__ ewt1,
                              bf16* __restrict__ xw1, bf16* __restrict__ e0w1,
                              const bf16* __restrict__ xn_bf, const bf16* __restrict__ qkvt_l,
                              float* __restrict__ qkv,
                              const int* __restrict__ adj, const float* __restrict__ x,
                              float* __restrict__ w0o, float* __restrict__ w1o,
                              float* __restrict__ w2o) {
    __shared__ __align__(16) char lds[4 * 64 * RSTR];
    int bid = blockIdx.x;
    if (bid < 264) {
        int bx = bid >> 3, by = bid & 7;
        if (bx < 8)
            gemm64_body<3>(lds, x_bf, ewt1, xw1, nullptr, 512, 512, 512, bx, by, 0, 512);
        else if (bx == 8)
            gemm64_body<3>(lds, E0, ewt1, e0w1, nullptr, 64, 512, 512, 0, by, 0, 512);
        else {
            int tq = bx - 9;
            int z = tq >> 3, mb = tq & 7;
            gemm64_body<0>(lds, xn_bf, qkvt_l + (size_t)z * 262144,
                           qkv + (size_t)z * 262144, nullptr, 512, 512, 512, mb, by, 0, 512);
        }
    } else {
        int k = bid - 264;
        int tid = threadIdx.x;
        int lane = tid & 63, tyv = tid >> 6;
        for (int pp = 0; pp < 4; ++pp) {
            int pair = k * 16 + pp * 4 + tyv;
            int b = pair >> 12;
            int i = (pair >> 6) & 63;
            int j = pair & 63;
            const uint4*  e4  = (const uint4*)(E0 + (size_t)adj[pair] * H_);
            const float4* xi4 = (const float4*)(x + (size_t)(b * 64 + i) * H_);
            const float4* xj4 = (const float4*)(x + (size_t)(b * 64 + j) * H_);
            uint4  eu = e4[lane];
            float4 a0 = xi4[lane * 2], a1 = xi4[lane * 2 + 1];
            float4 c0 = xj4[lane * 2], c1 = xj4[lane * 2 + 1];
            float ef[8], af[8], cf[8];
            unpack8(eu, ef);
            af[0] = a0.x; af[1] = a0.y; af[2] = a0.z; af[3] = a0.w;
            af[4] = a1.x; af[5] = a1.y; af[6] = a1.z; af[7] = a1.w;
            cf[0] = c0.x; cf[1] = c0.y; cf[2] = c0.z; cf[3] = c0.w;
            cf[4] = c1.x; cf[5] = c1.y; cf[6] = c1.z; cf[7] = c1.w;
            float s0 = 0.f, s1 = 0.f, s2 = 0.f;
            #pragma unroll
            for (int t = 0; t < 8; ++t) {
                s0 += ef[t] * ef[t]; s1 += ef[t] * af[t]; s2 += ef[t] * cf[t];
            }
            #pragma unroll
            for (int off = 32; off; off >>= 1) {
                s0 += __shfl_xor(s0, off);
                s1 += __shfl_xor(s1, off);
                s2 += __shfl_xor(s2, off);
            }
            float t0 = s0 * INV_SCALE, t1 = s1 * INV_SCALE, t2 = s2 * INV_SCALE;
            float m = fmaxf(t0, fmaxf(t1, t2));
            float e0 = expf(t0 - m), e1 = expf(t1 - m), e2 = expf(t2 - m);
            float inv = 1.0f / (e0 + e1 + e2);
            if (lane == 0) {
                w0o[pair] = e0 * inv;
                w1o[pair] = e1 * inv;
                w2o[pair] = e2 * inv;
            }
        }
    }
}

// ------------------------------------------------ l=2 head: basis2 + qkv + gram1
// grid: [0,328) gemm | [328,368) gram1 (b=k&7, z=k>>3)
__launch_bounds__(256)
__global__ void basis2_qkv_g1(const bf16* __restrict__ xw1, const bf16* __restrict__ x_bf,
                              const bf16* __restrict__ e0w1, const bf16* __restrict__ ewt2,
                              bf16* __restrict__ xw12, bf16* __restrict__ x2w2,
                              bf16* __restrict__ e0w12,
                              const bf16* __restrict__ xn_bf, const bf16* __restrict__ qkvt_l,
                              float* __restrict__ qkv, float* __restrict__ gbuf) {
    __shared__ __align__(16) char lds[4 * 64 * RSTR];
    int bid = blockIdx.x;
    if (bid < 328) {
        int bx = bid >> 3, by = bid & 7;
        if (bx < 8)
            gemm64_body<3>(lds, xw1, ewt2, xw12, nullptr, 512, 512, 512, bx, by, 0, 512);
        else if (bx < 16)
            gemm64_body<3>(lds, x_bf, ewt2, x2w2, nullptr, 512, 512, 512, bx - 8, by, 0, 512);
        else if (bx == 16)
            gemm64_body<3>(lds, e0w1, ewt2, e0w12, nullptr, 64, 512, 512, 0, by, 0, 512);
        else {
            int tq = bx - 17;
            int z = tq >> 3, mb = tq & 7;
            gemm64_body<0>(lds, xn_bf, qkvt_l + (size_t)z * 262144,
                           qkv + (size_t)z * 262144, nullptr, 512, 512, 512, mb, by, 0, 512);
        }
    } else {
        int k = bid - 328;
        int b = k & 7, z = k >> 3;
        size_t ob = (size_t)b * 32768;
        const bf16 *A, *Bt;
        switch (z) {
            case 0: A = xw1 + ob; Bt = xw1 + ob; break;
            case 1: A = e0w1;     Bt = xw1 + ob; break;
            case 2: A = xw1 + ob; Bt = x_bf + ob; break;
            case 3: A = e0w1;     Bt = x_bf + ob; break;
            default: A = e0w1;    Bt = e0w1;     break;
        }
        float* C = gbuf + (size_t)z * 32768 + (size_t)b * 4096;
        gemm64_body<0>(lds, A, Bt, C, nullptr, 64, 64, 512, 0, 0, 0, 512);
    }
}

// ------------------------------------------------ l=2: ptable(3) + coeff1
// grid: [0,192) ptable (z=bid>>6, b=(bid&63)>>3, h=bid&7) | [192,256) coeff1 (8 rows each)
__launch_bounds__(256)
__global__ void ptable2c(const float* __restrict__ q,
                         const bf16* __restrict__ B0, const bf16* __restrict__ B1,
                         const bf16* __restrict__ B2,
                         float* __restrict__ P0, float* __restrict__ P1,
                         float* __restrict__ P2,
                         const int* __restrict__ adj,
                         const float* __restrict__ c0a, const float* __restrict__ c1a,
                         const float* __restrict__ c2a, const float* __restrict__ gbuf,
                         float* __restrict__ w0o, float* __restrict__ w1o,
                         float* __restrict__ w2o) {
    __shared__ __align__(16) char lds[4 * 64 * RSTR];
    int bid = blockIdx.x;
    if (bid < 192) {
        int z = bid >> 6, rem = bid & 63;
        int b = rem >> 3, h = rem & 7;
        const bf16* Bt = (z == 0) ? B0 : (z == 1 ? B1 : B2);
        float* P = (z == 0) ? P0 : (z == 1 ? P1 : P2);
        ptable_body(lds, q, Bt, P, b, h, z == 2);
    } else {
        int k = bid - 192;
        int tid = threadIdx.x;
        int j = tid & 63;
        #pragma unroll
        for (int pass = 0; pass < 2; ++pass) {
            int row = k * 8 + pass * 4 + (tid >> 6);
            coeff1_body(adj, c0a, c1a, c2a, gbuf, row, j, w0o, w1o, w2o);
        }
    }
}

// ------------------------------------------------ l=1: ptable (2 bases), standalone
__launch_bounds__(256)
__global__ void ptable_kernel(const float* __restrict__ q,
                              const bf16* __restrict__ B0, const bf16* __restrict__ B1,
                              float* __restrict__ P0, float* __restrict__ P1) {
    __shared__ __align__(16) char lds[4 * 64 * RSTR];
    const int b = blockIdx.x, h = blockIdx.y, z = blockIdx.z;
    const bf16* Bt = (z == 0) ? B0 : B1;
    float* P = (z == 0) ? P0 : P1;
    ptable_body(lds, q, Bt, P, b, h, z == 1);
}

// ------------------------------------------------ l=3 head: qkv + gram2
// grid: [0,192) qkv (z=bid>>6, mb=(bid>>3)&7, by=bid&7) | [192,264) gram2
__launch_bounds__(256)
__global__ void l3qkv_g2(const bf16* __restrict__ xn_bf, const bf16* __restrict__ qkvt_l,
                         float* __restrict__ qkv,
                         const bf16* __restrict__ xw12, const bf16* __restrict__ x2w2,
                         const bf16* __restrict__ e0w12, const bf16* __restrict__ x_bf,
                         float* __restrict__ gbuf) {
    __shared__ __align__(16) char lds[4 * 64 * RSTR];
    int bid = blockIdx.x;
    if (bid < 192) {
        int z = bid >> 6, rem = bid & 63;
        int mb = rem >> 3, by = rem & 7;
        gemm64_body<0>(lds, xn_bf, qkvt_l + (size_t)z * 262144,
                       qkv + (size_t)z * 262144, nullptr, 512, 512, 512, mb, by, 0, 512);
    } else {
        int k = bid - 192;
        int b = k & 7, z = k >> 3;
        size_t ob = (size_t)b * 32768;
        const bf16 *A, *Bt;
        switch (z) {
            case 0: A = xw12 + ob; Bt = xw12 + ob; break;
            case 1: A = xw12 + ob; Bt = x2w2 + ob; break;
            case 2: A = x2w2 + ob; Bt = x2w2 + ob; break;
            case 3: A = e0w12;     Bt = xw12 + ob; break;
            case 4: A = e0w12;     Bt = x2w2 + ob; break;
            case 5: A = e0w12;     Bt = e0w12;     break;
            case 6: A = xw12 + ob; Bt = x_bf + ob; break;
            case 7: A = x2w2 + ob; Bt = x_bf + ob; break;
            default: A = e0w12;    Bt = x_bf + ob; break;
        }
        float* C = gbuf + (size_t)z * 32768 + (size_t)b * 4096;
        gemm64_body<0>(lds, A, Bt, C, nullptr, 64, 64, 512, 0, 0, 0, 512);
    }
}

// ------------------------------------------------ l=3: u_gemm + coeff2
// grid: [0,512) u (h=bid>>6, mb=(bid>>3)&7, nb=bid&7) | [512,576) coeff2 (8 rows each)
__launch_bounds__(256)
__global__ void u_c2(const float* __restrict__ q, const bf16* __restrict__ wc3,
                     bf16* __restrict__ ubf,
                     const int* __restrict__ adj,
                     const float* __restrict__ c0a, const float* __restrict__ c1a,
                     const float* __restrict__ c2a,
                     const float* __restrict__ c0b, const float* __restrict__ c1b,
                     const float* __restrict__ c2b,
                     const float* __restrict__ gbuf,
                     float* __restrict__ w0o, float* __restrict__ w1o,
                     float* __restrict__ w2o) {
    __shared__ __align__(16) char lds[4 * 64 * RSTR];
    int bid = blockIdx.x;
    if (bid < 512) {
        int h = bid >> 6, mb = (bid >> 3) & 7, nb = bid & 7;
        ugemm_body(lds, q, wc3, ubf, h, mb, nb);
    } else {
        int k = bid - 512;
        int tid = threadIdx.x;
        int j = tid & 63;
        #pragma unroll
        for (int pass = 0; pass < 2; ++pass) {
            int row = k * 8 + pass * 4 + (tid >> 6);
            coeff2_body(adj, c0a, c1a, c2a, c0b, c1b, c2b, gbuf, row, j, w0o, w1o, w2o);
        }
    }
}

// M-tables: for each b, U_b (512 rows (i,h) x 512 k) @ basis_b^T (64 x 512)
__launch_bounds__(256)
__global__ void mbuf_gemm(const bf16* __restrict__ ubf, const bf16* __restrict__ xw12,
                          const bf16* __restrict__ x2w2, const bf16* __restrict__ x_bf,
                          const bf16* __restrict__ e0w12,
                          float* __restrict__ MX, float* __restrict__ MY,
                          float* __restrict__ MZ, float* __restrict__ DE) {
    __shared__ __align__(16) char lds[4 * 64 * RSTR];
    int b = blockIdx.x, mt = blockIdx.y, z = blockIdx.z;
    const bf16* A = ubf + (size_t)b * 512 * 512;
    const bf16* Bt;
    float* C;
    if (z == 0)      { Bt = xw12 + (size_t)b * 64 * 512; C = MX + (size_t)b * 512 * 64; }
    else if (z == 1) { Bt = x2w2 + (size_t)b * 64 * 512; C = MY + (size_t)b * 512 * 64; }
    else if (z == 2) { Bt = x_bf + (size_t)b * 64 * 512; C = MZ + (size_t)b * 512 * 64; }
    else             { Bt = e0w12;                        C = DE + (size_t)b * 512 * 64; }
    gemm64_body<0>(lds, A, Bt, C, nullptr, 512, 64, 512, mt, 0, 0, 512);
}

// ---------------------- split-K reduce + residual + LN variants
__global__ void reduce_stack_ln(const float* __restrict__ part, const float* __restrict__ base,
                                float* __restrict__ resid, bf16* __restrict__ ffin_bf) {
    const int MN = 512 * H_;
    int row = blockIdx.x;
    int tid = threadIdx.x;
    size_t b0 = (size_t)row * H_;
    float v0 = base[b0 + tid], v1 = base[b0 + tid + 256];
    #pragma unroll
    for (int s = 0; s < 4; ++s) {
        v0 += part[(size_t)s * MN + b0 + tid];
        v1 += part[(size_t)s * MN + b0 + tid + 256];
    }
    resid[b0 + tid] = v0;
    resid[b0 + tid + 256] = v1;
    float s = v0 + v1, sq = v0 * v0 + v1 * v1;
    #pragma unroll
    for (int off = 32; off; off >>= 1) {
        s  += __shfl_xor(s,  off);
        sq += __shfl_xor(sq, off);
    }
    __shared__ float ls[4], lq[4];
    int w = tid >> 6;
    if ((tid & 63) == 0) { ls[w] = s; lq[w] = sq; }
    __syncthreads();
    float S = ls[0] + ls[1] + ls[2] + ls[3];
    float Q = lq[0] + lq[1] + lq[2] + lq[3];
    float mean = S * (1.0f / H_);
    float var  = Q * (1.0f / H_) - mean * mean;
    float inv  = rsqrtf(var + 1e-5f);
    ffin_bf[b0 + tid]       = f2bf((v0 - mean) * inv);
    ffin_bf[b0 + tid + 256] = f2bf((v1 - mean) * inv);
}

template <bool DO_LN>
__global__ void reduce_ln_kernel(const float* __restrict__ part, const float* __restrict__ resid,
                                 float* __restrict__ x, bf16* __restrict__ x_bf,
                                 float* __restrict__ xn, bf16* __restrict__ xn_bf) {
    const int MN = 512 * H_;
    int row = blockIdx.x;
    int tid = threadIdx.x;
    size_t base = (size_t)row * H_;
    float v0 = resid[base + tid], v1 = resid[base + tid + 256];
    #pragma unroll
    for (int s = 0; s < 4; ++s) {
        v0 += part[(size_t)s * MN + base + tid];
        v1 += part[(size_t)s * MN + base + tid + 256];
    }
    x[base + tid] = v0;
    x[base + tid + 256] = v1;
    x_bf[base + tid]       = f2bf(v0);
    x_bf[base + tid + 256] = f2bf(v1);
    if (DO_LN) {
        float s = v0 + v1, sq = v0 * v0 + v1 * v1;
        #pragma unroll
        for (int off = 32; off; off >>= 1) {
            s  += __shfl_xor(s,  off);
            sq += __shfl_xor(sq, off);
        }
        __shared__ float ls[4], lq[4];
        int w = tid >> 6;
        if ((tid & 63) == 0) { ls[w] = s; lq[w] = sq; }
        __syncthreads();
        float S = ls[0] + ls[1] + ls[2] + ls[3];
        float Q = lq[0] + lq[1] + lq[2] + lq[3];
        float mean = S * (1.0f / H_);
        float var  = Q * (1.0f / H_) - mean * mean;
        float inv  = rsqrtf(var + 1e-5f);
        float y0 = (v0 - mean) * inv, y1 = (v1 - mean) * inv;
        xn[base + tid]       = y0;
        xn[base + tid + 256] = y1;
        xn_bf[base + tid]       = f2bf(y0);
        xn_bf[base + tid + 256] = f2bf(y1);
    }
}

// ---------------------------------------------------------------- attention
// l=0: w-row gathered from E0[adj[pair]] (8-row table, L1-resident)
template <bool GATHER>
__global__ void attn_kernel(const float* __restrict__ qkv, const bf16* __restrict__ ew,
                            const int* __restrict__ adj, bf16* __restrict__ o) {
    const float* q = qkv;
    const float* k = qkv + (size_t)512 * H_;
    const float* v = qkv + (size_t)1024 * H_;
    int bi = blockIdx.x;
    int b  = bi >> 6;
    int ty = threadIdx.y;
    int h  = blockIdx.y * 4 + ty;
    int lane = threadIdx.x;
    __shared__ float qs[4][64], as[4][64];
    qs[ty][lane] = q[(size_t)bi * H_ + h * 64 + lane];
    __syncthreads();

    int j = lane;
    int pair = bi * 64 + j;
    int aj = adj[pair];
    const float4* k4 = (const float4*)(k + (size_t)(b * 64 + j) * H_ + h * 64);
    const uint4*  w4 = (const uint4*)((GATHER ? ew + (size_t)aj * H_
                                              : ew + (size_t)pair * H_) + h * 64);
    float acc = 0.f;
    #pragma unroll
    for (int t = 0; t < 8; ++t) {
        uint4 wu = w4[t];
        float4 ka = k4[2 * t], kb = k4[2 * t + 1];
        float wf[8];
        unpack8(wu, wf);
        const float* qq = &qs[ty][t * 8];
        acc += qq[0] * (ka.x + wf[0]) + qq[1] * (ka.y + wf[1])
             + qq[2] * (ka.z + wf[2]) + qq[3] * (ka.w + wf[3])
             + qq[4] * (kb.x + wf[4]) + qq[5] * (kb.y + wf[5])
             + qq[6] * (kb.z + wf[6]) + qq[7] * (kb.w + wf[7]);
    }
    float logit = acc * INV_SCALE;
    if (aj <= 0) logit = -INFINITY;

    float m = logit;
    #pragma unroll
    for (int off = 32; off; off >>= 1) m = fmaxf(m, __shfl_xor(m, off));
    float p = expf(logit - m);
    float s = p;
    #pragma unroll
    for (int off = 32; off; off >>= 1) s += __shfl_xor(s, off);
    as[ty][lane] = p / s;
    __syncthreads();

    const float* vbase = v + (size_t)(b * 64) * H_ + h * 64;
    float oacc = 0.f;
    int d = lane;
    #pragma unroll 8
    for (int jj = 0; jj < 64; ++jj)
        oacc += as[ty][jj] * vbase[(size_t)jj * H_ + d];
    o[(size_t)bi * H_ + h * 64 + d] = __float2bfloat16(oacc);
}

// l=1/l=2: w-term combined inline from P-tables
template <int MODE>
__global__ void attn13_kernel(const float* __restrict__ qkv, const int* __restrict__ adj,
        const float* __restrict__ c0a, const float* __restrict__ c1a, const float* __restrict__ c2a,
        const float* __restrict__ c0b, const float* __restrict__ c1b, const float* __restrict__ c2b,
        const float* __restrict__ PX, const float* __restrict__ PY, const float* __restrict__ PE,
        bf16* __restrict__ o) {
    const float* q = qkv;
    const float* k = qkv + (size_t)512 * H_;
    const float* v = qkv + (size_t)1024 * H_;
    int bi = blockIdx.x;
    int b  = bi >> 6, i = bi & 63;
    int ty = threadIdx.y;
    int h  = blockIdx.y * 4 + ty;
    int lane = threadIdx.x;
    __shared__ float qs[4][64], as[4][64];
    qs[ty][lane] = q[(size_t)bi * H_ + h * 64 + lane];
    __syncthreads();

    int j = lane;
    int p = bi * 64 + j;
    int t = adj[p];
    size_t pb = (((size_t)b * 8 + h) * 64 + i) * 64;
    float acc;
    if (MODE == 1) {
        acc = c0a[p] * PE[pb + t] + c1a[p] * PX[pb + i] + c2a[p] * PX[pb + j];
    } else {
        float a0 = c0b[p];
        float AE = a0 * c0a[p], Aa = a0 * c1a[p], Ab = a0 * c2a[p];
        float Ac = c1b[p], Ad = c2b[p];
        acc = AE * PE[pb + t] + Aa * PX[pb + i] + Ab * PX[pb + j]
            + Ac * PY[pb + i] + Ad * PY[pb + j];
    }
    const float4* k4 = (const float4*)(k + (size_t)(b * 64 + j) * H_ + h * 64);
    #pragma unroll
    for (int tt = 0; tt < 8; ++tt) {
        float4 ka = k4[2 * tt], kb = k4[2 * tt + 1];
        const float* qq = &qs[ty][tt * 8];
        acc += qq[0] * ka.x + qq[1] * ka.y + qq[2] * ka.z + qq[3] * ka.w
             + qq[4] * kb.x + qq[5] * kb.y + qq[6] * kb.z + qq[7] * kb.w;
    }
    float logit = acc * INV_SCALE;
    if (t <= 0) logit = -INFINITY;

    float m = logit;
    #pragma unroll
    for (int off = 32; off; off >>= 1) m = fmaxf(m, __shfl_xor(m, off));
    float pe = expf(logit - m);
    float s = pe;
    #pragma unroll
    for (int off = 32; off; off >>= 1) s += __shfl_xor(s, off);
    as[ty][lane] = pe / s;
    __syncthreads();

    const float* vbase = v + (size_t)(b * 64) * H_ + h * 64;
    float oacc = 0.f;
    int d = lane;
    #pragma unroll 8
    for (int jj = 0; jj < 64; ++jj)
        oacc += as[ty][jj] * vbase[(size_t)jj * H_ + d];
    o[(size_t)bi * H_ + h * 64 + d] = __float2bfloat16(oacc);
}

// l=3: w-term computed inline from M-tables + coeffs (s2_assemble fused in)
__global__ void attn3s2_kernel(const float* __restrict__ qkv, const int* __restrict__ adj,
        const float* __restrict__ c0a, const float* __restrict__ c1a, const float* __restrict__ c2a,
        const float* __restrict__ c0b, const float* __restrict__ c1b, const float* __restrict__ c2b,
        const float* __restrict__ v0c, const float* __restrict__ v1c, const float* __restrict__ v2c,
        const float* __restrict__ MX, const float* __restrict__ MY,
        const float* __restrict__ MZ, const float* __restrict__ DE,
        bf16* __restrict__ o) {
    const float* q = qkv;
    const float* k = qkv + (size_t)512 * H_;
    const float* v = qkv + (size_t)1024 * H_;
    int bi = blockIdx.x;
    int b  = bi >> 6, i = bi & 63;
    int ty = threadIdx.y;
    int h  = blockIdx.y * 4 + ty;
    int lane = threadIdx.x;
    __shared__ float qs[4][64], as[4][64];
    qs[ty][lane] = q[(size_t)bi * H_ + h * 64 + lane];
    __syncthreads();

    int j = lane;
    int p = bi * 64 + j;
    int t = adj[p];
    float v0 = v0c[p];
    float q0 = v0 * c0b[p];
    float AE = q0 * c0a[p], Aa = q0 * c1a[p], Ab = q0 * c2a[p];
    float Ac = v0 * c1b[p], Ad = v0 * c2b[p];
    float Ae = v1c[p], Af = v2c[p];
    size_t rb = ((size_t)b * 512 + i * 8 + h) * 64;
    float acc = AE * DE[rb + t]
              + Aa * MX[rb + i] + Ac * MY[rb + i] + Ae * MZ[rb + i]
              + Ab * MX[rb + j] + Ad * MY[rb + j] + Af * MZ[rb + j];

    const float4* k4 = (const float4*)(k + (size_t)(b * 64 + j) * H_ + h * 64);
    #pragma unroll
    for (int tt = 0; tt < 8; ++tt) {
        float4 ka = k4[2 * tt], kb = k4[2 * tt + 1];
        const float* qq = &qs[ty][tt * 8];
        acc += qq[0] * ka.x + qq[1] * ka.y + qq[2] * ka.z + qq[3] * ka.w
             + qq[4] * kb.x + qq[5] * kb.y + qq[6] * kb.z + qq[7] * kb.w;
    }
    float logit = acc * INV_SCALE;
    if (t <= 0) logit = -INFINITY;

    float m = logit;
    #pragma unroll
    for (int off = 32; off; off >>= 1) m = fmaxf(m, __shfl_xor(m, off));
    float pe = expf(logit - m);
    float s = pe;
    #pragma unroll
    for (int off = 32; off; off >>= 1) s += __shfl_xor(s, off);
    as[ty][lane] = pe / s;
    __syncthreads();

    const float* vbase = v + (size_t)(b * 64) * H_ + h * 64;
    float oacc = 0.f;
    int d = lane;
    #pragma unroll 8
    for (int jj = 0; jj < 64; ++jj)
        oacc += as[ty][jj] * vbase[(size_t)jj * H_ + d];
    o[(size_t)bi * H_ + h * 64 + d] = __float2bfloat16(oacc);
}

// ---------------------------------------------------------------- head
__global__ void cls_part_kernel(const float* __restrict__ x, const float* __restrict__ Wout,
                                float* __restrict__ clspart) {
    int b  = blockIdx.x;
    int cb = blockIdx.y;
    int ks = blockIdx.z;
    int tid = threadIdx.x;
    int c  = cb * 64 + (tid & 63);
    int kk = tid >> 6;
    const float* xr = x + (size_t)(b * 64) * H_;
    int h0 = ks * 128 + kk * 32;
    float acc = 0.f;
    #pragma unroll
    for (int h = 0; h < 32; ++h)
        acc += xr[h0 + h] * Wout[(size_t)(h0 + h) * H_ + c];
    __shared__ float red[4][64];
    red[kk][tid & 63] = acc;
    __syncthreads();
    if (tid < 64) {
        float v = red[0][tid] + red[1][tid] + red[2][tid] + red[3][tid];
        clspart[((size_t)ks * 8 + b) * H_ + cb * 64 + tid] = v;
    }
}

__global__ void cls_pred2_kernel(const float* __restrict__ clspart,
                                 const float* __restrict__ Wpred,
                                 const float* __restrict__ bpred,
                                 float* __restrict__ out) {
    int b = blockIdx.x;
    int tid = threadIdx.x;
    __shared__ float red0[4], red1[4];
    float a0 = 0.f, a1 = 0.f;
    #pragma unroll
    for (int t = 0; t < 2; ++t) {
        int c = tid + t * 256;
        float v = clspart[((size_t)0 * 8 + b) * H_ + c]
                + clspart[((size_t)1 * 8 + b) * H_ + c]
                + clspart[((size_t)2 * 8 + b) * H_ + c]
                + clspart[((size_t)3 * 8 + b) * H_ + c];
        float tv = tanhf(v);
        a0 += tv * Wpred[c * 2 + 0];
        a1 += tv * Wpred[c * 2 + 1];
    }
    #pragma unroll
    for (int off = 32; off; off >>= 1) {
        a0 += __shfl_xor(a0, off);
        a1 += __shfl_xor(a1, off);
    }
    int w = tid >> 6;
    if ((tid & 63) == 0) { red0[w] = a0; red1[w] = a1; }
    __syncthreads();
    if (tid == 0) {
        float s0 = red0[0] + red0[1] + red0[2] + red0[3] + bpred[0];
        float s1 = red1[0] + red1[1] + red1[2] + red1[3] + bpred[1];
        float m = fmaxf(s0, s1);
        float e0 = expf(s0 - m), e1 = expf(s1 - m);
        float inv = 1.0f / (e0 + e1);
        out[b * 2 + 0] = e0 * inv;
        out[b * 2 + 1] = e1 * inv;
    }
}

// ---------------------------------------------------------------- launch
extern "C" void kernel_launch(void* const* d_in, const int* in_sizes, int n_in,
                              void* d_out, int out_size, void* d_ws, size_t ws_size,
                              hipStream_t stream) {
    const int*   ids      = (const int*)d_in[0];
    const int*   adj      = (const int*)d_in[1];
    const float* atom_emb = (const float*)d_in[2];
    const float* bond_emb = (const float*)d_in[3];
    const float* Wq     = (const float*)d_in[4];
    const float* Wk     = (const float*)d_in[5];
    const float* Wv     = (const float*)d_in[6];
    const float* Wew    = (const float*)d_in[7];
    const float* Wstack = (const float*)d_in[8];
    const float* Wf1    = (const float*)d_in[9];
    const float* Wf2    = (const float*)d_in[10];
    const float* Wout   = (const float*)d_in[11];
    const float* Wpred  = (const float*)d_in[12];
    const float* bpred  = (const float*)d_in[13];

    char* ws = (char*)d_ws;
    size_t off = 0;
    auto alloc = [&](size_t bytes) {
        size_t o = off;
        off += (bytes + 255) & ~(size_t)255;
        return o;
    };
    const size_t ROWS  = (size_t)B_ * N_;
    const size_t PAIRS = (size_t)B_ * N_ * N_;
    const size_t KN    = (size_t)H_ * H_;

    float* x       = (float*)(ws + alloc(ROWS * H_ * 4));
    float* xn      = (float*)(ws + alloc(ROWS * H_ * 4));
    bf16*  xn_bf   = (bf16*) (ws + alloc(ROWS * H_ * 2));
    bf16*  x_bf    = (bf16*) (ws + alloc(ROWS * H_ * 2));
    float* qkv     = (float*)(ws + alloc(3 * ROWS * H_ * 4));
    bf16*  o_bf    = (bf16*) (ws + alloc(ROWS * H_ * 2));
    float* resid   = (float*)(ws + alloc(ROWS * H_ * 4));
    bf16*  ffin_bf = (bf16*) (ws + alloc(ROWS * H_ * 2));
    bf16*  ffh_bf  = (bf16*) (ws + alloc(ROWS * 4 * H_ * 2));
    float* part    = (float*)(ws + alloc(4 * ROWS * H_ * 4));
    float* clspart = (float*)(ws + alloc(4 * 8 * H_ * 4));
    bf16*  ubf     = (bf16*) (ws + alloc(ROWS * 8 * 512 * 2));           // 4 MB
    float* MX      = (float*)(ws + alloc((size_t)4096 * 64 * 4));        // 1 MB each
    float* MY      = (float*)(ws + alloc((size_t)4096 * 64 * 4));
    float* MZ      = (float*)(ws + alloc((size_t)4096 * 64 * 4));
    float* DE      = (float*)(ws + alloc((size_t)4096 * 64 * 4));
    float* PT0     = (float*)(ws + alloc((size_t)4096 * 64 * 4));        // P-tables
    float* PT1     = (float*)(ws + alloc((size_t)4096 * 64 * 4));
    float* PT2     = (float*)(ws + alloc((size_t)4096 * 64 * 4));
    float* gbuf    = (float*)(ws + alloc((size_t)9 * 8 * 4096 * 4));     // Gram tables
    bf16*  wc3     = (bf16*) (ws + alloc(KN * 2));
    bf16*  bond_bf = (bf16*) (ws + alloc(64 * H_ * 2));      // bond_emb bf16, rows 8..63 zero
    bf16*  E0      = (bf16*) (ws + alloc(64 * H_ * 2));      // padded to 64 rows
    bf16*  e0w1    = (bf16*) (ws + alloc(64 * H_ * 2));
    bf16*  e0w12   = (bf16*) (ws + alloc(64 * H_ * 2));
    bf16*  xw1     = (bf16*) (ws + alloc(KN * 2));
    bf16*  xw12    = (bf16*) (ws + alloc(KN * 2));
    bf16*  x2w2    = (bf16*) (ws + alloc(KN * 2));
    float* cw      = (float*)(ws + alloc(9 * PAIRS * 4));    // edge softmax coeffs
    bf16*  qkvt    = (bf16*) (ws + alloc((size_t)L_ * 3 * KN * 2));
    bf16*  ewt     = (bf16*) (ws + alloc((size_t)L_ * KN * 2));
    bf16*  stackt  = (bf16*) (ws + alloc((size_t)L_ * KN * 2));
    bf16*  f1t     = (bf16*) (ws + alloc((size_t)L_ * 4 * KN * 2));
    bf16*  f2t     = (bf16*) (ws + alloc((size_t)L_ * 4 * KN * 2));
    (void)ws_size;

    float* cw0a = cw;
    float* cw1a = cw + PAIRS;
    float* cw2a = cw + 2 * PAIRS;
    float* cw0b = cw + 3 * PAIRS;
    float* cw1b = cw + 4 * PAIRS;
    float* cw2b = cw + 5 * PAIRS;
    float* cw0c = cw + 6 * PAIRS;
    float* cw1c = cw + 7 * PAIRS;
    float* cw2c = cw + 8 * PAIRS;

    // one-shot setup: embed+LN, weight transposes (64x64 vectorized), bond_bf, Wew3 cast
    setup_kernel<<<4096, 256, 0, stream>>>(ids, atom_emb, bond_emb,
                                           Wq, Wk, Wv, Wew, Wstack, Wf1, Wf2,
                                           xn, xn_bf, qkvt, ewt, stackt, f1t, f2t,
                                           bond_bf, wc3);

    for (int l = 0; l < L_; ++l) {
        if (l == 0) {
            // qkv + E0 (E0 = bond_bf @ ewt0 via MFMA; replaces latency-bound scalar dot)
            qkv0_e0<<<200, 256, 0, stream>>>(xn_bf, qkvt, qkv, bond_bf, ewt, E0);
            attn_kernel<true><<<dim3(512, 2), dim3(64, 4), 0, stream>>>(qkv, E0, adj, o_bf);
        } else if (l == 1) {
            // basis1 + qkv + edge_coeff(l=0)
            basis1_qkv_ec<<<2312, 256, 0, stream>>>(
                x_bf, E0, ewt + KN, xw1, e0w1, xn_bf, qkvt + (size_t)3 * KN, qkv,
                adj, x, cw0a, cw1a, cw2a);
            ptable_kernel<<<dim3(8, 8, 2), 256, 0, stream>>>(qkv, xw1, e0w1, PT0, PT1);
            attn13_kernel<1><<<dim3(512, 2), dim3(64, 4), 0, stream>>>(
                qkv, adj, cw0a, cw1a, cw2a, nullptr, nullptr, nullptr,
                PT0, nullptr, PT1, o_bf);
        } else if (l == 2) {
            // basis2 + qkv + gram1
            basis2_qkv_g1<<<368, 256, 0, stream>>>(
                xw1, x_bf, e0w1, ewt + 2 * KN, xw12, x2w2, e0w12,
                xn_bf, qkvt + (size_t)6 * KN, qkv, gbuf);
            // ptables + coeff1
            ptable2c<<<256, 256, 0, stream>>>(
                qkv, xw12, x2w2, e0w12, PT0, PT1, PT2,
                adj, cw0a, cw1a, cw2a, gbuf, cw0b, cw1b, cw2b);
            attn13_kernel<2><<<dim3(512, 2), dim3(64, 4), 0, stream>>>(
                qkv, adj, cw0a, cw1a, cw2a, cw0b, cw1b, cw2b,
                PT0, PT1, PT2, o_bf);
        } else {
            // qkv + gram2
            l3qkv_g2<<<264, 256, 0, stream>>>(
                xn_bf, qkvt + (size_t)9 * KN, qkv, xw12, x2w2, e0w12, x_bf, gbuf);
            // u + coeff2
            u_c2<<<576, 256, 0, stream>>>(
                qkv, wc3, ubf, adj, cw0a, cw1a, cw2a, cw0b, cw1b, cw2b,
                gbuf, cw0c, cw1c, cw2c);
            mbuf_gemm<<<dim3(8, 8, 4), 256, 0, stream>>>(ubf, xw12, x2w2, x_bf, e0w12,
                                                         MX, MY, MZ, DE);
            attn3s2_kernel<<<dim3(512, 2), dim3(64, 4), 0, stream>>>(
                qkv, adj, cw0a, cw1a, cw2a, cw0b, cw1b, cw2b, cw0c, cw1c, cw2c,
                MX, MY, MZ, DE, o_bf);
        }

        mfma_gemm_s<0, true><<<dim3(8, 8, 4), 256, 0, stream>>>(
            o_bf, stackt + (size_t)l * KN, part, nullptr, 512, 512, 512);
        reduce_stack_ln<<<512, 256, 0, stream>>>(part, xn, resid, ffin_bf);
        mfma_gemm_s<2, false><<<dim3(8, 32), 256, 0, stream>>>(
            ffin_bf, f1t + (size_t)l * 4 * KN, ffh_bf, nullptr, 512, 2048, 512);
        mfma_gemm_s<0, true><<<dim3(8, 8, 4), 256, 0, stream>>>(
            ffh_bf, f2t + (size_t)l * 4 * KN, part, nullptr, 512, 512, 2048);
        if (l < L_ - 1)
            reduce_ln_kernel<true><<<512, 256, 0, stream>>>(part, resid, x, x_bf, xn, xn_bf);
        else
            reduce_ln_kernel<false><<<512, 256, 0, stream>>>(part, resid, x, x_bf, xn, xn_bf);
    }

    cls_part_kernel<<<dim3(8, 8, 4), 256, 0, stream>>>(x, Wout, clspart);
    cls_pred2_kernel<<<8, 256, 0, stream>>>(clspart, Wpred, bpred, (float*)d_out);
}